// Round 1
// baseline (1821.428 us; speedup 1.0000x reference)
//
#include <hip/hip_runtime.h>
#include <math.h>

#define H_ 8
#define DH_ 64
#define DIM_ 512
#define M_ 256
#define N_ 8192
#define BH_ 16
#define LG_ 32
#define KC_ 33
#define PADC_ 16

// ---------------- shared 64x64 tile core (fp32, BK=16, 4x4 per thread) ----------------
__device__ __forceinline__ void mm_step(float (*As)[68], float (*Bs)[68],
                                        int tr, int tc, float acc[4][4]) {
#pragma unroll
  for (int kk = 0; kk < 16; ++kk) {
    const float4 a4 = *(const float4*)&As[kk][tr * 4];
    const float4 b4 = *(const float4*)&Bs[kk][tc * 4];
    const float a[4] = {a4.x, a4.y, a4.z, a4.w};
    const float b[4] = {b4.x, b4.y, b4.z, b4.w};
#pragma unroll
    for (int i = 0; i < 4; ++i) {
#pragma unroll
      for (int j = 0; j < 4; ++j) acc[i][j] = fmaf(a[i], b[j], acc[i][j]);
    }
  }
}

// stage A[m0+r][k0..k0+16) (row-major, stride lda) transposed into As[kk][r]
__device__ __forceinline__ void load_a_tile(const float* A, int lda, int m0, int k0,
                                            int tid, float (*As)[68]) {
  const int r = tid >> 2, kq = tid & 3;
  const float4 a4 = *(const float4*)(A + (size_t)(m0 + r) * lda + k0 + kq * 4);
  As[kq * 4 + 0][r] = a4.x;
  As[kq * 4 + 1][r] = a4.y;
  As[kq * 4 + 2][r] = a4.z;
  As[kq * 4 + 3][r] = a4.w;
}

// stage B[k0+kr][n0..n0+64) (row-major, stride ldb) into Bs[kr][c]
__device__ __forceinline__ void load_b_nn(const float* B, int ldb, int k0, int n0,
                                          int tid, float (*Bs)[68]) {
  const int kr = tid >> 4, c4 = tid & 15;
  const float4 b4 = *(const float4*)(B + (size_t)(k0 + kr) * ldb + n0 + c4 * 4);
  *(float4*)&Bs[kr][c4 * 4] = b4;
}

// NT: B row-major (N x K): stage B[n0+j][k0..k0+16) into Bs[kk][j]
__device__ __forceinline__ void load_b_nt(const float* B, int ldb, int k0, int n0,
                                          int tid, float (*Bs)[68]) {
  const int j = tid >> 2, kq = tid & 3;
  const float4 b4 = *(const float4*)(B + (size_t)(n0 + j) * ldb + k0 + kq * 4);
  Bs[kq * 4 + 0][j] = b4.x;
  Bs[kq * 4 + 1][j] = b4.y;
  Bs[kq * 4 + 2][j] = b4.z;
  Bs[kq * 4 + 3][j] = b4.w;
}

// ---------------- LayerNorm: one block of 128 per row of 512 ----------------
__global__ __launch_bounds__(128) void ln_kernel(const float* __restrict__ x,
                                                 const float* __restrict__ gamma,
                                                 const float* __restrict__ beta,
                                                 float* __restrict__ xn) {
  const int row = blockIdx.x, tid = threadIdx.x;
  const float4 v = ((const float4*)(x + (size_t)row * DIM_))[tid];
  float s = v.x + v.y + v.z + v.w;
  float ss = v.x * v.x + v.y * v.y + v.z * v.z + v.w * v.w;
  __shared__ float r1[128], r2[128];
  r1[tid] = s;
  r2[tid] = ss;
  __syncthreads();
  for (int off = 64; off > 0; off >>= 1) {
    if (tid < off) {
      r1[tid] += r1[tid + off];
      r2[tid] += r2[tid + off];
    }
    __syncthreads();
  }
  const float mu = r1[0] * (1.0f / DIM_);
  const float var = r2[0] * (1.0f / DIM_) - mu * mu;
  const float rs = rsqrtf(var + 1e-5f);
  const float4 g = ((const float4*)gamma)[tid];
  const float4 bb = ((const float4*)beta)[tid];
  float4 o;
  o.x = (v.x - mu) * rs * g.x + bb.x;
  o.y = (v.y - mu) * rs * g.y + bb.y;
  o.z = (v.z - mu) * rs * g.z + bb.z;
  o.w = (v.w - mu) * rs * g.w + bb.w;
  ((float4*)(xn + (size_t)row * DIM_))[tid] = o;
}

// ---------------- QKV GEMM: (16384x512)@(512x1536), scatter to (bh,n,d) ----------------
__global__ __launch_bounds__(256) void qkv_gemm(const float* __restrict__ A,
                                                const float* __restrict__ W,
                                                float* __restrict__ q,
                                                float* __restrict__ k,
                                                float* __restrict__ v) {
  const int m0 = blockIdx.x * 64, n0 = blockIdx.y * 64;
  const int tid = threadIdx.x, tr = tid >> 4, tc = tid & 15;
  __shared__ float As[16][68], Bs[16][68];
  float acc[4][4] = {};
  for (int k0 = 0; k0 < DIM_; k0 += 16) {
    load_a_tile(A, DIM_, m0, k0, tid, As);
    load_b_nn(W, 3 * DIM_, k0, n0, tid, Bs);
    __syncthreads();
    mm_step(As, Bs, tr, tc, acc);
    __syncthreads();
  }
  const int which = n0 >> 9, h = (n0 >> 6) & 7;
  float* dst = (which == 0) ? q : (which == 1) ? k : v;
  const float scale = (which == 0) ? 0.125f : 1.0f;  // DH^-0.5
#pragma unroll
  for (int i = 0; i < 4; ++i) {
    const int row = m0 + tr * 4 + i;
    const int b = row >> 13, t = row & (N_ - 1);
    const float4 o = make_float4(acc[i][0] * scale, acc[i][1] * scale,
                                 acc[i][2] * scale, acc[i][3] * scale);
    *(float4*)(dst + ((size_t)(b * H_ + h) * N_ + t) * DH_ + tc * 4) = o;
  }
}

// ---------------- landmarks: mean over 32 consecutive tokens ----------------
__global__ __launch_bounds__(256) void landmark_kernel(const float* __restrict__ q,
                                                       const float* __restrict__ k,
                                                       float* __restrict__ ql,
                                                       float* __restrict__ kl) {
  const int idx = blockIdx.x * 256 + threadIdx.x;  // < BH_*M_*DH_
  const int d = idx & (DH_ - 1);
  const int m = (idx >> 6) & (M_ - 1);
  const int bh = idx >> 14;
  const size_t base = ((size_t)bh * N_ + m * LG_) * DH_ + d;
  float sq = 0.f, sk = 0.f;
#pragma unroll 8
  for (int t = 0; t < LG_; ++t) {
    sq += q[base + (size_t)t * DH_];
    sk += k[base + (size_t)t * DH_];
  }
  ql[idx] = sq * (1.0f / LG_);
  kl[idx] = sk * (1.0f / LG_);
}

// ---------------- sim2 row + softmax: block per (bh, row) ----------------
__global__ __launch_bounds__(256) void sim2_softmax(const float* __restrict__ ql,
                                                    const float* __restrict__ kl,
                                                    float* __restrict__ a2) {
  const int i = blockIdx.x, bh = blockIdx.y, j = threadIdx.x;
  __shared__ float qrow[DH_];
  if (j < DH_) qrow[j] = ql[((size_t)bh * M_ + i) * DH_ + j];
  __syncthreads();
  const float* kr = kl + ((size_t)bh * M_ + j) * DH_;
  float s = 0.f;
#pragma unroll 16
  for (int d = 0; d < DH_; ++d) s += qrow[d] * kr[d];
  __shared__ float red[256];
  red[j] = s;
  __syncthreads();
  for (int off = 128; off > 0; off >>= 1) {
    if (j < off) red[j] = fmaxf(red[j], red[j + off]);
    __syncthreads();
  }
  const float mx = red[0];
  __syncthreads();
  const float e = expf(s - mx);
  red[j] = e;
  __syncthreads();
  for (int off = 128; off > 0; off >>= 1) {
    if (j < off) red[j] += red[j + off];
    __syncthreads();
  }
  a2[((size_t)bh * M_ + i) * M_ + j] = e / red[0];
}

// ---------------- scale = max column-sum of |a2| (row-sums are exactly 1) ----------------
__global__ __launch_bounds__(256) void colmax_kernel(const float* __restrict__ a2,
                                                     unsigned int* __restrict__ scalebits) {
  const int bh = blockIdx.x, j = threadIdx.x;
  const float* mat = a2 + (size_t)bh * M_ * M_;
  float s = 0.f;
  for (int i = 0; i < M_; ++i) s += fabsf(mat[i * M_ + j]);
  __shared__ float red[256];
  red[j] = s;
  __syncthreads();
  for (int off = 128; off > 0; off >>= 1) {
    if (j < off) red[j] = fmaxf(red[j], red[j + off]);
    __syncthreads();
  }
  if (j == 0) atomicMax(scalebits, __float_as_uint(red[0]));  // positive floats: bit order ok
}

// ---------------- z0 = a2^T / scale ----------------
__global__ __launch_bounds__(256) void transpose_scale(const float* __restrict__ a2,
                                                       float* __restrict__ z0,
                                                       const unsigned int* __restrict__ scalebits) {
  const float inv = 1.0f / __uint_as_float(*scalebits);
  const int idx = blockIdx.x * 256 + threadIdx.x;
  const int j = idx & (M_ - 1), i = (idx >> 8) & (M_ - 1), bh = idx >> 16;
  z0[idx] = a2[((size_t)bh * M_ + j) * M_ + i] * inv;
}

// ---------------- batched 256x256x256: C = beta*D + gamma*(A@B) ----------------
__global__ __launch_bounds__(256) void gemm256(const float* __restrict__ A,
                                               const float* __restrict__ B,
                                               const float* __restrict__ D,
                                               float* __restrict__ C, float beta, float gamma) {
  const int m0 = (blockIdx.x >> 2) * 64, n0 = (blockIdx.x & 3) * 64;
  const size_t mo = (size_t)blockIdx.y * (M_ * M_);
  A += mo; B += mo; D += mo; C += mo;
  const int tid = threadIdx.x, tr = tid >> 4, tc = tid & 15;
  __shared__ float As[16][68], Bs[16][68];
  float acc[4][4] = {};
  for (int k0 = 0; k0 < M_; k0 += 16) {
    load_a_tile(A, M_, m0, k0, tid, As);
    load_b_nn(B, M_, k0, n0, tid, Bs);
    __syncthreads();
    mm_step(As, Bs, tr, tc, acc);
    __syncthreads();
  }
#pragma unroll
  for (int i = 0; i < 4; ++i) {
    const int row = m0 + tr * 4 + i;
    float4 o = make_float4(gamma * acc[i][0], gamma * acc[i][1], gamma * acc[i][2],
                           gamma * acc[i][3]);
    if (beta != 0.f) {
      const float4 d4 = *(const float4*)(D + (size_t)row * M_ + n0 + tc * 4);
      o.x += beta * d4.x; o.y += beta * d4.y; o.z += beta * d4.z; o.w += beta * d4.w;
    }
    *(float4*)(C + (size_t)row * M_ + n0 + tc * 4) = o;
  }
}

// ---------------- batched NT GEMM, K=64: C[m,n] = sum_d A[m,d] B[n,d] ----------------
__global__ __launch_bounds__(256) void gemm_nt64(const float* __restrict__ A, long long strideA,
                                                 const float* __restrict__ B, long long strideB,
                                                 float* __restrict__ C, long long strideC,
                                                 int ldc) {
  A += (size_t)blockIdx.z * strideA;
  B += (size_t)blockIdx.z * strideB;
  C += (size_t)blockIdx.z * strideC;
  const int m0 = blockIdx.x * 64, n0 = blockIdx.y * 64;
  const int tid = threadIdx.x, tr = tid >> 4, tc = tid & 15;
  __shared__ float As[16][68], Bs[16][68];
  float acc[4][4] = {};
#pragma unroll
  for (int k0 = 0; k0 < DH_; k0 += 16) {
    load_a_tile(A, DH_, m0, k0, tid, As);
    load_b_nt(B, DH_, k0, n0, tid, Bs);
    __syncthreads();
    mm_step(As, Bs, tr, tc, acc);
    __syncthreads();
  }
#pragma unroll
  for (int i = 0; i < 4; ++i) {
    const int row = m0 + tr * 4 + i;
    *(float4*)(C + (size_t)row * ldc + n0 + tc * 4) =
        make_float4(acc[i][0], acc[i][1], acc[i][2], acc[i][3]);
  }
}

// ---------------- generic in-place row softmax ----------------
__global__ __launch_bounds__(256) void softmax_rows(float* __restrict__ data, int rowlen) {
  float* row = data + (size_t)blockIdx.x * rowlen;
  const int tid = threadIdx.x;
  float mx = -3.0e38f;
  for (int c = tid; c < rowlen; c += 256) mx = fmaxf(mx, row[c]);
  __shared__ float red[256];
  red[tid] = mx;
  __syncthreads();
  for (int off = 128; off > 0; off >>= 1) {
    if (tid < off) red[tid] = fmaxf(red[tid], red[tid + off]);
    __syncthreads();
  }
  mx = red[0];
  __syncthreads();
  float s = 0.f;
  for (int c = tid; c < rowlen; c += 256) {
    const float e = expf(row[c] - mx);
    row[c] = e;
    s += e;
  }
  red[tid] = s;
  __syncthreads();
  for (int off = 128; off > 0; off >>= 1) {
    if (tid < off) red[tid] += red[tid + off];
    __syncthreads();
  }
  const float inv = 1.0f / red[0];
  for (int c = tid; c < rowlen; c += 256) row[c] *= inv;
}

// ---------------- batched NN GEMM, N=64, optional K-split (partials) ----------------
__global__ __launch_bounds__(256) void gemm_nn64(const float* __restrict__ A, int lda,
                                                 long long strideA,
                                                 const float* __restrict__ B, long long strideB,
                                                 float* __restrict__ C, long long strideC,
                                                 int kchunk) {
  const int ks = blockIdx.y, bz = blockIdx.z;
  A += (size_t)bz * strideA;
  B += (size_t)bz * strideB;
  C += (size_t)(ks * gridDim.z + bz) * strideC;
  const int m0 = blockIdx.x * 64;
  const int tid = threadIdx.x, tr = tid >> 4, tc = tid & 15;
  __shared__ float As[16][68], Bs[16][68];
  float acc[4][4] = {};
  const int kbase = ks * kchunk;
  for (int k0 = 0; k0 < kchunk; k0 += 16) {
    load_a_tile(A, lda, m0, kbase + k0, tid, As);
    load_b_nn(B, DH_, kbase + k0, 0, tid, Bs);
    __syncthreads();
    mm_step(As, Bs, tr, tc, acc);
    __syncthreads();
  }
#pragma unroll
  for (int i = 0; i < 4; ++i) {
    const int row = m0 + tr * 4 + i;
    *(float4*)(C + (size_t)row * DH_ + tc * 4) =
        make_float4(acc[i][0], acc[i][1], acc[i][2], acc[i][3]);
  }
}

// ---------------- sum K-split partials ----------------
__global__ __launch_bounds__(256) void reduce_part(const float* __restrict__ part,
                                                   float* __restrict__ out, int nsum, int per) {
  const int i = blockIdx.x * 256 + threadIdx.x;
  float s = 0.f;
  for (int t = 0; t < nsum; ++t) s += part[(size_t)t * per + i];
  out[i] = s;
}

// ---------------- out = a1 @ w2, scattered to (b, n, h*64+d) layout ----------------
__global__ __launch_bounds__(256) void gemm_a1w2(const float* __restrict__ A,
                                                 const float* __restrict__ W2,
                                                 float* __restrict__ om, int bh0) {
  const int lb = blockIdx.z, bh = bh0 + lb;
  A += (size_t)lb * ((size_t)N_ * M_);
  W2 += (size_t)lb * (M_ * DH_);
  const int m0 = blockIdx.x * 64;
  const int tid = threadIdx.x, tr = tid >> 4, tc = tid & 15;
  __shared__ float As[16][68], Bs[16][68];
  float acc[4][4] = {};
  for (int k0 = 0; k0 < M_; k0 += 16) {
    load_a_tile(A, M_, m0, k0, tid, As);
    load_b_nn(W2, DH_, k0, 0, tid, Bs);
    __syncthreads();
    mm_step(As, Bs, tr, tc, acc);
    __syncthreads();
  }
  const int b = bh >> 3, h = bh & 7;
#pragma unroll
  for (int i = 0; i < 4; ++i) {
    const int t = m0 + tr * 4 + i;
    *(float4*)(om + ((size_t)(b * N_ + t)) * DIM_ + h * DH_ + tc * 4) =
        make_float4(acc[i][0], acc[i][1], acc[i][2], acc[i][3]);
  }
}

// ---------------- residual depthwise conv over sequence axis (kernel 33) ----------------
__global__ __launch_bounds__(256) void conv_kernel(const float* __restrict__ v,
                                                   const float* __restrict__ rk,
                                                   float* __restrict__ om) {
  const int idx = blockIdx.x * 256 + threadIdx.x;
  const int d = idx & (DH_ - 1);
  const int t = (idx >> 6) & (N_ - 1);
  const int bh = idx >> 19;
  const int h = bh & 7, b = bh >> 3;
  const float* vb = v + ((size_t)bh * N_) * DH_ + d;
  float acc = 0.f;
#pragma unroll
  for (int s = 0; s < KC_; ++s) {
    const int tt = t + s - PADC_;
    if (tt >= 0 && tt < N_) acc = fmaf(rk[h * KC_ + s], vb[(size_t)tt * DH_], acc);
  }
  om[((size_t)(b * N_ + t)) * DIM_ + h * DH_ + d] += acc;
}

// ---------------- final: y = x + om @ w_out + b_out ----------------
__global__ __launch_bounds__(256) void final_gemm(const float* __restrict__ A,
                                                  const float* __restrict__ W,
                                                  const float* __restrict__ x,
                                                  const float* __restrict__ bout,
                                                  float* __restrict__ y) {
  const int m0 = blockIdx.x * 64, n0 = blockIdx.y * 64;
  const int tid = threadIdx.x, tr = tid >> 4, tc = tid & 15;
  __shared__ float As[16][68], Bs[16][68];
  float acc[4][4] = {};
  for (int k0 = 0; k0 < DIM_; k0 += 16) {
    load_a_tile(A, DIM_, m0, k0, tid, As);
    load_b_nn(W, DIM_, k0, n0, tid, Bs);
    __syncthreads();
    mm_step(As, Bs, tr, tc, acc);
    __syncthreads();
  }
  const float4 bo = *(const float4*)(bout + n0 + tc * 4);
#pragma unroll
  for (int i = 0; i < 4; ++i) {
    const int row = m0 + tr * 4 + i;
    const float4 xv = *(const float4*)(x + (size_t)row * DIM_ + n0 + tc * 4);
    *(float4*)(y + (size_t)row * DIM_ + n0 + tc * 4) =
        make_float4(acc[i][0] + xv.x + bo.x, acc[i][1] + xv.y + bo.y,
                    acc[i][2] + xv.z + bo.z, acc[i][3] + xv.w + bo.w);
  }
}

extern "C" void kernel_launch(void* const* d_in, const int* in_sizes, int n_in,
                              void* d_out, int out_size, void* d_ws, size_t ws_size,
                              hipStream_t stream) {
  (void)in_sizes; (void)n_in; (void)out_size;
  const float* x = (const float*)d_in[0];
  const float* gamma = (const float*)d_in[1];
  const float* beta = (const float*)d_in[2];
  const float* wqkv = (const float*)d_in[3];
  const float* wout = (const float*)d_in[4];
  const float* bout = (const float*)d_in[5];
  const float* rk = (const float*)d_in[6];
  float* y = (float*)d_out;
  float* ws = (float*)d_ws;

  size_t o = 0;
  float* xn = ws + o;  o += (size_t)2 * N_ * DIM_;      // 8,388,608 (reused as out_mat)
  float* q = ws + o;   o += (size_t)BH_ * N_ * DH_;     // 8,388,608
  float* k = ws + o;   o += (size_t)BH_ * N_ * DH_;
  float* v = ws + o;   o += (size_t)BH_ * N_ * DH_;
  float* ql = ws + o;  o += (size_t)BH_ * M_ * DH_;     // 262,144
  float* kl = ws + o;  o += (size_t)BH_ * M_ * DH_;
  float* a2 = ws + o;  o += (size_t)BH_ * M_ * M_;      // 1,048,576
  float* z0 = ws + o;  o += (size_t)BH_ * M_ * M_;
  float* z1 = ws + o;  o += (size_t)BH_ * M_ * M_;
  float* az = ws + o;  o += (size_t)BH_ * M_ * M_;
  float* t2 = ws + o;  o += (size_t)BH_ * M_ * M_;
  float* t4 = ws + o;  o += (size_t)BH_ * M_ * M_;
  float* a3v = ws + o; o += (size_t)BH_ * M_ * DH_;
  float* w2 = ws + o;  o += (size_t)BH_ * M_ * DH_;
  float* sim = ws + o; o += (size_t)4 * M_ * N_;        // 8,388,608: 4-head chunk
  float* part = ws + o; o += (size_t)32 * 4 * M_ * DH_; // 2,097,152
  unsigned int* scalebits = (unsigned int*)(ws + o); o += 16;
  if (ws_size < o * sizeof(float)) return;  // workspace too small: fail loudly via absmax

  float* om = xn;  // out_mat reuses xn (xn dead after qkv_gemm)

  hipMemsetAsync(scalebits, 0, 64, stream);
  ln_kernel<<<2 * N_, 128, 0, stream>>>(x, gamma, beta, xn);
  qkv_gemm<<<dim3(2 * N_ / 64, 24), 256, 0, stream>>>(xn, wqkv, q, k, v);
  landmark_kernel<<<BH_ * M_ * DH_ / 256, 256, 0, stream>>>(q, k, ql, kl);
  sim2_softmax<<<dim3(M_, BH_), 256, 0, stream>>>(ql, kl, a2);
  colmax_kernel<<<BH_, 256, 0, stream>>>(a2, scalebits);
  transpose_scale<<<BH_ * M_ * M_ / 256, 256, 0, stream>>>(a2, z0, scalebits);

  // Newton-Schulz: z' = 0.25 z (13I - az(15I - az(7I - az)))
  //   az = a@z; t2 = 7az - az@az; t4 = 15az - az@t2; z' = 3.25z - 0.25 z@t4
  for (int it = 0; it < 6; ++it) {
    float* zi = (it & 1) ? z1 : z0;
    float* zo = (it & 1) ? z0 : z1;
    gemm256<<<dim3(16, BH_), 256, 0, stream>>>(a2, zi, az, az, 0.f, 1.f);
    gemm256<<<dim3(16, BH_), 256, 0, stream>>>(az, az, az, t2, 7.f, -1.f);
    gemm256<<<dim3(16, BH_), 256, 0, stream>>>(az, t2, az, t4, 15.f, -1.f);
    gemm256<<<dim3(16, BH_), 256, 0, stream>>>(zi, t4, zi, zo, 3.25f, -0.25f);
  }
  // pinv result now in z0 (even number of iterations)

  // a3v[bh] = softmax(q_l @ k^T, axis=-1) @ v, chunked 4 heads at a time
  for (int g = 0; g < 4; ++g) {
    const float* qlg = ql + (size_t)g * 4 * M_ * DH_;
    const float* kg = k + (size_t)g * 4 * N_ * DH_;
    const float* vg = v + (size_t)g * 4 * N_ * DH_;
    gemm_nt64<<<dim3(M_ / 64, N_ / 64, 4), 256, 0, stream>>>(
        qlg, (long long)M_ * DH_, kg, (long long)N_ * DH_, sim, (long long)M_ * N_, N_);
    softmax_rows<<<4 * M_, 256, 0, stream>>>(sim, N_);
    gemm_nn64<<<dim3(M_ / 64, 32, 4), 256, 0, stream>>>(
        sim, N_, (long long)M_ * N_, vg, (long long)N_ * DH_, part, (long long)M_ * DH_, 256);
    reduce_part<<<4 * M_ * DH_ / 256, 256, 0, stream>>>(part, a3v + (size_t)g * 4 * M_ * DH_,
                                                        32, 4 * M_ * DH_);
  }
  // w2 = a2_inv @ a3v   (reassociated: out = a1 @ (a2_inv @ (a3 @ v)))
  gemm_nn64<<<dim3(M_ / 64, 1, BH_), 256, 0, stream>>>(
      z0, M_, (long long)M_ * M_, a3v, (long long)M_ * DH_, w2, (long long)M_ * DH_, M_);

  // out = softmax(q @ k_l^T, axis=-1) @ w2, chunked
  for (int g = 0; g < 4; ++g) {
    const float* qg = q + (size_t)g * 4 * N_ * DH_;
    const float* klg = kl + (size_t)g * 4 * M_ * DH_;
    gemm_nt64<<<dim3(N_ / 64, M_ / 64, 4), 256, 0, stream>>>(
        qg, (long long)N_ * DH_, klg, (long long)M_ * DH_, sim, (long long)N_ * M_, M_);
    softmax_rows<<<4 * N_, 256, 0, stream>>>(sim, M_);
    gemm_a1w2<<<dim3(N_ / 64, 1, 4), 256, 0, stream>>>(sim, w2 + (size_t)g * 4 * M_ * DH_,
                                                       om, g * 4);
  }
  conv_kernel<<<BH_ * N_ * DH_ / 256, 256, 0, stream>>>(v, rk, om);
  final_gemm<<<dim3(2 * N_ / 64, DIM_ / 64), 256, 0, stream>>>(om, wout, x, bout, y);
}

// Round 2
// 1463.507 us; speedup vs baseline: 1.2446x; 1.2446x over previous
//
#include <hip/hip_runtime.h>
#include <math.h>

#define H_ 8
#define DH_ 64
#define DIM_ 512
#define M_ 256
#define N_ 8192
#define BH_ 16
#define LG_ 32
#define KC_ 33
#define PADC_ 16

typedef __attribute__((ext_vector_type(8))) short bf16x8;
typedef __attribute__((ext_vector_type(4))) short s16x4;
typedef __attribute__((ext_vector_type(4))) float f32x4;

__device__ __forceinline__ short f2bf(float f) {
  unsigned u = __float_as_uint(f);
  unsigned r = (u + 0x7FFF + ((u >> 16) & 1)) >> 16;  // round-to-nearest-even
  return (short)r;
}

// =================== bf16 MFMA NT core: C(128x128) += A(Mx K) @ Bt(N x K)^T ===================
// A, Bt row-major bf16 (lda/ldb in elements, multiples of 8). K multiple of 32.
// LDS tiles [128][32] bf16, staged via global_load_lds width 16 (lane-contiguous).
__device__ __forceinline__ void mfma_nt_core(const short* __restrict__ A,
                                             const short* __restrict__ Bt, int K,
                                             int m0, int n0, size_t lda, size_t ldb,
                                             f32x4 acc[4][4], short* As, short* Bs) {
  const int tid = threadIdx.x;
  const int wave = tid >> 6, lane = tid & 63;
  const int wr = (wave >> 1) * 64, wc = (wave & 1) * 64;
  const int mi = lane & 15, quad = lane >> 4;
  for (int k0 = 0; k0 < K; k0 += 32) {
#pragma unroll
    for (int t = 0; t < 2; ++t) {
      const int cbase = (t * 4 + wave) * 64;   // wave-uniform chunk base
      const int chunk = cbase + lane;          // 16B chunk id in [0,512)
      const int row = chunk >> 2, cc = (chunk & 3) * 8;
      __builtin_amdgcn_global_load_lds(
          (const __attribute__((address_space(1))) void*)(A + (size_t)(m0 + row) * lda + k0 + cc),
          (__attribute__((address_space(3))) void*)(As + (size_t)cbase * 8), 16, 0, 0);
      __builtin_amdgcn_global_load_lds(
          (const __attribute__((address_space(1))) void*)(Bt + (size_t)(n0 + row) * ldb + k0 + cc),
          (__attribute__((address_space(3))) void*)(Bs + (size_t)cbase * 8), 16, 0, 0);
    }
    __syncthreads();
    bf16x8 af[4], bf[4];
#pragma unroll
    for (int i = 0; i < 4; ++i)
      af[i] = *(const bf16x8*)&As[(wr + i * 16 + mi) * 32 + quad * 8];
#pragma unroll
    for (int j = 0; j < 4; ++j)
      bf[j] = *(const bf16x8*)&Bs[(wc + j * 16 + mi) * 32 + quad * 8];
#pragma unroll
    for (int i = 0; i < 4; ++i)
#pragma unroll
      for (int j = 0; j < 4; ++j)
        acc[i][j] = __builtin_amdgcn_mfma_f32_16x16x32_bf16(af[i], bf[j], acc[i][j], 0, 0, 0);
    __syncthreads();
  }
}

// QKV: (16384x512)bf16 @ (1536x512)bf16^T, scatter to q/k/v (bh,n,d) fp32, q scaled
__global__ __launch_bounds__(256) void qkv_mfma(const short* __restrict__ xnb,
                                                const short* __restrict__ wt,
                                                float* __restrict__ q, float* __restrict__ k,
                                                float* __restrict__ v) {
  __shared__ short As[128 * 32], Bs[128 * 32];
  f32x4 acc[4][4] = {};
  const int m0 = blockIdx.x * 128, n0 = blockIdx.y * 128;
  mfma_nt_core(xnb, wt, DIM_, m0, n0, DIM_, DIM_, acc, As, Bs);
  const int wave = threadIdx.x >> 6, lane = threadIdx.x & 63;
  const int wr = (wave >> 1) * 64, wc = (wave & 1) * 64;
  const int mi = lane & 15, quad = lane >> 4;
  const int which = n0 >> 9;  // uniform per block (128 | 512)
  float* dst = which == 0 ? q : which == 1 ? k : v;
  const float sc = which == 0 ? 0.125f : 1.0f;  // DH^-0.5
#pragma unroll
  for (int j = 0; j < 4; ++j) {
    const int col = n0 + wc + j * 16 + mi;
    const int h = (col >> 6) & 7, d = col & 63;
#pragma unroll
    for (int i = 0; i < 4; ++i) {
#pragma unroll
      for (int r = 0; r < 4; ++r) {
        const int row = m0 + wr + i * 16 + quad * 4 + r;
        const int b = row >> 13, t = row & (N_ - 1);
        dst[((size_t)(b * H_ + h) * N_ + t) * DH_ + d] = acc[i][j][r] * sc;
      }
    }
  }
}

// final: y = x + omb @ woutt^T + b_out   (16384x512x512)
__global__ __launch_bounds__(256) void final_mfma(const short* __restrict__ omb,
                                                  const short* __restrict__ wt,
                                                  const float* __restrict__ x,
                                                  const float* __restrict__ bout,
                                                  float* __restrict__ y) {
  __shared__ short As[128 * 32], Bs[128 * 32];
  f32x4 acc[4][4] = {};
  const int m0 = blockIdx.x * 128, n0 = blockIdx.y * 128;
  mfma_nt_core(omb, wt, DIM_, m0, n0, DIM_, DIM_, acc, As, Bs);
  const int wave = threadIdx.x >> 6, lane = threadIdx.x & 63;
  const int wr = (wave >> 1) * 64, wc = (wave & 1) * 64;
  const int mi = lane & 15, quad = lane >> 4;
#pragma unroll
  for (int j = 0; j < 4; ++j) {
    const int col = n0 + wc + j * 16 + mi;
    const float bo = bout[col];
#pragma unroll
    for (int i = 0; i < 4; ++i) {
#pragma unroll
      for (int r = 0; r < 4; ++r) {
        const int row = m0 + wr + i * 16 + quad * 4 + r;
        y[(size_t)row * DIM_ + col] = acc[i][j][r] + x[(size_t)row * DIM_ + col] + bo;
      }
    }
  }
}

// fp32 (K x N) -> bf16 transposed (N x K), 32x32 LDS tiles
__global__ __launch_bounds__(256) void convt_kernel(const float* __restrict__ in,
                                                    short* __restrict__ out, int K, int N) {
  __shared__ float tile[32][33];
  const int n0 = blockIdx.x * 32, k0 = blockIdx.y * 32;
  const int tx = threadIdx.x & 31, ty = threadIdx.x >> 5;
  for (int r = ty; r < 32; r += 8) tile[r][tx] = in[(size_t)(k0 + r) * N + n0 + tx];
  __syncthreads();
  for (int r = ty; r < 32; r += 8) out[(size_t)(n0 + r) * K + k0 + tx] = f2bf(tile[tx][r]);
}

// fp32 -> bf16 (flat, 4 elems/thread)
__global__ __launch_bounds__(256) void cvt_bf16(const float* __restrict__ in,
                                                short* __restrict__ out) {
  const int i = blockIdx.x * 256 + threadIdx.x;
  const float4 f = ((const float4*)in)[i];
  s16x4 o = {f2bf(f.x), f2bf(f.y), f2bf(f.z), f2bf(f.w)};
  *(s16x4*)(out + (size_t)i * 4) = o;
}

// ---------------- fp32 64x64 tile core (for the remaining small/medium GEMMs) ----------------
__device__ __forceinline__ void mm_step(float (*As)[68], float (*Bs)[68],
                                        int tr, int tc, float acc[4][4]) {
#pragma unroll
  for (int kk = 0; kk < 16; ++kk) {
    const float4 a4 = *(const float4*)&As[kk][tr * 4];
    const float4 b4 = *(const float4*)&Bs[kk][tc * 4];
    const float a[4] = {a4.x, a4.y, a4.z, a4.w};
    const float b[4] = {b4.x, b4.y, b4.z, b4.w};
#pragma unroll
    for (int i = 0; i < 4; ++i) {
#pragma unroll
      for (int j = 0; j < 4; ++j) acc[i][j] = fmaf(a[i], b[j], acc[i][j]);
    }
  }
}

__device__ __forceinline__ void load_a_tile(const float* A, int lda, int m0, int k0,
                                            int tid, float (*As)[68]) {
  const int r = tid >> 2, kq = tid & 3;
  const float4 a4 = *(const float4*)(A + (size_t)(m0 + r) * lda + k0 + kq * 4);
  As[kq * 4 + 0][r] = a4.x;
  As[kq * 4 + 1][r] = a4.y;
  As[kq * 4 + 2][r] = a4.z;
  As[kq * 4 + 3][r] = a4.w;
}

__device__ __forceinline__ void load_b_nn(const float* B, int ldb, int k0, int n0,
                                          int tid, float (*Bs)[68]) {
  const int kr = tid >> 4, c4 = tid & 15;
  const float4 b4 = *(const float4*)(B + (size_t)(k0 + kr) * ldb + n0 + c4 * 4);
  *(float4*)&Bs[kr][c4 * 4] = b4;
}

__device__ __forceinline__ void load_b_nt(const float* B, int ldb, int k0, int n0,
                                          int tid, float (*Bs)[68]) {
  const int j = tid >> 2, kq = tid & 3;
  const float4 b4 = *(const float4*)(B + (size_t)(n0 + j) * ldb + k0 + kq * 4);
  Bs[kq * 4 + 0][j] = b4.x;
  Bs[kq * 4 + 1][j] = b4.y;
  Bs[kq * 4 + 2][j] = b4.z;
  Bs[kq * 4 + 3][j] = b4.w;
}

// ---------------- LayerNorm -> bf16 activations ----------------
__global__ __launch_bounds__(128) void ln_kernel(const float* __restrict__ x,
                                                 const float* __restrict__ gamma,
                                                 const float* __restrict__ beta,
                                                 short* __restrict__ xnb) {
  const int row = blockIdx.x, tid = threadIdx.x;
  const float4 v = ((const float4*)(x + (size_t)row * DIM_))[tid];
  float s = v.x + v.y + v.z + v.w;
  float ss = v.x * v.x + v.y * v.y + v.z * v.z + v.w * v.w;
  __shared__ float r1[128], r2[128];
  r1[tid] = s;
  r2[tid] = ss;
  __syncthreads();
  for (int off = 64; off > 0; off >>= 1) {
    if (tid < off) {
      r1[tid] += r1[tid + off];
      r2[tid] += r2[tid + off];
    }
    __syncthreads();
  }
  const float mu = r1[0] * (1.0f / DIM_);
  const float var = r2[0] * (1.0f / DIM_) - mu * mu;
  const float rs = rsqrtf(var + 1e-5f);
  const float4 g = ((const float4*)gamma)[tid];
  const float4 bb = ((const float4*)beta)[tid];
  s16x4 o = {f2bf((v.x - mu) * rs * g.x + bb.x), f2bf((v.y - mu) * rs * g.y + bb.y),
             f2bf((v.z - mu) * rs * g.z + bb.z), f2bf((v.w - mu) * rs * g.w + bb.w)};
  ((s16x4*)(xnb + (size_t)row * DIM_))[tid] = o;
}

// ---------------- landmarks ----------------
__global__ __launch_bounds__(256) void landmark_kernel(const float* __restrict__ q,
                                                       const float* __restrict__ k,
                                                       float* __restrict__ ql,
                                                       float* __restrict__ kl) {
  const int idx = blockIdx.x * 256 + threadIdx.x;
  const int d = idx & (DH_ - 1);
  const int m = (idx >> 6) & (M_ - 1);
  const int bh = idx >> 14;
  const size_t base = ((size_t)bh * N_ + m * LG_) * DH_ + d;
  float sq = 0.f, sk = 0.f;
#pragma unroll 8
  for (int t = 0; t < LG_; ++t) {
    sq += q[base + (size_t)t * DH_];
    sk += k[base + (size_t)t * DH_];
  }
  ql[idx] = sq * (1.0f / LG_);
  kl[idx] = sk * (1.0f / LG_);
}

// ---------------- sim2 + softmax ----------------
__global__ __launch_bounds__(256) void sim2_softmax(const float* __restrict__ ql,
                                                    const float* __restrict__ kl,
                                                    float* __restrict__ a2) {
  const int i = blockIdx.x, bh = blockIdx.y, j = threadIdx.x;
  __shared__ float qrow[DH_];
  if (j < DH_) qrow[j] = ql[((size_t)bh * M_ + i) * DH_ + j];
  __syncthreads();
  const float* kr = kl + ((size_t)bh * M_ + j) * DH_;
  float s = 0.f;
#pragma unroll 16
  for (int d = 0; d < DH_; ++d) s += qrow[d] * kr[d];
  __shared__ float red[256];
  red[j] = s;
  __syncthreads();
  for (int off = 128; off > 0; off >>= 1) {
    if (j < off) red[j] = fmaxf(red[j], red[j + off]);
    __syncthreads();
  }
  const float mx = red[0];
  __syncthreads();
  const float e = expf(s - mx);
  red[j] = e;
  __syncthreads();
  for (int off = 128; off > 0; off >>= 1) {
    if (j < off) red[j] += red[j + off];
    __syncthreads();
  }
  a2[((size_t)bh * M_ + i) * M_ + j] = e / red[0];
}

// ---------------- max column-sum (row-sums are exactly 1) ----------------
__global__ __launch_bounds__(256) void colmax_kernel(const float* __restrict__ a2,
                                                     unsigned int* __restrict__ scalebits) {
  const int bh = blockIdx.x, j = threadIdx.x;
  const float* mat = a2 + (size_t)bh * M_ * M_;
  float s = 0.f;
  for (int i = 0; i < M_; ++i) s += fabsf(mat[i * M_ + j]);
  __shared__ float red[256];
  red[j] = s;
  __syncthreads();
  for (int off = 128; off > 0; off >>= 1) {
    if (j < off) red[j] = fmaxf(red[j], red[j + off]);
    __syncthreads();
  }
  if (j == 0) atomicMax(scalebits, __float_as_uint(red[0]));
}

__global__ __launch_bounds__(256) void transpose_scale(const float* __restrict__ a2,
                                                       float* __restrict__ z0,
                                                       const unsigned int* __restrict__ scalebits) {
  const float inv = 1.0f / __uint_as_float(*scalebits);
  const int idx = blockIdx.x * 256 + threadIdx.x;
  const int j = idx & (M_ - 1), i = (idx >> 8) & (M_ - 1), bh = idx >> 16;
  z0[idx] = a2[((size_t)bh * M_ + j) * M_ + i] * inv;
}

// ---------------- batched 256x256x256: C = beta*D + gamma*(A@B) ----------------
__global__ __launch_bounds__(256) void gemm256(const float* __restrict__ A,
                                               const float* __restrict__ B,
                                               const float* __restrict__ D,
                                               float* __restrict__ C, float beta, float gamma) {
  const int m0 = (blockIdx.x >> 2) * 64, n0 = (blockIdx.x & 3) * 64;
  const size_t mo = (size_t)blockIdx.y * (M_ * M_);
  A += mo; B += mo; D += mo; C += mo;
  const int tid = threadIdx.x, tr = tid >> 4, tc = tid & 15;
  __shared__ float As[16][68], Bs[16][68];
  float acc[4][4] = {};
  for (int k0 = 0; k0 < M_; k0 += 16) {
    load_a_tile(A, M_, m0, k0, tid, As);
    load_b_nn(B, M_, k0, n0, tid, Bs);
    __syncthreads();
    mm_step(As, Bs, tr, tc, acc);
    __syncthreads();
  }
#pragma unroll
  for (int i = 0; i < 4; ++i) {
    const int row = m0 + tr * 4 + i;
    float4 o = make_float4(gamma * acc[i][0], gamma * acc[i][1], gamma * acc[i][2],
                           gamma * acc[i][3]);
    if (beta != 0.f) {
      const float4 d4 = *(const float4*)(D + (size_t)row * M_ + n0 + tc * 4);
      o.x += beta * d4.x; o.y += beta * d4.y; o.z += beta * d4.z; o.w += beta * d4.w;
    }
    *(float4*)(C + (size_t)row * M_ + n0 + tc * 4) = o;
  }
}

// ---------------- batched NT GEMM, K=64 ----------------
__global__ __launch_bounds__(256) void gemm_nt64(const float* __restrict__ A, long long strideA,
                                                 const float* __restrict__ B, long long strideB,
                                                 float* __restrict__ C, long long strideC,
                                                 int ldc) {
  A += (size_t)blockIdx.z * strideA;
  B += (size_t)blockIdx.z * strideB;
  C += (size_t)blockIdx.z * strideC;
  const int m0 = blockIdx.x * 64, n0 = blockIdx.y * 64;
  const int tid = threadIdx.x, tr = tid >> 4, tc = tid & 15;
  __shared__ float As[16][68], Bs[16][68];
  float acc[4][4] = {};
#pragma unroll
  for (int k0 = 0; k0 < DH_; k0 += 16) {
    load_a_tile(A, DH_, m0, k0, tid, As);
    load_b_nt(B, DH_, k0, n0, tid, Bs);
    __syncthreads();
    mm_step(As, Bs, tr, tc, acc);
    __syncthreads();
  }
#pragma unroll
  for (int i = 0; i < 4; ++i) {
    const int row = m0 + tr * 4 + i;
    *(float4*)(C + (size_t)row * ldc + n0 + tc * 4) =
        make_float4(acc[i][0], acc[i][1], acc[i][2], acc[i][3]);
  }
}

// ---------------- in-place row softmax ----------------
__global__ __launch_bounds__(256) void softmax_rows(float* __restrict__ data, int rowlen) {
  float* row = data + (size_t)blockIdx.x * rowlen;
  const int tid = threadIdx.x;
  float mx = -3.0e38f;
  for (int c = tid; c < rowlen; c += 256) mx = fmaxf(mx, row[c]);
  __shared__ float red[256];
  red[tid] = mx;
  __syncthreads();
  for (int off = 128; off > 0; off >>= 1) {
    if (tid < off) red[tid] = fmaxf(red[tid], red[tid + off]);
    __syncthreads();
  }
  mx = red[0];
  __syncthreads();
  float s = 0.f;
  for (int c = tid; c < rowlen; c += 256) {
    const float e = expf(row[c] - mx);
    row[c] = e;
    s += e;
  }
  red[tid] = s;
  __syncthreads();
  for (int off = 128; off > 0; off >>= 1) {
    if (tid < off) red[tid] += red[tid + off];
    __syncthreads();
  }
  const float inv = 1.0f / red[0];
  for (int c = tid; c < rowlen; c += 256) row[c] *= inv;
}

// ---------------- batched NN GEMM, N=64, K-split ----------------
__global__ __launch_bounds__(256) void gemm_nn64(const float* __restrict__ A, int lda,
                                                 long long strideA,
                                                 const float* __restrict__ B, long long strideB,
                                                 float* __restrict__ C, long long strideC,
                                                 int kchunk) {
  const int ks = blockIdx.y, bz = blockIdx.z;
  A += (size_t)bz * strideA;
  B += (size_t)bz * strideB;
  C += (size_t)(ks * gridDim.z + bz) * strideC;
  const int m0 = blockIdx.x * 64;
  const int tid = threadIdx.x, tr = tid >> 4, tc = tid & 15;
  __shared__ float As[16][68], Bs[16][68];
  float acc[4][4] = {};
  const int kbase = ks * kchunk;
  for (int k0 = 0; k0 < kchunk; k0 += 16) {
    load_a_tile(A, lda, m0, kbase + k0, tid, As);
    load_b_nn(B, DH_, kbase + k0, 0, tid, Bs);
    __syncthreads();
    mm_step(As, Bs, tr, tc, acc);
    __syncthreads();
  }
#pragma unroll
  for (int i = 0; i < 4; ++i) {
    const int row = m0 + tr * 4 + i;
    *(float4*)(C + (size_t)row * DH_ + tc * 4) =
        make_float4(acc[i][0], acc[i][1], acc[i][2], acc[i][3]);
  }
}

__global__ __launch_bounds__(256) void reduce_part(const float* __restrict__ part,
                                                   float* __restrict__ out, int nsum, int per) {
  const int i = blockIdx.x * 256 + threadIdx.x;
  float s = 0.f;
  for (int t = 0; t < nsum; ++t) s += part[(size_t)t * per + i];
  out[i] = s;
}

// ---------------- out = a1 @ w2, scatter to (b,n,dim) ----------------
__global__ __launch_bounds__(256) void gemm_a1w2(const float* __restrict__ A,
                                                 const float* __restrict__ W2,
                                                 float* __restrict__ om, int bh0) {
  const int lb = blockIdx.z, bh = bh0 + lb;
  A += (size_t)lb * ((size_t)N_ * M_);
  W2 += (size_t)lb * (M_ * DH_);
  const int m0 = blockIdx.x * 64;
  const int tid = threadIdx.x, tr = tid >> 4, tc = tid & 15;
  __shared__ float As[16][68], Bs[16][68];
  float acc[4][4] = {};
  for (int k0 = 0; k0 < M_; k0 += 16) {
    load_a_tile(A, M_, m0, k0, tid, As);
    load_b_nn(W2, DH_, k0, 0, tid, Bs);
    __syncthreads();
    mm_step(As, Bs, tr, tc, acc);
    __syncthreads();
  }
  const int b = bh >> 3, h = bh & 7;
#pragma unroll
  for (int i = 0; i < 4; ++i) {
    const int t = m0 + tr * 4 + i;
    *(float4*)(om + ((size_t)(b * N_ + t)) * DIM_ + h * DH_ + tc * 4) =
        make_float4(acc[i][0], acc[i][1], acc[i][2], acc[i][3]);
  }
}

// ---------------- residual depthwise conv ----------------
__global__ __launch_bounds__(256) void conv_kernel(const float* __restrict__ v,
                                                   const float* __restrict__ rk,
                                                   float* __restrict__ om) {
  const int idx = blockIdx.x * 256 + threadIdx.x;
  const int d = idx & (DH_ - 1);
  const int t = (idx >> 6) & (N_ - 1);
  const int bh = idx >> 19;
  const int h = bh & 7, b = bh >> 3;
  const float* vb = v + ((size_t)bh * N_) * DH_ + d;
  float acc = 0.f;
#pragma unroll
  for (int s = 0; s < KC_; ++s) {
    const int tt = t + s - PADC_;
    if (tt >= 0 && tt < N_) acc = fmaf(rk[h * KC_ + s], vb[(size_t)tt * DH_], acc);
  }
  om[((size_t)(b * N_ + t)) * DIM_ + h * DH_ + d] += acc;
}

extern "C" void kernel_launch(void* const* d_in, const int* in_sizes, int n_in,
                              void* d_out, int out_size, void* d_ws, size_t ws_size,
                              hipStream_t stream) {
  (void)in_sizes; (void)n_in; (void)out_size;
  const float* x = (const float*)d_in[0];
  const float* gamma = (const float*)d_in[1];
  const float* beta = (const float*)d_in[2];
  const float* wqkv = (const float*)d_in[3];
  const float* wout = (const float*)d_in[4];
  const float* bout = (const float*)d_in[5];
  const float* rk = (const float*)d_in[6];
  float* y = (float*)d_out;
  float* ws = (float*)d_ws;

  size_t o = 0;
  float* om = ws + o;  o += (size_t)2 * N_ * DIM_;      // fp32 out_mat (pre-projection)
  float* q = ws + o;   o += (size_t)BH_ * N_ * DH_;
  float* k = ws + o;   o += (size_t)BH_ * N_ * DH_;
  float* v = ws + o;   o += (size_t)BH_ * N_ * DH_;
  float* ql = ws + o;  o += (size_t)BH_ * M_ * DH_;
  float* kl = ws + o;  o += (size_t)BH_ * M_ * DH_;
  float* a2 = ws + o;  o += (size_t)BH_ * M_ * M_;
  float* z0 = ws + o;  o += (size_t)BH_ * M_ * M_;
  float* z1 = ws + o;  o += (size_t)BH_ * M_ * M_;
  float* az = ws + o;  o += (size_t)BH_ * M_ * M_;
  float* t2 = ws + o;  o += (size_t)BH_ * M_ * M_;
  float* t4 = ws + o;  o += (size_t)BH_ * M_ * M_;
  float* a3v = ws + o; o += (size_t)BH_ * M_ * DH_;
  float* w2 = ws + o;  o += (size_t)BH_ * M_ * DH_;
  float* sim = ws + o; o += (size_t)4 * M_ * N_;        // 4-head chunk of sim
  float* part = ws + o; o += (size_t)32 * 4 * M_ * DH_;
  unsigned int* scalebits = (unsigned int*)(ws + o); o += 16;
  if (ws_size < o * sizeof(float)) return;

  // bf16 temporaries overlap dead regions:
  short* xnb = (short*)sim;    // live: ln -> qkv (sim unused until a3 chain)
  short* wqkvt = (short*)part; // live: convt -> qkv (part unused until a3 chain)
  short* omb = (short*)sim;    // live: after a1 chain (sim dead)
  short* woutt = (short*)part; // live: after a3 chain (part dead)

  hipMemsetAsync(scalebits, 0, 64, stream);
  ln_kernel<<<2 * N_, 128, 0, stream>>>(x, gamma, beta, xnb);
  convt_kernel<<<dim3(3 * DIM_ / 32, DIM_ / 32), 256, 0, stream>>>(wqkv, wqkvt, DIM_, 3 * DIM_);
  qkv_mfma<<<dim3(2 * N_ / 128, 3 * DIM_ / 128), 256, 0, stream>>>(xnb, wqkvt, q, k, v);

  landmark_kernel<<<BH_ * M_ * DH_ / 256, 256, 0, stream>>>(q, k, ql, kl);
  sim2_softmax<<<dim3(M_, BH_), 256, 0, stream>>>(ql, kl, a2);
  colmax_kernel<<<BH_, 256, 0, stream>>>(a2, scalebits);
  transpose_scale<<<BH_ * M_ * M_ / 256, 256, 0, stream>>>(a2, z0, scalebits);

  // Newton-Schulz pinv (fp32)
  for (int it = 0; it < 6; ++it) {
    float* zi = (it & 1) ? z1 : z0;
    float* zo = (it & 1) ? z0 : z1;
    gemm256<<<dim3(16, BH_), 256, 0, stream>>>(a2, zi, az, az, 0.f, 1.f);
    gemm256<<<dim3(16, BH_), 256, 0, stream>>>(az, az, az, t2, 7.f, -1.f);
    gemm256<<<dim3(16, BH_), 256, 0, stream>>>(az, t2, az, t4, 15.f, -1.f);
    gemm256<<<dim3(16, BH_), 256, 0, stream>>>(zi, t4, zi, zo, 3.25f, -0.25f);
  }

  // a3v = softmax(q_l @ k^T) @ v, chunked 4 heads
  for (int g = 0; g < 4; ++g) {
    const float* qlg = ql + (size_t)g * 4 * M_ * DH_;
    const float* kg = k + (size_t)g * 4 * N_ * DH_;
    const float* vg = v + (size_t)g * 4 * N_ * DH_;
    gemm_nt64<<<dim3(M_ / 64, N_ / 64, 4), 256, 0, stream>>>(
        qlg, (long long)M_ * DH_, kg, (long long)N_ * DH_, sim, (long long)M_ * N_, N_);
    softmax_rows<<<4 * M_, 256, 0, stream>>>(sim, N_);
    gemm_nn64<<<dim3(M_ / 64, 32, 4), 256, 0, stream>>>(
        sim, N_, (long long)M_ * N_, vg, (long long)N_ * DH_, part, (long long)M_ * DH_, 256);
    reduce_part<<<4 * M_ * DH_ / 256, 256, 0, stream>>>(part, a3v + (size_t)g * 4 * M_ * DH_,
                                                        32, 4 * M_ * DH_);
  }
  // w2 = a2_inv @ a3v
  gemm_nn64<<<dim3(M_ / 64, 1, BH_), 256, 0, stream>>>(
      z0, M_, (long long)M_ * M_, a3v, (long long)M_ * DH_, w2, (long long)M_ * DH_, M_);

  // out = softmax(q @ k_l^T) @ w2, chunked
  for (int g = 0; g < 4; ++g) {
    const float* qg = q + (size_t)g * 4 * N_ * DH_;
    const float* klg = kl + (size_t)g * 4 * M_ * DH_;
    gemm_nt64<<<dim3(N_ / 64, M_ / 64, 4), 256, 0, stream>>>(
        qg, (long long)N_ * DH_, klg, (long long)M_ * DH_, sim, (long long)N_ * M_, M_);
    softmax_rows<<<4 * N_, 256, 0, stream>>>(sim, M_);
    gemm_a1w2<<<dim3(N_ / 64, 1, 4), 256, 0, stream>>>(sim, w2 + (size_t)g * 4 * M_ * DH_,
                                                       om, g * 4);
  }
  conv_kernel<<<BH_ * N_ * DH_ / 256, 256, 0, stream>>>(v, rk, om);

  cvt_bf16<<<2 * N_ * DIM_ / 1024, 256, 0, stream>>>(om, omb);
  convt_kernel<<<dim3(DIM_ / 32, DIM_ / 32), 256, 0, stream>>>(wout, woutt, DIM_, DIM_);
  final_mfma<<<dim3(2 * N_ / 128, DIM_ / 128), 256, 0, stream>>>(omb, woutt, x, bout, y);
}

// Round 3
// 776.603 us; speedup vs baseline: 2.3454x; 1.8845x over previous
//
#include <hip/hip_runtime.h>
#include <math.h>

#define H_ 8
#define DH_ 64
#define DIM_ 512
#define M_ 256
#define N_ 8192
#define BH_ 16
#define LG_ 32
#define KC_ 33
#define PADC_ 16

typedef __attribute__((ext_vector_type(8))) short bf16x8;
typedef __attribute__((ext_vector_type(4))) short s16x4;
typedef __attribute__((ext_vector_type(4))) float f32x4;

__device__ __forceinline__ short f2bf(float f) {
  unsigned u = __float_as_uint(f);
  unsigned r = (u + 0x7FFF + ((u >> 16) & 1)) >> 16;  // RNE
  return (short)r;
}
__device__ __forceinline__ float bf2f(short s) {
  return __uint_as_float(((unsigned)(unsigned short)s) << 16);
}

// =================== bf16 MFMA NT core (128x128 tile) ===================
__device__ __forceinline__ void mfma_nt_core(const short* __restrict__ A,
                                             const short* __restrict__ Bt, int K,
                                             int m0, int n0, size_t lda, size_t ldb,
                                             f32x4 acc[4][4], short* As, short* Bs) {
  const int tid = threadIdx.x;
  const int wave = tid >> 6, lane = tid & 63;
  const int wr = (wave >> 1) * 64, wc = (wave & 1) * 64;
  const int mi = lane & 15, quad = lane >> 4;
  for (int k0 = 0; k0 < K; k0 += 32) {
#pragma unroll
    for (int t = 0; t < 2; ++t) {
      const int cbase = (t * 4 + wave) * 64;
      const int chunk = cbase + lane;
      const int row = chunk >> 2, cc = (chunk & 3) * 8;
      __builtin_amdgcn_global_load_lds(
          (const __attribute__((address_space(1))) void*)(A + (size_t)(m0 + row) * lda + k0 + cc),
          (__attribute__((address_space(3))) void*)(As + (size_t)cbase * 8), 16, 0, 0);
      __builtin_amdgcn_global_load_lds(
          (const __attribute__((address_space(1))) void*)(Bt + (size_t)(n0 + row) * ldb + k0 + cc),
          (__attribute__((address_space(3))) void*)(Bs + (size_t)cbase * 8), 16, 0, 0);
    }
    __syncthreads();
    bf16x8 af[4], bf[4];
#pragma unroll
    for (int i = 0; i < 4; ++i)
      af[i] = *(const bf16x8*)&As[(wr + i * 16 + mi) * 32 + quad * 8];
#pragma unroll
    for (int j = 0; j < 4; ++j)
      bf[j] = *(const bf16x8*)&Bs[(wc + j * 16 + mi) * 32 + quad * 8];
#pragma unroll
    for (int i = 0; i < 4; ++i)
#pragma unroll
      for (int j = 0; j < 4; ++j)
        acc[i][j] = __builtin_amdgcn_mfma_f32_16x16x32_bf16(af[i], bf[j], acc[i][j], 0, 0, 0);
    __syncthreads();
  }
}

// QKV: (16384x512)bf16 @ (1536x512)^T, scatter bf16 q/k/v (bh,n,d), q scaled
__global__ __launch_bounds__(256) void qkv_mfma(const short* __restrict__ xnb,
                                                const short* __restrict__ wt,
                                                short* __restrict__ qb, short* __restrict__ kb,
                                                short* __restrict__ vb) {
  __shared__ short As[128 * 32], Bs[128 * 32];
  f32x4 acc[4][4] = {};
  const int m0 = blockIdx.x * 128, n0 = blockIdx.y * 128;
  mfma_nt_core(xnb, wt, DIM_, m0, n0, DIM_, DIM_, acc, As, Bs);
  const int wave = threadIdx.x >> 6, lane = threadIdx.x & 63;
  const int wr = (wave >> 1) * 64, wc = (wave & 1) * 64;
  const int mi = lane & 15, quad = lane >> 4;
  const int which = n0 >> 9;
  short* dst = which == 0 ? qb : which == 1 ? kb : vb;
  const float sc = which == 0 ? 0.125f : 1.0f;
#pragma unroll
  for (int j = 0; j < 4; ++j) {
    const int col = n0 + wc + j * 16 + mi;
    const int h = (col >> 6) & 7, d = col & 63;
#pragma unroll
    for (int i = 0; i < 4; ++i) {
#pragma unroll
      for (int r = 0; r < 4; ++r) {
        const int row = m0 + wr + i * 16 + quad * 4 + r;
        const int b = row >> 13, t = row & (N_ - 1);
        dst[((size_t)(b * H_ + h) * N_ + t) * DH_ + d] = f2bf(acc[i][j][r] * sc);
      }
    }
  }
}

// final: y = x + omb @ woutt^T + b_out
__global__ __launch_bounds__(256) void final_mfma(const short* __restrict__ omb,
                                                  const short* __restrict__ wt,
                                                  const float* __restrict__ x,
                                                  const float* __restrict__ bout,
                                                  float* __restrict__ y) {
  __shared__ short As[128 * 32], Bs[128 * 32];
  f32x4 acc[4][4] = {};
  const int m0 = blockIdx.x * 128, n0 = blockIdx.y * 128;
  mfma_nt_core(omb, wt, DIM_, m0, n0, DIM_, DIM_, acc, As, Bs);
  const int wave = threadIdx.x >> 6, lane = threadIdx.x & 63;
  const int wr = (wave >> 1) * 64, wc = (wave & 1) * 64;
  const int mi = lane & 15, quad = lane >> 4;
#pragma unroll
  for (int j = 0; j < 4; ++j) {
    const int col = n0 + wc + j * 16 + mi;
    const float bo = bout[col];
#pragma unroll
    for (int i = 0; i < 4; ++i) {
#pragma unroll
      for (int r = 0; r < 4; ++r) {
        const int row = m0 + wr + i * 16 + quad * 4 + r;
        y[(size_t)row * DIM_ + col] = acc[i][j][r] + x[(size_t)row * DIM_ + col] + bo;
      }
    }
  }
}

// fp32 (K x N) -> bf16 transposed (N x K)
__global__ __launch_bounds__(256) void convt_kernel(const float* __restrict__ in,
                                                    short* __restrict__ out, int K, int N) {
  __shared__ float tile[32][33];
  const int n0 = blockIdx.x * 32, k0 = blockIdx.y * 32;
  const int tx = threadIdx.x & 31, ty = threadIdx.x >> 5;
  for (int r = ty; r < 32; r += 8) tile[r][tx] = in[(size_t)(k0 + r) * N + n0 + tx];
  __syncthreads();
  for (int r = ty; r < 32; r += 8) out[(size_t)(n0 + r) * K + k0 + tx] = f2bf(tile[tx][r]);
}

// ---------------- LayerNorm -> bf16 ----------------
__global__ __launch_bounds__(128) void ln_kernel(const float* __restrict__ x,
                                                 const float* __restrict__ gamma,
                                                 const float* __restrict__ beta,
                                                 short* __restrict__ xnb) {
  const int row = blockIdx.x, tid = threadIdx.x;
  const float4 v = ((const float4*)(x + (size_t)row * DIM_))[tid];
  float s = v.x + v.y + v.z + v.w;
  float ss = v.x * v.x + v.y * v.y + v.z * v.z + v.w * v.w;
  __shared__ float r1[128], r2[128];
  r1[tid] = s;
  r2[tid] = ss;
  __syncthreads();
  for (int off = 64; off > 0; off >>= 1) {
    if (tid < off) {
      r1[tid] += r1[tid + off];
      r2[tid] += r2[tid + off];
    }
    __syncthreads();
  }
  const float mu = r1[0] * (1.0f / DIM_);
  const float var = r2[0] * (1.0f / DIM_) - mu * mu;
  const float rs = rsqrtf(var + 1e-5f);
  const float4 g = ((const float4*)gamma)[tid];
  const float4 bb = ((const float4*)beta)[tid];
  s16x4 o = {f2bf((v.x - mu) * rs * g.x + bb.x), f2bf((v.y - mu) * rs * g.y + bb.y),
             f2bf((v.z - mu) * rs * g.z + bb.z), f2bf((v.w - mu) * rs * g.w + bb.w)};
  ((s16x4*)(xnb + (size_t)row * DIM_))[tid] = o;
}

// ---------------- landmarks: fp32 + bf16 outputs ----------------
__global__ __launch_bounds__(256) void landmark_kernel(const short* __restrict__ qb,
                                                       const short* __restrict__ kb,
                                                       float* __restrict__ ql,
                                                       float* __restrict__ kl,
                                                       short* __restrict__ qlb,
                                                       short* __restrict__ klb) {
  const int idx = blockIdx.x * 256 + threadIdx.x;
  const int d = idx & (DH_ - 1);
  const int m = (idx >> 6) & (M_ - 1);
  const int bh = idx >> 14;
  const size_t base = ((size_t)bh * N_ + m * LG_) * DH_ + d;
  float sq = 0.f, sk = 0.f;
#pragma unroll 8
  for (int t = 0; t < LG_; ++t) {
    sq += bf2f(qb[base + (size_t)t * DH_]);
    sk += bf2f(kb[base + (size_t)t * DH_]);
  }
  sq *= (1.0f / LG_);
  sk *= (1.0f / LG_);
  ql[idx] = sq;
  kl[idx] = sk;
  qlb[idx] = f2bf(sq);
  klb[idx] = f2bf(sk);
}

// ---------------- sim2 + softmax (fp32, feeds pinv) ----------------
__global__ __launch_bounds__(256) void sim2_softmax(const float* __restrict__ ql,
                                                    const float* __restrict__ kl,
                                                    float* __restrict__ a2) {
  const int i = blockIdx.x, bh = blockIdx.y, j = threadIdx.x;
  __shared__ float qrow[DH_];
  if (j < DH_) qrow[j] = ql[((size_t)bh * M_ + i) * DH_ + j];
  __syncthreads();
  const float* kr = kl + ((size_t)bh * M_ + j) * DH_;
  float s = 0.f;
#pragma unroll 16
  for (int d = 0; d < DH_; ++d) s += qrow[d] * kr[d];
  __shared__ float red[256];
  red[j] = s;
  __syncthreads();
  for (int off = 128; off > 0; off >>= 1) {
    if (j < off) red[j] = fmaxf(red[j], red[j + off]);
    __syncthreads();
  }
  const float mx = red[0];
  __syncthreads();
  const float e = expf(s - mx);
  red[j] = e;
  __syncthreads();
  for (int off = 128; off > 0; off >>= 1) {
    if (j < off) red[j] += red[j + off];
    __syncthreads();
  }
  a2[((size_t)bh * M_ + i) * M_ + j] = e / red[0];
}

__global__ __launch_bounds__(256) void colmax_kernel(const float* __restrict__ a2,
                                                     unsigned int* __restrict__ scalebits) {
  const int bh = blockIdx.x, j = threadIdx.x;
  const float* mat = a2 + (size_t)bh * M_ * M_;
  float s = 0.f;
  for (int i = 0; i < M_; ++i) s += fabsf(mat[i * M_ + j]);
  __shared__ float red[256];
  red[j] = s;
  __syncthreads();
  for (int off = 128; off > 0; off >>= 1) {
    if (j < off) red[j] = fmaxf(red[j], red[j + off]);
    __syncthreads();
  }
  if (j == 0) atomicMax(scalebits, __float_as_uint(red[0]));
}

__global__ __launch_bounds__(256) void transpose_scale(const float* __restrict__ a2,
                                                       float* __restrict__ z0,
                                                       const unsigned int* __restrict__ scalebits) {
  const float inv = 1.0f / __uint_as_float(*scalebits);
  const int idx = blockIdx.x * 256 + threadIdx.x;
  const int j = idx & (M_ - 1), i = (idx >> 8) & (M_ - 1), bh = idx >> 16;
  z0[idx] = a2[((size_t)bh * M_ + j) * M_ + i] * inv;
}

// ---------------- fp32 64x64 tile core (pinv + w2) ----------------
__device__ __forceinline__ void mm_step(float (*As)[68], float (*Bs)[68],
                                        int tr, int tc, float acc[4][4]) {
#pragma unroll
  for (int kk = 0; kk < 16; ++kk) {
    const float4 a4 = *(const float4*)&As[kk][tr * 4];
    const float4 b4 = *(const float4*)&Bs[kk][tc * 4];
    const float a[4] = {a4.x, a4.y, a4.z, a4.w};
    const float b[4] = {b4.x, b4.y, b4.z, b4.w};
#pragma unroll
    for (int i = 0; i < 4; ++i)
#pragma unroll
      for (int j = 0; j < 4; ++j) acc[i][j] = fmaf(a[i], b[j], acc[i][j]);
  }
}

__device__ __forceinline__ void load_a_tile(const float* A, int lda, int m0, int k0,
                                            int tid, float (*As)[68]) {
  const int r = tid >> 2, kq = tid & 3;
  const float4 a4 = *(const float4*)(A + (size_t)(m0 + r) * lda + k0 + kq * 4);
  As[kq * 4 + 0][r] = a4.x;
  As[kq * 4 + 1][r] = a4.y;
  As[kq * 4 + 2][r] = a4.z;
  As[kq * 4 + 3][r] = a4.w;
}

__device__ __forceinline__ void load_b_nn(const float* B, int ldb, int k0, int n0,
                                          int tid, float (*Bs)[68]) {
  const int kr = tid >> 4, c4 = tid & 15;
  const float4 b4 = *(const float4*)(B + (size_t)(k0 + kr) * ldb + n0 + c4 * 4);
  *(float4*)&Bs[kr][c4 * 4] = b4;
}

__global__ __launch_bounds__(256) void gemm256(const float* __restrict__ A,
                                               const float* __restrict__ B,
                                               const float* __restrict__ D,
                                               float* __restrict__ C, float beta, float gamma) {
  const int m0 = (blockIdx.x >> 2) * 64, n0 = (blockIdx.x & 3) * 64;
  const size_t mo = (size_t)blockIdx.y * (M_ * M_);
  A += mo; B += mo; D += mo; C += mo;
  const int tid = threadIdx.x, tr = tid >> 4, tc = tid & 15;
  __shared__ float As[16][68], Bs[16][68];
  float acc[4][4] = {};
  for (int k0 = 0; k0 < M_; k0 += 16) {
    load_a_tile(A, M_, m0, k0, tid, As);
    load_b_nn(B, M_, k0, n0, tid, Bs);
    __syncthreads();
    mm_step(As, Bs, tr, tc, acc);
    __syncthreads();
  }
#pragma unroll
  for (int i = 0; i < 4; ++i) {
    const int row = m0 + tr * 4 + i;
    float4 o = make_float4(gamma * acc[i][0], gamma * acc[i][1], gamma * acc[i][2],
                           gamma * acc[i][3]);
    if (beta != 0.f) {
      const float4 d4 = *(const float4*)(D + (size_t)row * M_ + n0 + tc * 4);
      o.x += beta * d4.x; o.y += beta * d4.y; o.z += beta * d4.z; o.w += beta * d4.w;
    }
    *(float4*)(C + (size_t)row * M_ + n0 + tc * 4) = o;
  }
}

__global__ __launch_bounds__(256) void gemm_nn64(const float* __restrict__ A, int lda,
                                                 long long strideA,
                                                 const float* __restrict__ B, long long strideB,
                                                 float* __restrict__ C, long long strideC,
                                                 int kchunk) {
  const int bz = blockIdx.z;
  A += (size_t)bz * strideA;
  B += (size_t)bz * strideB;
  C += (size_t)bz * strideC;
  const int m0 = blockIdx.x * 64;
  const int tid = threadIdx.x, tr = tid >> 4, tc = tid & 15;
  __shared__ float As[16][68], Bs[16][68];
  float acc[4][4] = {};
  for (int k0 = 0; k0 < kchunk; k0 += 16) {
    load_a_tile(A, lda, m0, k0, tid, As);
    load_b_nn(B, DH_, k0, 0, tid, Bs);
    __syncthreads();
    mm_step(As, Bs, tr, tc, acc);
    __syncthreads();
  }
#pragma unroll
  for (int i = 0; i < 4; ++i) {
    const int row = m0 + tr * 4 + i;
    *(float4*)(C + (size_t)row * DH_ + tc * 4) =
        make_float4(acc[i][0], acc[i][1], acc[i][2], acc[i][3]);
  }
}

// ---------------- a3 flash: Opart[chunk] = exp(q_l @ k^T - m) @ v over 1024-chunks ----------------
__global__ __launch_bounds__(256) void a3_flash(const short* __restrict__ qlb,
                                                const short* __restrict__ kb,
                                                const short* __restrict__ vb,
                                                float* __restrict__ Opart,
                                                float* __restrict__ mpart,
                                                float* __restrict__ lpart) {
  const int chunk = blockIdx.x, rt = blockIdx.y, bh = blockIdx.z;
  __shared__ short qs[64 * 80], ks[64 * 80], vts[64 * 80], ps[64 * 80];
  const int tid = threadIdx.x, wave = tid >> 6, lane = tid & 63;
  const int mi = lane & 15, quad = lane >> 4;
#pragma unroll
  for (int i = 0; i < 2; ++i) {
    const int c = tid * 2 + i, row = c >> 3, col = (c & 7) * 8;
    *(bf16x8*)&qs[row * 80 + col] =
        *(const bf16x8*)(qlb + ((size_t)bh * M_ + rt * 64 + row) * DH_ + col);
  }
  __syncthreads();
  const bf16x8 aq0 = *(const bf16x8*)&qs[(wave * 16 + mi) * 80 + quad * 8];
  const bf16x8 aq1 = *(const bf16x8*)&qs[(wave * 16 + mi) * 80 + 32 + quad * 8];
  float m[4] = {-INFINITY, -INFINITY, -INFINITY, -INFINITY};
  float l[4] = {0.f, 0.f, 0.f, 0.f};
  f32x4 o[4] = {};
  for (int t = 0; t < 16; ++t) {
    const int n0 = chunk * 1024 + t * 64;
#pragma unroll
    for (int i = 0; i < 2; ++i) {
      const int c = tid * 2 + i, row = c >> 3, col = (c & 7) * 8;
      *(bf16x8*)&ks[row * 80 + col] =
          *(const bf16x8*)(kb + ((size_t)bh * N_ + n0 + row) * DH_ + col);
      const bf16x8 vv = *(const bf16x8*)(vb + ((size_t)bh * N_ + n0 + row) * DH_ + col);
#pragma unroll
      for (int e = 0; e < 8; ++e) vts[(col + e) * 80 + row] = vv[e];
    }
    __syncthreads();
    f32x4 s[4];
#pragma unroll
    for (int j = 0; j < 4; ++j) {
      const bf16x8 b0 = *(const bf16x8*)&ks[(j * 16 + mi) * 80 + quad * 8];
      const bf16x8 b1 = *(const bf16x8*)&ks[(j * 16 + mi) * 80 + 32 + quad * 8];
      f32x4 z = {0.f, 0.f, 0.f, 0.f};
      z = __builtin_amdgcn_mfma_f32_16x16x32_bf16(aq0, b0, z, 0, 0, 0);
      s[j] = __builtin_amdgcn_mfma_f32_16x16x32_bf16(aq1, b1, z, 0, 0, 0);
    }
    float alpha[4];
#pragma unroll
    for (int r = 0; r < 4; ++r) {
      float v = fmaxf(fmaxf(s[0][r], s[1][r]), fmaxf(s[2][r], s[3][r]));
      v = fmaxf(v, __shfl_xor(v, 1, 64));
      v = fmaxf(v, __shfl_xor(v, 2, 64));
      v = fmaxf(v, __shfl_xor(v, 4, 64));
      v = fmaxf(v, __shfl_xor(v, 8, 64));
      const float mnew = fmaxf(m[r], v);
      alpha[r] = __expf(m[r] - mnew);
      m[r] = mnew;
    }
    float rs[4] = {0.f, 0.f, 0.f, 0.f};
#pragma unroll
    for (int j = 0; j < 4; ++j)
#pragma unroll
      for (int r = 0; r < 4; ++r) {
        const float p = __expf(s[j][r] - m[r]);
        rs[r] += p;
        ps[(wave * 16 + quad * 4 + r) * 80 + j * 16 + mi] = f2bf(p);
      }
#pragma unroll
    for (int r = 0; r < 4; ++r) {
      float v = rs[r];
      v += __shfl_xor(v, 1, 64);
      v += __shfl_xor(v, 2, 64);
      v += __shfl_xor(v, 4, 64);
      v += __shfl_xor(v, 8, 64);
      l[r] = l[r] * alpha[r] + v;
#pragma unroll
      for (int j = 0; j < 4; ++j) o[j][r] *= alpha[r];
    }
    __syncthreads();
    const bf16x8 ap0 = *(const bf16x8*)&ps[(wave * 16 + mi) * 80 + quad * 8];
    const bf16x8 ap1 = *(const bf16x8*)&ps[(wave * 16 + mi) * 80 + 32 + quad * 8];
#pragma unroll
    for (int j = 0; j < 4; ++j) {
      const bf16x8 b0 = *(const bf16x8*)&vts[(j * 16 + mi) * 80 + quad * 8];
      const bf16x8 b1 = *(const bf16x8*)&vts[(j * 16 + mi) * 80 + 32 + quad * 8];
      o[j] = __builtin_amdgcn_mfma_f32_16x16x32_bf16(ap0, b0, o[j], 0, 0, 0);
      o[j] = __builtin_amdgcn_mfma_f32_16x16x32_bf16(ap1, b1, o[j], 0, 0, 0);
    }
    __syncthreads();
  }
  const int p2 = bh * 4 + rt;
  float* Ob = Opart + ((size_t)chunk * 64 + p2) * 4096;
#pragma unroll
  for (int j = 0; j < 4; ++j)
#pragma unroll
    for (int r = 0; r < 4; ++r)
      Ob[(wave * 16 + quad * 4 + r) * 64 + j * 16 + mi] = o[j][r];
  if (mi == 0) {
#pragma unroll
    for (int r = 0; r < 4; ++r) {
      mpart[((size_t)chunk * 64 + p2) * 64 + wave * 16 + quad * 4 + r] = m[r];
      lpart[((size_t)chunk * 64 + p2) * 64 + wave * 16 + quad * 4 + r] = l[r];
    }
  }
}

__global__ __launch_bounds__(256) void a3_combine(const float* __restrict__ Opart,
                                                  const float* __restrict__ mpart,
                                                  const float* __restrict__ lpart,
                                                  float* __restrict__ a3v) {
  const int p2 = blockIdx.x;
  const int bh = p2 >> 2, rt = p2 & 3;
  __shared__ float wgt[8][64];
  const int tid = threadIdx.x;
  if (tid < 64) {
    float mg = -INFINITY;
    for (int c = 0; c < 8; ++c) mg = fmaxf(mg, mpart[((size_t)c * 64 + p2) * 64 + tid]);
    float e[8], lg = 0.f;
    for (int c = 0; c < 8; ++c) {
      e[c] = __expf(mpart[((size_t)c * 64 + p2) * 64 + tid] - mg);
      lg += lpart[((size_t)c * 64 + p2) * 64 + tid] * e[c];
    }
    const float inv = 1.f / lg;
    for (int c = 0; c < 8; ++c) wgt[c][tid] = e[c] * inv;
  }
  __syncthreads();
  for (int i = tid; i < 4096; i += 256) {
    const int row = i >> 6, d = i & 63;
    float s = 0.f;
    for (int c = 0; c < 8; ++c) s += Opart[((size_t)c * 64 + p2) * 4096 + i] * wgt[c][row];
    a3v[((size_t)bh * M_ + rt * 64 + row) * DH_ + d] = s;
  }
}

// ---------------- w2 (fp32, 256x64) -> w2t bf16 (64x256) per bh ----------------
__global__ __launch_bounds__(256) void w2t_kernel(const float* __restrict__ w2,
                                                  short* __restrict__ w2tb) {
  const int bh = blockIdx.x, tid = threadIdx.x;
  for (int i = tid; i < M_ * DH_; i += 256) {
    const int r = i >> 6, d = i & 63;
    w2tb[((size_t)bh * DH_ + d) * M_ + r] = f2bf(w2[(size_t)bh * M_ * DH_ + i]);
  }
}

// ---------------- a1 fused: omb = softmax(q @ kl^T) @ w2 + conv(v), bf16 out ----------------
__global__ __launch_bounds__(256) void a1_conv(const short* __restrict__ qb,
                                               const short* __restrict__ klb,
                                               const short* __restrict__ w2tb,
                                               const short* __restrict__ vb,
                                               const float* __restrict__ rk,
                                               short* __restrict__ omb) {
  __shared__ char smem[51456];
  short* qs = (short*)smem;                 // [64][80]  phase A
  short* kls = (short*)(smem + 10240);      // [256][80] phase A
  short* ps = (short*)smem;                 // [64][264] phase B
  short* vcs = (short*)(smem + 33792);      // [96][88]  phase B
  float* rkl = (float*)(smem + 50688);      // [33]
  const int bh = blockIdx.y, t0 = blockIdx.x * 64;
  const int b = bh >> 3, h = bh & 7;
  const int tid = threadIdx.x, wave = tid >> 6, lane = tid & 63;
  const int mi = lane & 15, quad = lane >> 4;
#pragma unroll
  for (int i = 0; i < 2; ++i) {
    const int c = tid * 2 + i, row = c >> 3, col = (c & 7) * 8;
    *(bf16x8*)&qs[row * 80 + col] =
        *(const bf16x8*)(qb + ((size_t)bh * N_ + t0 + row) * DH_ + col);
  }
#pragma unroll
  for (int i = 0; i < 8; ++i) {
    const int c = tid + i * 256, row = c >> 3, col = (c & 7) * 8;
    *(bf16x8*)&kls[row * 80 + col] =
        *(const bf16x8*)(klb + ((size_t)bh * M_ + row) * DH_ + col);
  }
  __syncthreads();
  const bf16x8 aq0 = *(const bf16x8*)&qs[(wave * 16 + mi) * 80 + quad * 8];
  const bf16x8 aq1 = *(const bf16x8*)&qs[(wave * 16 + mi) * 80 + 32 + quad * 8];
  f32x4 s[16];
#pragma unroll
  for (int f = 0; f < 16; ++f) {
    const bf16x8 b0 = *(const bf16x8*)&kls[(f * 16 + mi) * 80 + quad * 8];
    const bf16x8 b1 = *(const bf16x8*)&kls[(f * 16 + mi) * 80 + 32 + quad * 8];
    f32x4 z = {0.f, 0.f, 0.f, 0.f};
    z = __builtin_amdgcn_mfma_f32_16x16x32_bf16(aq0, b0, z, 0, 0, 0);
    s[f] = __builtin_amdgcn_mfma_f32_16x16x32_bf16(aq1, b1, z, 0, 0, 0);
  }
  float inv[4];
#pragma unroll
  for (int r = 0; r < 4; ++r) {
    float v = s[0][r];
#pragma unroll
    for (int f = 1; f < 16; ++f) v = fmaxf(v, s[f][r]);
    v = fmaxf(v, __shfl_xor(v, 1, 64));
    v = fmaxf(v, __shfl_xor(v, 2, 64));
    v = fmaxf(v, __shfl_xor(v, 4, 64));
    v = fmaxf(v, __shfl_xor(v, 8, 64));
    float sum = 0.f;
#pragma unroll
    for (int f = 0; f < 16; ++f) {
      const float p = __expf(s[f][r] - v);
      s[f][r] = p;
      sum += p;
    }
    sum += __shfl_xor(sum, 1, 64);
    sum += __shfl_xor(sum, 2, 64);
    sum += __shfl_xor(sum, 4, 64);
    sum += __shfl_xor(sum, 8, 64);
    inv[r] = 1.f / sum;
  }
  __syncthreads();  // everyone done reading qs/kls before ps/vcs overwrite
#pragma unroll
  for (int f = 0; f < 16; ++f)
#pragma unroll
    for (int r = 0; r < 4; ++r)
      ps[(wave * 16 + quad * 4 + r) * 264 + f * 16 + mi] = f2bf(s[f][r] * inv[r]);
#pragma unroll
  for (int i = 0; i < 3; ++i) {
    const int c = tid + i * 256, row = c >> 3, col = (c & 7) * 8;
    const int g = t0 - 16 + row;
    bf16x8 vv;
    if (g >= 0 && g < N_) {
      vv = *(const bf16x8*)(vb + ((size_t)bh * N_ + g) * DH_ + col);
    } else {
#pragma unroll
      for (int e = 0; e < 8; ++e) vv[e] = 0;
    }
    *(bf16x8*)&vcs[row * 88 + col] = vv;
  }
  if (tid < KC_) rkl[tid] = rk[h * KC_ + tid];
  __syncthreads();
  f32x4 o[4] = {};
#pragma unroll
  for (int k0 = 0; k0 < 8; ++k0) {
    const bf16x8 ap = *(const bf16x8*)&ps[(wave * 16 + mi) * 264 + k0 * 32 + quad * 8];
#pragma unroll
    for (int j = 0; j < 4; ++j) {
      const bf16x8 bw =
          *(const bf16x8*)(w2tb + ((size_t)bh * DH_ + j * 16 + mi) * M_ + k0 * 32 + quad * 8);
      o[j] = __builtin_amdgcn_mfma_f32_16x16x32_bf16(ap, bw, o[j], 0, 0, 0);
    }
  }
  const int r0 = wave * 16 + quad * 4;
#pragma unroll
  for (int j = 0; j < 4; ++j) {
    const int d = j * 16 + mi;
    float w[36];
#pragma unroll
    for (int e = 0; e < 36; ++e) w[e] = bf2f(vcs[(r0 + e) * 88 + d]);
#pragma unroll
    for (int r = 0; r < 4; ++r) {
      float acc = o[j][r];
#pragma unroll
      for (int ss = 0; ss < KC_; ++ss) acc = fmaf(rkl[ss], w[r + ss], acc);
      const int t = t0 + r0 + r;
      omb[((size_t)(b * N_ + t)) * DIM_ + h * DH_ + d] = f2bf(acc);
    }
  }
}

extern "C" void kernel_launch(void* const* d_in, const int* in_sizes, int n_in,
                              void* d_out, int out_size, void* d_ws, size_t ws_size,
                              hipStream_t stream) {
  (void)in_sizes; (void)n_in; (void)out_size;
  const float* x = (const float*)d_in[0];
  const float* gamma = (const float*)d_in[1];
  const float* beta = (const float*)d_in[2];
  const float* wqkv = (const float*)d_in[3];
  const float* wout = (const float*)d_in[4];
  const float* bout = (const float*)d_in[5];
  const float* rk = (const float*)d_in[6];
  float* y = (float*)d_out;
  float* ws = (float*)d_ws;

  size_t o = 0;
  short* xnb = (short*)(ws + o);   o += (size_t)2 * N_ * DIM_ / 2;        // 4,194,304
  short* wqkvt = (short*)(ws + o); o += (size_t)3 * DIM_ * DIM_ / 2;      //   393,216
  short* woutt = (short*)(ws + o); o += (size_t)DIM_ * DIM_ / 2;          //   131,072
  short* qb = (short*)(ws + o);    o += (size_t)BH_ * N_ * DH_ / 2;       // 4,194,304
  short* kb = (short*)(ws + o);    o += (size_t)BH_ * N_ * DH_ / 2;
  short* vb = (short*)(ws + o);    o += (size_t)BH_ * N_ * DH_ / 2;
  float* ql = ws + o;  o += (size_t)BH_ * M_ * DH_;                       //   262,144
  float* kl = ws + o;  o += (size_t)BH_ * M_ * DH_;
  short* qlb = (short*)(ws + o); o += (size_t)BH_ * M_ * DH_ / 2;         //   131,072
  short* klb = (short*)(ws + o); o += (size_t)BH_ * M_ * DH_ / 2;
  float* a2 = ws + o;  o += (size_t)BH_ * M_ * M_;                        // 1,048,576
  float* z0 = ws + o;  o += (size_t)BH_ * M_ * M_;
  float* z1 = ws + o;  o += (size_t)BH_ * M_ * M_;
  float* az = ws + o;  o += (size_t)BH_ * M_ * M_;
  float* t2 = ws + o;  o += (size_t)BH_ * M_ * M_;
  float* t4 = ws + o;  o += (size_t)BH_ * M_ * M_;
  float* Opart = ws + o; o += (size_t)8 * 64 * 4096;                      // 2,097,152
  float* mpart = ws + o; o += (size_t)8 * 64 * 64;                        //    32,768
  float* lpart = ws + o; o += (size_t)8 * 64 * 64;
  float* a3v = ws + o; o += (size_t)BH_ * M_ * DH_;
  float* w2 = ws + o;  o += (size_t)BH_ * M_ * DH_;
  short* w2tb = (short*)(ws + o); o += (size_t)BH_ * M_ * DH_ / 2;
  short* omb = (short*)(ws + o);  o += (size_t)2 * N_ * DIM_ / 2;         // 4,194,304
  unsigned int* scalebits = (unsigned int*)(ws + o); o += 16;
  if (ws_size < o * sizeof(float)) return;

  hipMemsetAsync(scalebits, 0, 64, stream);
  ln_kernel<<<2 * N_, 128, 0, stream>>>(x, gamma, beta, xnb);
  convt_kernel<<<dim3(3 * DIM_ / 32, DIM_ / 32), 256, 0, stream>>>(wqkv, wqkvt, DIM_, 3 * DIM_);
  convt_kernel<<<dim3(DIM_ / 32, DIM_ / 32), 256, 0, stream>>>(wout, woutt, DIM_, DIM_);
  qkv_mfma<<<dim3(2 * N_ / 128, 3 * DIM_ / 128), 256, 0, stream>>>(xnb, wqkvt, qb, kb, vb);

  landmark_kernel<<<BH_ * M_ * DH_ / 256, 256, 0, stream>>>(qb, kb, ql, kl, qlb, klb);
  sim2_softmax<<<dim3(M_, BH_), 256, 0, stream>>>(ql, kl, a2);
  colmax_kernel<<<BH_, 256, 0, stream>>>(a2, scalebits);
  transpose_scale<<<BH_ * M_ * M_ / 256, 256, 0, stream>>>(a2, z0, scalebits);

  // a3 flash (independent of pinv)
  a3_flash<<<dim3(8, 4, BH_), 256, 0, stream>>>(qlb, kb, vb, Opart, mpart, lpart);
  a3_combine<<<64, 256, 0, stream>>>(Opart, mpart, lpart, a3v);

  // Newton-Schulz pinv (fp32)
  for (int it = 0; it < 6; ++it) {
    float* zi = (it & 1) ? z1 : z0;
    float* zo = (it & 1) ? z0 : z1;
    gemm256<<<dim3(16, BH_), 256, 0, stream>>>(a2, zi, az, az, 0.f, 1.f);
    gemm256<<<dim3(16, BH_), 256, 0, stream>>>(az, az, az, t2, 7.f, -1.f);
    gemm256<<<dim3(16, BH_), 256, 0, stream>>>(az, t2, az, t4, 15.f, -1.f);
    gemm256<<<dim3(16, BH_), 256, 0, stream>>>(zi, t4, zi, zo, 3.25f, -0.25f);
  }

  // w2 = z0 @ a3v ; transpose to bf16
  gemm_nn64<<<dim3(M_ / 64, 1, BH_), 256, 0, stream>>>(
      z0, M_, (long long)M_ * M_, a3v, (long long)M_ * DH_, w2, (long long)M_ * DH_, M_);
  w2t_kernel<<<BH_, 256, 0, stream>>>(w2, w2tb);

  // fused a1 @ w2 + depthwise conv -> omb bf16
  a1_conv<<<dim3(N_ / 64, BH_), 256, 0, stream>>>(qb, klb, w2tb, vb, rk, omb);

  final_mfma<<<dim3(2 * N_ / 128, DIM_ / 128), 256, 0, stream>>>(omb, woutt, x, bout, y);
}

// Round 4
// 604.899 us; speedup vs baseline: 3.0111x; 1.2839x over previous
//
#include <hip/hip_runtime.h>
#include <math.h>

#define H_ 8
#define DH_ 64
#define DIM_ 512
#define M_ 256
#define N_ 8192
#define BH_ 16
#define LG_ 32
#define KC_ 33
#define PADC_ 16

typedef __attribute__((ext_vector_type(8))) short bf16x8;
typedef __attribute__((ext_vector_type(4))) short s16x4;
typedef __attribute__((ext_vector_type(4))) float f32x4;

__device__ __forceinline__ short f2bf(float f) {
  unsigned u = __float_as_uint(f);
  unsigned r = (u + 0x7FFF + ((u >> 16) & 1)) >> 16;  // RNE
  return (short)r;
}
__device__ __forceinline__ float bf2f(short s) {
  return __uint_as_float(((unsigned)(unsigned short)s) << 16);
}

// =================== bf16 MFMA NT core (128x128 tile) ===================
__device__ __forceinline__ void mfma_nt_core(const short* __restrict__ A,
                                             const short* __restrict__ Bt, int K,
                                             int m0, int n0, size_t lda, size_t ldb,
                                             f32x4 acc[4][4], short* As, short* Bs) {
  const int tid = threadIdx.x;
  const int wave = tid >> 6, lane = tid & 63;
  const int wr = (wave >> 1) * 64, wc = (wave & 1) * 64;
  const int mi = lane & 15, quad = lane >> 4;
  for (int k0 = 0; k0 < K; k0 += 32) {
#pragma unroll
    for (int t = 0; t < 2; ++t) {
      const int cbase = (t * 4 + wave) * 64;
      const int chunk = cbase + lane;
      const int row = chunk >> 2, cc = (chunk & 3) * 8;
      __builtin_amdgcn_global_load_lds(
          (const __attribute__((address_space(1))) void*)(A + (size_t)(m0 + row) * lda + k0 + cc),
          (__attribute__((address_space(3))) void*)(As + (size_t)cbase * 8), 16, 0, 0);
      __builtin_amdgcn_global_load_lds(
          (const __attribute__((address_space(1))) void*)(Bt + (size_t)(n0 + row) * ldb + k0 + cc),
          (__attribute__((address_space(3))) void*)(Bs + (size_t)cbase * 8), 16, 0, 0);
    }
    __syncthreads();
    bf16x8 af[4], bf[4];
#pragma unroll
    for (int i = 0; i < 4; ++i)
      af[i] = *(const bf16x8*)&As[(wr + i * 16 + mi) * 32 + quad * 8];
#pragma unroll
    for (int j = 0; j < 4; ++j)
      bf[j] = *(const bf16x8*)&Bs[(wc + j * 16 + mi) * 32 + quad * 8];
#pragma unroll
    for (int i = 0; i < 4; ++i)
#pragma unroll
      for (int j = 0; j < 4; ++j)
        acc[i][j] = __builtin_amdgcn_mfma_f32_16x16x32_bf16(af[i], bf[j], acc[i][j], 0, 0, 0);
    __syncthreads();
  }
}

// QKV GEMM -> bf16 q/k/v (bh,n,d), q scaled
__global__ __launch_bounds__(256) void qkv_mfma(const short* __restrict__ xnb,
                                                const short* __restrict__ wt,
                                                short* __restrict__ qb, short* __restrict__ kb,
                                                short* __restrict__ vb) {
  __shared__ short As[128 * 32], Bs[128 * 32];
  f32x4 acc[4][4] = {};
  const int m0 = blockIdx.x * 128, n0 = blockIdx.y * 128;
  mfma_nt_core(xnb, wt, DIM_, m0, n0, DIM_, DIM_, acc, As, Bs);
  const int wave = threadIdx.x >> 6, lane = threadIdx.x & 63;
  const int wr = (wave >> 1) * 64, wc = (wave & 1) * 64;
  const int mi = lane & 15, quad = lane >> 4;
  const int which = n0 >> 9;
  short* dst = which == 0 ? qb : which == 1 ? kb : vb;
  const float sc = which == 0 ? 0.125f : 1.0f;
#pragma unroll
  for (int j = 0; j < 4; ++j) {
    const int col = n0 + wc + j * 16 + mi;
    const int h = (col >> 6) & 7, d = col & 63;
#pragma unroll
    for (int i = 0; i < 4; ++i) {
#pragma unroll
      for (int r = 0; r < 4; ++r) {
        const int row = m0 + wr + i * 16 + quad * 4 + r;
        const int b = row >> 13, t = row & (N_ - 1);
        dst[((size_t)(b * H_ + h) * N_ + t) * DH_ + d] = f2bf(acc[i][j][r] * sc);
      }
    }
  }
}

// final: y = x + omb @ woutt^T + b_out
__global__ __launch_bounds__(256) void final_mfma(const short* __restrict__ omb,
                                                  const short* __restrict__ wt,
                                                  const float* __restrict__ x,
                                                  const float* __restrict__ bout,
                                                  float* __restrict__ y) {
  __shared__ short As[128 * 32], Bs[128 * 32];
  f32x4 acc[4][4] = {};
  const int m0 = blockIdx.x * 128, n0 = blockIdx.y * 128;
  mfma_nt_core(omb, wt, DIM_, m0, n0, DIM_, DIM_, acc, As, Bs);
  const int wave = threadIdx.x >> 6, lane = threadIdx.x & 63;
  const int wr = (wave >> 1) * 64, wc = (wave & 1) * 64;
  const int mi = lane & 15, quad = lane >> 4;
#pragma unroll
  for (int j = 0; j < 4; ++j) {
    const int col = n0 + wc + j * 16 + mi;
    const float bo = bout[col];
#pragma unroll
    for (int i = 0; i < 4; ++i) {
#pragma unroll
      for (int r = 0; r < 4; ++r) {
        const int row = m0 + wr + i * 16 + quad * 4 + r;
        y[(size_t)row * DIM_ + col] = acc[i][j][r] + x[(size_t)row * DIM_ + col] + bo;
      }
    }
  }
}

// fp32 (K x N) -> bf16 transposed (N x K)
__global__ __launch_bounds__(256) void convt_kernel(const float* __restrict__ in,
                                                    short* __restrict__ out, int K, int N) {
  __shared__ float tile[32][33];
  const int n0 = blockIdx.x * 32, k0 = blockIdx.y * 32;
  const int tx = threadIdx.x & 31, ty = threadIdx.x >> 5;
  for (int r = ty; r < 32; r += 8) tile[r][tx] = in[(size_t)(k0 + r) * N + n0 + tx];
  __syncthreads();
  for (int r = ty; r < 32; r += 8) out[(size_t)(n0 + r) * K + k0 + tx] = f2bf(tile[tx][r]);
}

// ---------------- LayerNorm -> bf16 ----------------
__global__ __launch_bounds__(128) void ln_kernel(const float* __restrict__ x,
                                                 const float* __restrict__ gamma,
                                                 const float* __restrict__ beta,
                                                 short* __restrict__ xnb) {
  const int row = blockIdx.x, tid = threadIdx.x;
  const float4 v = ((const float4*)(x + (size_t)row * DIM_))[tid];
  float s = v.x + v.y + v.z + v.w;
  float ss = v.x * v.x + v.y * v.y + v.z * v.z + v.w * v.w;
  __shared__ float r1[128], r2[128];
  r1[tid] = s;
  r2[tid] = ss;
  __syncthreads();
  for (int off = 64; off > 0; off >>= 1) {
    if (tid < off) {
      r1[tid] += r1[tid + off];
      r2[tid] += r2[tid + off];
    }
    __syncthreads();
  }
  const float mu = r1[0] * (1.0f / DIM_);
  const float var = r2[0] * (1.0f / DIM_) - mu * mu;
  const float rs = rsqrtf(var + 1e-5f);
  const float4 g = ((const float4*)gamma)[tid];
  const float4 bb = ((const float4*)beta)[tid];
  s16x4 o = {f2bf((v.x - mu) * rs * g.x + bb.x), f2bf((v.y - mu) * rs * g.y + bb.y),
             f2bf((v.z - mu) * rs * g.z + bb.z), f2bf((v.w - mu) * rs * g.w + bb.w)};
  ((s16x4*)(xnb + (size_t)row * DIM_))[tid] = o;
}

// ---------------- landmarks ----------------
__global__ __launch_bounds__(256) void landmark_kernel(const short* __restrict__ qb,
                                                       const short* __restrict__ kb,
                                                       float* __restrict__ ql,
                                                       float* __restrict__ kl,
                                                       short* __restrict__ qlb,
                                                       short* __restrict__ klb) {
  const int idx = blockIdx.x * 256 + threadIdx.x;
  const int d = idx & (DH_ - 1);
  const int m = (idx >> 6) & (M_ - 1);
  const int bh = idx >> 14;
  const size_t base = ((size_t)bh * N_ + m * LG_) * DH_ + d;
  float sq = 0.f, sk = 0.f;
#pragma unroll 8
  for (int t = 0; t < LG_; ++t) {
    sq += bf2f(qb[base + (size_t)t * DH_]);
    sk += bf2f(kb[base + (size_t)t * DH_]);
  }
  sq *= (1.0f / LG_);
  sk *= (1.0f / LG_);
  ql[idx] = sq;
  kl[idx] = sk;
  qlb[idx] = f2bf(sq);
  klb[idx] = f2bf(sk);
}

// ---------------- sim2 + softmax: fp32 (colmax) + bf16 (pinv inputs) ----------------
__global__ __launch_bounds__(256) void sim2_softmax(const float* __restrict__ ql,
                                                    const float* __restrict__ kl,
                                                    float* __restrict__ a2,
                                                    short* __restrict__ a2b) {
  const int i = blockIdx.x, bh = blockIdx.y, j = threadIdx.x;
  __shared__ float qrow[DH_];
  if (j < DH_) qrow[j] = ql[((size_t)bh * M_ + i) * DH_ + j];
  __syncthreads();
  const float* kr = kl + ((size_t)bh * M_ + j) * DH_;
  float s = 0.f;
#pragma unroll 16
  for (int d = 0; d < DH_; ++d) s += qrow[d] * kr[d];
  __shared__ float red[256];
  red[j] = s;
  __syncthreads();
  for (int off = 128; off > 0; off >>= 1) {
    if (j < off) red[j] = fmaxf(red[j], red[j + off]);
    __syncthreads();
  }
  const float mx = red[0];
  __syncthreads();
  const float e = expf(s - mx);
  red[j] = e;
  __syncthreads();
  for (int off = 128; off > 0; off >>= 1) {
    if (j < off) red[j] += red[j + off];
    __syncthreads();
  }
  const float out = e / red[0];
  a2[((size_t)bh * M_ + i) * M_ + j] = out;
  a2b[((size_t)bh * M_ + i) * M_ + j] = f2bf(out);
}

__global__ __launch_bounds__(256) void colmax_kernel(const float* __restrict__ a2,
                                                     unsigned int* __restrict__ scalebits) {
  const int bh = blockIdx.x, j = threadIdx.x;
  const float* mat = a2 + (size_t)bh * M_ * M_;
  float s = 0.f;
  for (int i = 0; i < M_; ++i) s += fabsf(mat[i * M_ + j]);
  __shared__ float red[256];
  red[j] = s;
  __syncthreads();
  for (int off = 128; off > 0; off >>= 1) {
    if (j < off) red[j] = fmaxf(red[j], red[j + off]);
    __syncthreads();
  }
  if (j == 0) atomicMax(scalebits, __float_as_uint(red[0]));
}

// z0b = bf16(a2^T / scale)
__global__ __launch_bounds__(256) void transpose_scale(const float* __restrict__ a2,
                                                       short* __restrict__ z0b,
                                                       const unsigned int* __restrict__ scalebits) {
  const float inv = 1.0f / __uint_as_float(*scalebits);
  const int idx = blockIdx.x * 256 + threadIdx.x;
  const int j = idx & (M_ - 1), i = (idx >> 8) & (M_ - 1), bh = idx >> 16;
  z0b[idx] = f2bf(a2[((size_t)bh * M_ + j) * M_ + i] * inv);
}

// ---------------- batched bf16 MFMA 256x256x256: C = bf16(gamma*(A@B) + beta*D) ----------------
// B staged transposed in LDS (NN product). Optional fp32 copy to Cf (final z).
__global__ __launch_bounds__(256) void gemm256_bf(const short* __restrict__ A,
                                                  const short* __restrict__ B,
                                                  const short* __restrict__ D,
                                                  short* __restrict__ C,
                                                  float* __restrict__ Cf,
                                                  float beta, float gamma) {
  const int m0 = (blockIdx.x >> 2) * 64, n0 = (blockIdx.x & 3) * 64;
  const size_t mo = (size_t)blockIdx.y * (M_ * M_);
  A += mo; B += mo; C += mo; D += mo;
  __shared__ short As[64 * 32];
  __shared__ short Bs[64 * 40];
  const int tid = threadIdx.x, wave = tid >> 6, lane = tid & 63;
  const int mi = lane & 15, quad = lane >> 4;
  const int arow = tid >> 2, acol = (tid & 3) * 8;   // A stage chunk = tid
  const int bkk = tid >> 3, bnc = (tid & 7) * 8;     // B stage chunk
  f32x4 acc[4] = {};
  for (int k0 = 0; k0 < M_; k0 += 32) {
    __builtin_amdgcn_global_load_lds(
        (const __attribute__((address_space(1))) void*)(A + (size_t)(m0 + arow) * M_ + k0 + acol),
        (__attribute__((address_space(3))) void*)(As + (size_t)wave * 512), 16, 0, 0);
    const bf16x8 bv = *(const bf16x8*)(B + (size_t)(k0 + bkk) * M_ + n0 + bnc);
#pragma unroll
    for (int e = 0; e < 8; ++e) Bs[(bnc + e) * 40 + bkk] = bv[e];
    __syncthreads();
    const bf16x8 af = *(const bf16x8*)&As[(wave * 16 + mi) * 32 + quad * 8];
#pragma unroll
    for (int j = 0; j < 4; ++j) {
      const bf16x8 bfr = *(const bf16x8*)&Bs[(j * 16 + mi) * 40 + quad * 8];
      acc[j] = __builtin_amdgcn_mfma_f32_16x16x32_bf16(af, bfr, acc[j], 0, 0, 0);
    }
    __syncthreads();
  }
#pragma unroll
  for (int j = 0; j < 4; ++j) {
#pragma unroll
    for (int r = 0; r < 4; ++r) {
      const int row = m0 + wave * 16 + quad * 4 + r, col = n0 + j * 16 + mi;
      float v = gamma * acc[j][r];
      if (beta != 0.f) v += beta * bf2f(D[(size_t)row * M_ + col]);
      C[(size_t)row * M_ + col] = f2bf(v);
      if (Cf) Cf[mo + (size_t)row * M_ + col] = v;
    }
  }
}

// ---------------- fp32 64x64 core (w2 = z @ a3v only) ----------------
__device__ __forceinline__ void mm_step(float (*As)[68], float (*Bs)[68],
                                        int tr, int tc, float acc[4][4]) {
#pragma unroll
  for (int kk = 0; kk < 16; ++kk) {
    const float4 a4 = *(const float4*)&As[kk][tr * 4];
    const float4 b4 = *(const float4*)&Bs[kk][tc * 4];
    const float a[4] = {a4.x, a4.y, a4.z, a4.w};
    const float b[4] = {b4.x, b4.y, b4.z, b4.w};
#pragma unroll
    for (int i = 0; i < 4; ++i)
#pragma unroll
      for (int j = 0; j < 4; ++j) acc[i][j] = fmaf(a[i], b[j], acc[i][j]);
  }
}

__device__ __forceinline__ void load_a_tile(const float* A, int lda, int m0, int k0,
                                            int tid, float (*As)[68]) {
  const int r = tid >> 2, kq = tid & 3;
  const float4 a4 = *(const float4*)(A + (size_t)(m0 + r) * lda + k0 + kq * 4);
  As[kq * 4 + 0][r] = a4.x;
  As[kq * 4 + 1][r] = a4.y;
  As[kq * 4 + 2][r] = a4.z;
  As[kq * 4 + 3][r] = a4.w;
}

__device__ __forceinline__ void load_b_nn(const float* B, int ldb, int k0, int n0,
                                          int tid, float (*Bs)[68]) {
  const int kr = tid >> 4, c4 = tid & 15;
  const float4 b4 = *(const float4*)(B + (size_t)(k0 + kr) * ldb + n0 + c4 * 4);
  *(float4*)&Bs[kr][c4 * 4] = b4;
}

__global__ __launch_bounds__(256) void gemm_nn64(const float* __restrict__ A, int lda,
                                                 long long strideA,
                                                 const float* __restrict__ B, long long strideB,
                                                 float* __restrict__ C, long long strideC,
                                                 int kchunk) {
  const int bz = blockIdx.z;
  A += (size_t)bz * strideA;
  B += (size_t)bz * strideB;
  C += (size_t)bz * strideC;
  const int m0 = blockIdx.x * 64;
  const int tid = threadIdx.x, tr = tid >> 4, tc = tid & 15;
  __shared__ float As[16][68], Bs[16][68];
  float acc[4][4] = {};
  for (int k0 = 0; k0 < kchunk; k0 += 16) {
    load_a_tile(A, lda, m0, k0, tid, As);
    load_b_nn(B, DH_, k0, 0, tid, Bs);
    __syncthreads();
    mm_step(As, Bs, tr, tc, acc);
    __syncthreads();
  }
#pragma unroll
  for (int i = 0; i < 4; ++i) {
    const int row = m0 + tr * 4 + i;
    *(float4*)(C + (size_t)row * DH_ + tc * 4) =
        make_float4(acc[i][0], acc[i][1], acc[i][2], acc[i][3]);
  }
}

// ---------------- a3 flash ----------------
__global__ __launch_bounds__(256) void a3_flash(const short* __restrict__ qlb,
                                                const short* __restrict__ kb,
                                                const short* __restrict__ vb,
                                                float* __restrict__ Opart,
                                                float* __restrict__ mpart,
                                                float* __restrict__ lpart) {
  const int chunk = blockIdx.x, rt = blockIdx.y, bh = blockIdx.z;
  __shared__ short qs[64 * 80], ks[64 * 80], vts[64 * 80], ps[64 * 80];
  const int tid = threadIdx.x, wave = tid >> 6, lane = tid & 63;
  const int mi = lane & 15, quad = lane >> 4;
#pragma unroll
  for (int i = 0; i < 2; ++i) {
    const int c = tid * 2 + i, row = c >> 3, col = (c & 7) * 8;
    *(bf16x8*)&qs[row * 80 + col] =
        *(const bf16x8*)(qlb + ((size_t)bh * M_ + rt * 64 + row) * DH_ + col);
  }
  __syncthreads();
  const bf16x8 aq0 = *(const bf16x8*)&qs[(wave * 16 + mi) * 80 + quad * 8];
  const bf16x8 aq1 = *(const bf16x8*)&qs[(wave * 16 + mi) * 80 + 32 + quad * 8];
  float m[4] = {-INFINITY, -INFINITY, -INFINITY, -INFINITY};
  float l[4] = {0.f, 0.f, 0.f, 0.f};
  f32x4 o[4] = {};
  for (int t = 0; t < 16; ++t) {
    const int n0 = chunk * 1024 + t * 64;
#pragma unroll
    for (int i = 0; i < 2; ++i) {
      const int c = tid * 2 + i, row = c >> 3, col = (c & 7) * 8;
      *(bf16x8*)&ks[row * 80 + col] =
          *(const bf16x8*)(kb + ((size_t)bh * N_ + n0 + row) * DH_ + col);
      const bf16x8 vv = *(const bf16x8*)(vb + ((size_t)bh * N_ + n0 + row) * DH_ + col);
#pragma unroll
      for (int e = 0; e < 8; ++e) vts[(col + e) * 80 + row] = vv[e];
    }
    __syncthreads();
    f32x4 s[4];
#pragma unroll
    for (int j = 0; j < 4; ++j) {
      const bf16x8 b0 = *(const bf16x8*)&ks[(j * 16 + mi) * 80 + quad * 8];
      const bf16x8 b1 = *(const bf16x8*)&ks[(j * 16 + mi) * 80 + 32 + quad * 8];
      f32x4 z = {0.f, 0.f, 0.f, 0.f};
      z = __builtin_amdgcn_mfma_f32_16x16x32_bf16(aq0, b0, z, 0, 0, 0);
      s[j] = __builtin_amdgcn_mfma_f32_16x16x32_bf16(aq1, b1, z, 0, 0, 0);
    }
    float alpha[4];
#pragma unroll
    for (int r = 0; r < 4; ++r) {
      float v = fmaxf(fmaxf(s[0][r], s[1][r]), fmaxf(s[2][r], s[3][r]));
      v = fmaxf(v, __shfl_xor(v, 1, 64));
      v = fmaxf(v, __shfl_xor(v, 2, 64));
      v = fmaxf(v, __shfl_xor(v, 4, 64));
      v = fmaxf(v, __shfl_xor(v, 8, 64));
      const float mnew = fmaxf(m[r], v);
      alpha[r] = __expf(m[r] - mnew);
      m[r] = mnew;
    }
    float rs[4] = {0.f, 0.f, 0.f, 0.f};
#pragma unroll
    for (int j = 0; j < 4; ++j)
#pragma unroll
      for (int r = 0; r < 4; ++r) {
        const float p = __expf(s[j][r] - m[r]);
        rs[r] += p;
        ps[(wave * 16 + quad * 4 + r) * 80 + j * 16 + mi] = f2bf(p);
      }
#pragma unroll
    for (int r = 0; r < 4; ++r) {
      float v = rs[r];
      v += __shfl_xor(v, 1, 64);
      v += __shfl_xor(v, 2, 64);
      v += __shfl_xor(v, 4, 64);
      v += __shfl_xor(v, 8, 64);
      l[r] = l[r] * alpha[r] + v;
#pragma unroll
      for (int j = 0; j < 4; ++j) o[j][r] *= alpha[r];
    }
    __syncthreads();
    const bf16x8 ap0 = *(const bf16x8*)&ps[(wave * 16 + mi) * 80 + quad * 8];
    const bf16x8 ap1 = *(const bf16x8*)&ps[(wave * 16 + mi) * 80 + 32 + quad * 8];
#pragma unroll
    for (int j = 0; j < 4; ++j) {
      const bf16x8 b0 = *(const bf16x8*)&vts[(j * 16 + mi) * 80 + quad * 8];
      const bf16x8 b1 = *(const bf16x8*)&vts[(j * 16 + mi) * 80 + 32 + quad * 8];
      o[j] = __builtin_amdgcn_mfma_f32_16x16x32_bf16(ap0, b0, o[j], 0, 0, 0);
      o[j] = __builtin_amdgcn_mfma_f32_16x16x32_bf16(ap1, b1, o[j], 0, 0, 0);
    }
    __syncthreads();
  }
  const int p2 = bh * 4 + rt;
  float* Ob = Opart + ((size_t)chunk * 64 + p2) * 4096;
#pragma unroll
  for (int j = 0; j < 4; ++j)
#pragma unroll
    for (int r = 0; r < 4; ++r)
      Ob[(wave * 16 + quad * 4 + r) * 64 + j * 16 + mi] = o[j][r];
  if (mi == 0) {
#pragma unroll
    for (int r = 0; r < 4; ++r) {
      mpart[((size_t)chunk * 64 + p2) * 64 + wave * 16 + quad * 4 + r] = m[r];
      lpart[((size_t)chunk * 64 + p2) * 64 + wave * 16 + quad * 4 + r] = l[r];
    }
  }
}

__global__ __launch_bounds__(256) void a3_combine(const float* __restrict__ Opart,
                                                  const float* __restrict__ mpart,
                                                  const float* __restrict__ lpart,
                                                  float* __restrict__ a3v) {
  const int p2 = blockIdx.x;
  const int bh = p2 >> 2, rt = p2 & 3;
  __shared__ float wgt[8][64];
  const int tid = threadIdx.x;
  if (tid < 64) {
    float mg = -INFINITY;
    for (int c = 0; c < 8; ++c) mg = fmaxf(mg, mpart[((size_t)c * 64 + p2) * 64 + tid]);
    float e[8], lg = 0.f;
    for (int c = 0; c < 8; ++c) {
      e[c] = __expf(mpart[((size_t)c * 64 + p2) * 64 + tid] - mg);
      lg += lpart[((size_t)c * 64 + p2) * 64 + tid] * e[c];
    }
    const float inv = 1.f / lg;
    for (int c = 0; c < 8; ++c) wgt[c][tid] = e[c] * inv;
  }
  __syncthreads();
  for (int i = tid; i < 4096; i += 256) {
    const int row = i >> 6, d = i & 63;
    float s = 0.f;
    for (int c = 0; c < 8; ++c) s += Opart[((size_t)c * 64 + p2) * 4096 + i] * wgt[c][row];
    a3v[((size_t)bh * M_ + rt * 64 + row) * DH_ + d] = s;
  }
}

// ---------------- w2 fp32 -> w2t bf16 ----------------
__global__ __launch_bounds__(256) void w2t_kernel(const float* __restrict__ w2,
                                                  short* __restrict__ w2tb) {
  const int bh = blockIdx.x, tid = threadIdx.x;
  for (int i = tid; i < M_ * DH_; i += 256) {
    const int r = i >> 6, d = i & 63;
    w2tb[((size_t)bh * DH_ + d) * M_ + r] = f2bf(w2[(size_t)bh * M_ * DH_ + i]);
  }
}

// ---------------- a1 fused: omb = softmax(q @ kl^T) @ w2 + Band@Vc (conv), bf16 ----------------
// LDS: [0,33792) ps[64][264] (first 9216 B double as qs[64][72]);
//      [33792,47104) vcsT[64][104]; [47104,60416) band[64][104]
__global__ __launch_bounds__(256) void a1_conv(const short* __restrict__ qb,
                                               const short* __restrict__ klb,
                                               const short* __restrict__ w2tb,
                                               const short* __restrict__ vb,
                                               const float* __restrict__ rk,
                                               short* __restrict__ omb) {
  __shared__ __align__(16) char smem[60416];
  short* qs = (short*)smem;
  short* ps = (short*)smem;
  short* vcsT = (short*)(smem + 33792);
  short* band = (short*)(smem + 47104);
  const int bh = blockIdx.y, t0 = blockIdx.x * 64;
  const int b = bh >> 3, h = bh & 7;
  const int tid = threadIdx.x, wave = tid >> 6, lane = tid & 63;
  const int mi = lane & 15, quad = lane >> 4;
  // stage q tile [64][72]
#pragma unroll
  for (int i = 0; i < 2; ++i) {
    const int c = tid * 2 + i, row = c >> 3, col = (c & 7) * 8;
    *(bf16x8*)&qs[row * 72 + col] =
        *(const bf16x8*)(qb + ((size_t)bh * N_ + t0 + row) * DH_ + col);
  }
  __syncthreads();
  const bf16x8 aq0 = *(const bf16x8*)&qs[(wave * 16 + mi) * 72 + quad * 8];
  const bf16x8 aq1 = *(const bf16x8*)&qs[(wave * 16 + mi) * 72 + 32 + quad * 8];
  // build vcsT (transposed v window, zero-padded) + band (conv coefficients)
#pragma unroll
  for (int i = 0; i < 3; ++i) {
    const int c = tid + i * 256, vrow = c >> 3, vcol = (c & 7) * 8;
    const int g = t0 - 16 + vrow;
    bf16x8 vv;
    if (g >= 0 && g < N_) {
      vv = *(const bf16x8*)(vb + ((size_t)bh * N_ + g) * DH_ + vcol);
    } else {
#pragma unroll
      for (int e = 0; e < 8; ++e) vv[e] = 0;
    }
#pragma unroll
    for (int e = 0; e < 8; ++e) vcsT[(vcol + e) * 104 + vrow] = vv[e];
  }
  {
    const int r = tid >> 2, cb = (tid & 3) * 24;
#pragma unroll
    for (int e = 0; e < 24; ++e) {
      const int c = cb + e, u = c - r;
      band[r * 104 + c] = (u >= 0 && u < KC_) ? f2bf(rk[h * KC_ + u]) : (short)0;
    }
  }
  // S = q @ kl^T (B-frags straight from global, L1/L2-resident)
  f32x4 s[16];
#pragma unroll
  for (int f = 0; f < 16; ++f) {
    const bf16x8 b0 = *(const bf16x8*)(klb + ((size_t)bh * M_ + f * 16 + mi) * DH_ + quad * 8);
    const bf16x8 b1 =
        *(const bf16x8*)(klb + ((size_t)bh * M_ + f * 16 + mi) * DH_ + 32 + quad * 8);
    f32x4 z = {0.f, 0.f, 0.f, 0.f};
    z = __builtin_amdgcn_mfma_f32_16x16x32_bf16(aq0, b0, z, 0, 0, 0);
    s[f] = __builtin_amdgcn_mfma_f32_16x16x32_bf16(aq1, b1, z, 0, 0, 0);
  }
  // exact softmax over 256 cols (cross-lane via shfl over the 16 mi lanes x 4 quads)
  float inv[4];
#pragma unroll
  for (int r = 0; r < 4; ++r) {
    float v = s[0][r];
#pragma unroll
    for (int f = 1; f < 16; ++f) v = fmaxf(v, s[f][r]);
    v = fmaxf(v, __shfl_xor(v, 1, 64));
    v = fmaxf(v, __shfl_xor(v, 2, 64));
    v = fmaxf(v, __shfl_xor(v, 4, 64));
    v = fmaxf(v, __shfl_xor(v, 8, 64));
    float sum = 0.f;
#pragma unroll
    for (int f = 0; f < 16; ++f) {
      const float p = __expf(s[f][r] - v);
      s[f][r] = p;
      sum += p;
    }
    sum += __shfl_xor(sum, 1, 64);
    sum += __shfl_xor(sum, 2, 64);
    sum += __shfl_xor(sum, 4, 64);
    sum += __shfl_xor(sum, 8, 64);
    inv[r] = 1.f / sum;
  }
  __syncthreads();  // qs dead; vcsT/band visible to all
#pragma unroll
  for (int f = 0; f < 16; ++f)
#pragma unroll
    for (int r = 0; r < 4; ++r)
      ps[(wave * 16 + quad * 4 + r) * 264 + f * 16 + mi] = f2bf(s[f][r] * inv[r]);
  __syncthreads();
  // O = P @ w2 (w2tb frags from global) + Band @ Vc (conv), all MFMA
  f32x4 o[4] = {};
#pragma unroll
  for (int k0 = 0; k0 < 8; ++k0) {
    const bf16x8 ap = *(const bf16x8*)&ps[(wave * 16 + mi) * 264 + k0 * 32 + quad * 8];
#pragma unroll
    for (int j = 0; j < 4; ++j) {
      const bf16x8 bw =
          *(const bf16x8*)(w2tb + ((size_t)bh * DH_ + j * 16 + mi) * M_ + k0 * 32 + quad * 8);
      o[j] = __builtin_amdgcn_mfma_f32_16x16x32_bf16(ap, bw, o[j], 0, 0, 0);
    }
  }
#pragma unroll
  for (int ks = 0; ks < 3; ++ks) {
    const bf16x8 ab = *(const bf16x8*)&band[(wave * 16 + mi) * 104 + ks * 32 + quad * 8];
#pragma unroll
    for (int j = 0; j < 4; ++j) {
      const bf16x8 bv = *(const bf16x8*)&vcsT[(j * 16 + mi) * 104 + ks * 32 + quad * 8];
      o[j] = __builtin_amdgcn_mfma_f32_16x16x32_bf16(ab, bv, o[j], 0, 0, 0);
    }
  }
#pragma unroll
  for (int j = 0; j < 4; ++j) {
    const int d = j * 16 + mi;
#pragma unroll
    for (int r = 0; r < 4; ++r) {
      const int t = t0 + wave * 16 + quad * 4 + r;
      omb[((size_t)(b * N_ + t)) * DIM_ + h * DH_ + d] = f2bf(o[j][r]);
    }
  }
}

extern "C" void kernel_launch(void* const* d_in, const int* in_sizes, int n_in,
                              void* d_out, int out_size, void* d_ws, size_t ws_size,
                              hipStream_t stream) {
  (void)in_sizes; (void)n_in; (void)out_size;
  const float* x = (const float*)d_in[0];
  const float* gamma = (const float*)d_in[1];
  const float* beta = (const float*)d_in[2];
  const float* wqkv = (const float*)d_in[3];
  const float* wout = (const float*)d_in[4];
  const float* bout = (const float*)d_in[5];
  const float* rk = (const float*)d_in[6];
  float* y = (float*)d_out;
  float* ws = (float*)d_ws;

  size_t o = 0;
  short* xnb = (short*)(ws + o);   o += (size_t)2 * N_ * DIM_ / 2;
  short* wqkvt = (short*)(ws + o); o += (size_t)3 * DIM_ * DIM_ / 2;
  short* woutt = (short*)(ws + o); o += (size_t)DIM_ * DIM_ / 2;
  short* qb = (short*)(ws + o);    o += (size_t)BH_ * N_ * DH_ / 2;
  short* kb = (short*)(ws + o);    o += (size_t)BH_ * N_ * DH_ / 2;
  short* vb = (short*)(ws + o);    o += (size_t)BH_ * N_ * DH_ / 2;
  float* ql = ws + o;  o += (size_t)BH_ * M_ * DH_;
  float* kl = ws + o;  o += (size_t)BH_ * M_ * DH_;
  short* qlb = (short*)(ws + o); o += (size_t)BH_ * M_ * DH_ / 2;
  short* klb = (short*)(ws + o); o += (size_t)BH_ * M_ * DH_ / 2;
  float* a2 = ws + o;  o += (size_t)BH_ * M_ * M_;
  float* z0f = ws + o; o += (size_t)BH_ * M_ * M_;
  short* a2b = (short*)(ws + o); o += (size_t)BH_ * M_ * M_ / 2;
  short* z0b = (short*)(ws + o); o += (size_t)BH_ * M_ * M_ / 2;
  short* z1b = (short*)(ws + o); o += (size_t)BH_ * M_ * M_ / 2;
  short* azb = (short*)(ws + o); o += (size_t)BH_ * M_ * M_ / 2;
  short* t2b = (short*)(ws + o); o += (size_t)BH_ * M_ * M_ / 2;
  short* t4b = (short*)(ws + o); o += (size_t)BH_ * M_ * M_ / 2;
  float* Opart = ws + o; o += (size_t)8 * 64 * 4096;
  float* mpart = ws + o; o += (size_t)8 * 64 * 64;
  float* lpart = ws + o; o += (size_t)8 * 64 * 64;
  float* a3v = ws + o; o += (size_t)BH_ * M_ * DH_;
  float* w2 = ws + o;  o += (size_t)BH_ * M_ * DH_;
  short* w2tb = (short*)(ws + o); o += (size_t)BH_ * M_ * DH_ / 2;
  short* omb = (short*)(ws + o);  o += (size_t)2 * N_ * DIM_ / 2;
  unsigned int* scalebits = (unsigned int*)(ws + o); o += 16;
  if (ws_size < o * sizeof(float)) return;

  hipMemsetAsync(scalebits, 0, 64, stream);
  ln_kernel<<<2 * N_, 128, 0, stream>>>(x, gamma, beta, xnb);
  convt_kernel<<<dim3(3 * DIM_ / 32, DIM_ / 32), 256, 0, stream>>>(wqkv, wqkvt, DIM_, 3 * DIM_);
  convt_kernel<<<dim3(DIM_ / 32, DIM_ / 32), 256, 0, stream>>>(wout, woutt, DIM_, DIM_);
  qkv_mfma<<<dim3(2 * N_ / 128, 3 * DIM_ / 128), 256, 0, stream>>>(xnb, wqkvt, qb, kb, vb);

  landmark_kernel<<<BH_ * M_ * DH_ / 256, 256, 0, stream>>>(qb, kb, ql, kl, qlb, klb);
  sim2_softmax<<<dim3(M_, BH_), 256, 0, stream>>>(ql, kl, a2, a2b);
  colmax_kernel<<<BH_, 256, 0, stream>>>(a2, scalebits);
  transpose_scale<<<BH_ * M_ * M_ / 256, 256, 0, stream>>>(a2, z0b, scalebits);

  // a3 flash (independent of pinv)
  a3_flash<<<dim3(8, 4, BH_), 256, 0, stream>>>(qlb, kb, vb, Opart, mpart, lpart);
  a3_combine<<<64, 256, 0, stream>>>(Opart, mpart, lpart, a3v);

  // Newton-Schulz pinv, bf16 MFMA (self-correcting: only last-iter rounding survives)
  for (int it = 0; it < 6; ++it) {
    short* zi = (it & 1) ? z1b : z0b;
    short* zo = (it & 1) ? z0b : z1b;
    float* cf = (it == 5) ? z0f : nullptr;
    gemm256_bf<<<dim3(16, BH_), 256, 0, stream>>>(a2b, zi, azb, azb, nullptr, 0.f, 1.f);
    gemm256_bf<<<dim3(16, BH_), 256, 0, stream>>>(azb, azb, azb, t2b, nullptr, 7.f, -1.f);
    gemm256_bf<<<dim3(16, BH_), 256, 0, stream>>>(azb, t2b, azb, t4b, nullptr, 15.f, -1.f);
    gemm256_bf<<<dim3(16, BH_), 256, 0, stream>>>(zi, t4b, zi, zo, cf, 3.25f, -0.25f);
  }

  // w2 = z @ a3v (fp32), transpose to bf16
  gemm_nn64<<<dim3(M_ / 64, 1, BH_), 256, 0, stream>>>(
      z0f, M_, (long long)M_ * M_, a3v, (long long)M_ * DH_, w2, (long long)M_ * DH_, M_);
  w2t_kernel<<<BH_, 256, 0, stream>>>(w2, w2tb);

  // fused a1 @ w2 + band-MFMA depthwise conv -> omb bf16
  a1_conv<<<dim3(N_ / 64, BH_), 256, 0, stream>>>(qb, klb, w2tb, vb, rk, omb);

  final_mfma<<<dim3(2 * N_ / 128, DIM_ / 128), 256, 0, stream>>>(omb, woutt, x, bout, y);
}

// Round 6
// 534.892 us; speedup vs baseline: 3.4052x; 1.1309x over previous
//
#include <hip/hip_runtime.h>
#include <math.h>

#define H_ 8
#define DH_ 64
#define DIM_ 512
#define M_ 256
#define N_ 8192
#define BH_ 16
#define LG_ 32
#define KC_ 33
#define PADC_ 16

typedef __attribute__((ext_vector_type(8))) short bf16x8;
typedef __attribute__((ext_vector_type(4))) short s16x4;
typedef __attribute__((ext_vector_type(4))) float f32x4;

__device__ __forceinline__ short f2bf(float f) {
  unsigned u = __float_as_uint(f);
  unsigned r = (u + 0x7FFF + ((u >> 16) & 1)) >> 16;  // RNE
  return (short)r;
}
__device__ __forceinline__ float bf2f(short s) {
  return __uint_as_float(((unsigned)(unsigned short)s) << 16);
}

// =================== bf16 MFMA NT core (128x128 tile) ===================
__device__ __forceinline__ void mfma_nt_core(const short* __restrict__ A,
                                             const short* __restrict__ Bt, int K,
                                             int m0, int n0, size_t lda, size_t ldb,
                                             f32x4 acc[4][4], short* As, short* Bs) {
  const int tid = threadIdx.x;
  const int wave = tid >> 6, lane = tid & 63;
  const int wr = (wave >> 1) * 64, wc = (wave & 1) * 64;
  const int mi = lane & 15, quad = lane >> 4;
  for (int k0 = 0; k0 < K; k0 += 32) {
#pragma unroll
    for (int t = 0; t < 2; ++t) {
      const int cbase = (t * 4 + wave) * 64;
      const int chunk = cbase + lane;
      const int row = chunk >> 2, cc = (chunk & 3) * 8;
      __builtin_amdgcn_global_load_lds(
          (const __attribute__((address_space(1))) void*)(A + (size_t)(m0 + row) * lda + k0 + cc),
          (__attribute__((address_space(3))) void*)(As + (size_t)cbase * 8), 16, 0, 0);
      __builtin_amdgcn_global_load_lds(
          (const __attribute__((address_space(1))) void*)(Bt + (size_t)(n0 + row) * ldb + k0 + cc),
          (__attribute__((address_space(3))) void*)(Bs + (size_t)cbase * 8), 16, 0, 0);
    }
    __syncthreads();
    bf16x8 af[4], bf[4];
#pragma unroll
    for (int i = 0; i < 4; ++i)
      af[i] = *(const bf16x8*)&As[(wr + i * 16 + mi) * 32 + quad * 8];
#pragma unroll
    for (int j = 0; j < 4; ++j)
      bf[j] = *(const bf16x8*)&Bs[(wc + j * 16 + mi) * 32 + quad * 8];
#pragma unroll
    for (int i = 0; i < 4; ++i)
#pragma unroll
      for (int j = 0; j < 4; ++j)
        acc[i][j] = __builtin_amdgcn_mfma_f32_16x16x32_bf16(af[i], bf[j], acc[i][j], 0, 0, 0);
    __syncthreads();
  }
}

// QKV GEMM -> bf16 q/k/v (bh,n,d), q scaled
__global__ __launch_bounds__(256) void qkv_mfma(const short* __restrict__ xnb,
                                                const short* __restrict__ wt,
                                                short* __restrict__ qb, short* __restrict__ kb,
                                                short* __restrict__ vb) {
  __shared__ short As[128 * 32], Bs[128 * 32];
  f32x4 acc[4][4] = {};
  const int m0 = blockIdx.x * 128, n0 = blockIdx.y * 128;
  mfma_nt_core(xnb, wt, DIM_, m0, n0, DIM_, DIM_, acc, As, Bs);
  const int wave = threadIdx.x >> 6, lane = threadIdx.x & 63;
  const int wr = (wave >> 1) * 64, wc = (wave & 1) * 64;
  const int mi = lane & 15, quad = lane >> 4;
  const int which = n0 >> 9;
  short* dst = which == 0 ? qb : which == 1 ? kb : vb;
  const float sc = which == 0 ? 0.125f : 1.0f;
#pragma unroll
  for (int j = 0; j < 4; ++j) {
    const int col = n0 + wc + j * 16 + mi;
    const int h = (col >> 6) & 7, d = col & 63;
#pragma unroll
    for (int i = 0; i < 4; ++i) {
#pragma unroll
      for (int r = 0; r < 4; ++r) {
        const int row = m0 + wr + i * 16 + quad * 4 + r;
        const int b = row >> 13, t = row & (N_ - 1);
        dst[((size_t)(b * H_ + h) * N_ + t) * DH_ + d] = f2bf(acc[i][j][r] * sc);
      }
    }
  }
}

// final: y = x + omb @ woutt^T + b_out
__global__ __launch_bounds__(256) void final_mfma(const short* __restrict__ omb,
                                                  const short* __restrict__ wt,
                                                  const float* __restrict__ x,
                                                  const float* __restrict__ bout,
                                                  float* __restrict__ y) {
  __shared__ short As[128 * 32], Bs[128 * 32];
  f32x4 acc[4][4] = {};
  const int m0 = blockIdx.x * 128, n0 = blockIdx.y * 128;
  mfma_nt_core(omb, wt, DIM_, m0, n0, DIM_, DIM_, acc, As, Bs);
  const int wave = threadIdx.x >> 6, lane = threadIdx.x & 63;
  const int wr = (wave >> 1) * 64, wc = (wave & 1) * 64;
  const int mi = lane & 15, quad = lane >> 4;
#pragma unroll
  for (int j = 0; j < 4; ++j) {
    const int col = n0 + wc + j * 16 + mi;
    const float bo = bout[col];
#pragma unroll
    for (int i = 0; i < 4; ++i) {
#pragma unroll
      for (int r = 0; r < 4; ++r) {
        const int row = m0 + wr + i * 16 + quad * 4 + r;
        y[(size_t)row * DIM_ + col] = acc[i][j][r] + x[(size_t)row * DIM_ + col] + bo;
      }
    }
  }
}

// fp32 (K x N) -> bf16 transposed (N x K)
__global__ __launch_bounds__(256) void convt_kernel(const float* __restrict__ in,
                                                    short* __restrict__ out, int K, int N) {
  __shared__ float tile[32][33];
  const int n0 = blockIdx.x * 32, k0 = blockIdx.y * 32;
  const int tx = threadIdx.x & 31, ty = threadIdx.x >> 5;
  for (int r = ty; r < 32; r += 8) tile[r][tx] = in[(size_t)(k0 + r) * N + n0 + tx];
  __syncthreads();
  for (int r = ty; r < 32; r += 8) out[(size_t)(n0 + r) * K + k0 + tx] = f2bf(tile[tx][r]);
}

// bf16 v (bh,t,d) -> vtb (bh,d,t): 32x32 LDS tiles, conflict-free (+1 pad)
__global__ __launch_bounds__(256) void vt_kernel(const short* __restrict__ vb,
                                                 short* __restrict__ vtb) {
  __shared__ short tile[32][33];
  const int t0 = blockIdx.x * 32, d0 = blockIdx.y * 32, bh = blockIdx.z;
  const int tx = threadIdx.x & 31, ty = threadIdx.x >> 5;
  for (int r = ty; r < 32; r += 8)
    tile[r][tx] = vb[((size_t)bh * N_ + t0 + r) * DH_ + d0 + tx];
  __syncthreads();
  for (int r = ty; r < 32; r += 8)
    vtb[((size_t)bh * DH_ + d0 + r) * N_ + t0 + tx] = tile[tx][r];
}

// ---------------- LayerNorm -> bf16 ----------------
__global__ __launch_bounds__(128) void ln_kernel(const float* __restrict__ x,
                                                 const float* __restrict__ gamma,
                                                 const float* __restrict__ beta,
                                                 short* __restrict__ xnb) {
  const int row = blockIdx.x, tid = threadIdx.x;
  const float4 v = ((const float4*)(x + (size_t)row * DIM_))[tid];
  float s = v.x + v.y + v.z + v.w;
  float ss = v.x * v.x + v.y * v.y + v.z * v.z + v.w * v.w;
  __shared__ float r1[128], r2[128];
  r1[tid] = s;
  r2[tid] = ss;
  __syncthreads();
  for (int off = 64; off > 0; off >>= 1) {
    if (tid < off) {
      r1[tid] += r1[tid + off];
      r2[tid] += r2[tid + off];
    }
    __syncthreads();
  }
  const float mu = r1[0] * (1.0f / DIM_);
  const float var = r2[0] * (1.0f / DIM_) - mu * mu;
  const float rs = rsqrtf(var + 1e-5f);
  const float4 g = ((const float4*)gamma)[tid];
  const float4 bb = ((const float4*)beta)[tid];
  s16x4 o = {f2bf((v.x - mu) * rs * g.x + bb.x), f2bf((v.y - mu) * rs * g.y + bb.y),
             f2bf((v.z - mu) * rs * g.z + bb.z), f2bf((v.w - mu) * rs * g.w + bb.w)};
  ((s16x4*)(xnb + (size_t)row * DIM_))[tid] = o;
}

// ---------------- landmarks ----------------
__global__ __launch_bounds__(256) void landmark_kernel(const short* __restrict__ qb,
                                                       const short* __restrict__ kb,
                                                       float* __restrict__ ql,
                                                       float* __restrict__ kl,
                                                       short* __restrict__ qlb,
                                                       short* __restrict__ klb) {
  const int idx = blockIdx.x * 256 + threadIdx.x;
  const int d = idx & (DH_ - 1);
  const int m = (idx >> 6) & (M_ - 1);
  const int bh = idx >> 14;
  const size_t base = ((size_t)bh * N_ + m * LG_) * DH_ + d;
  float sq = 0.f, sk = 0.f;
#pragma unroll 8
  for (int t = 0; t < LG_; ++t) {
    sq += bf2f(qb[base + (size_t)t * DH_]);
    sk += bf2f(kb[base + (size_t)t * DH_]);
  }
  sq *= (1.0f / LG_);
  sk *= (1.0f / LG_);
  ql[idx] = sq;
  kl[idx] = sk;
  qlb[idx] = f2bf(sq);
  klb[idx] = f2bf(sk);
}

// ---------------- sim2 + softmax ----------------
__global__ __launch_bounds__(256) void sim2_softmax(const float* __restrict__ ql,
                                                    const float* __restrict__ kl,
                                                    float* __restrict__ a2,
                                                    short* __restrict__ a2b) {
  const int i = blockIdx.x, bh = blockIdx.y, j = threadIdx.x;
  __shared__ float qrow[DH_];
  if (j < DH_) qrow[j] = ql[((size_t)bh * M_ + i) * DH_ + j];
  __syncthreads();
  const float* kr = kl + ((size_t)bh * M_ + j) * DH_;
  float s = 0.f;
#pragma unroll 16
  for (int d = 0; d < DH_; ++d) s += qrow[d] * kr[d];
  __shared__ float red[256];
  red[j] = s;
  __syncthreads();
  for (int off = 128; off > 0; off >>= 1) {
    if (j < off) red[j] = fmaxf(red[j], red[j + off]);
    __syncthreads();
  }
  const float mx = red[0];
  __syncthreads();
  const float e = expf(s - mx);
  red[j] = e;
  __syncthreads();
  for (int off = 128; off > 0; off >>= 1) {
    if (j < off) red[j] += red[j + off];
    __syncthreads();
  }
  const float out = e / red[0];
  a2[((size_t)bh * M_ + i) * M_ + j] = out;
  a2b[((size_t)bh * M_ + i) * M_ + j] = f2bf(out);
}

__global__ __launch_bounds__(256) void colmax_kernel(const float* __restrict__ a2,
                                                     unsigned int* __restrict__ scalebits) {
  const int bh = blockIdx.x, j = threadIdx.x;
  const float* mat = a2 + (size_t)bh * M_ * M_;
  float s = 0.f;
  for (int i = 0; i < M_; ++i) s += fabsf(mat[i * M_ + j]);
  __shared__ float red[256];
  red[j] = s;
  __syncthreads();
  for (int off = 128; off > 0; off >>= 1) {
    if (j < off) red[j] = fmaxf(red[j], red[j + off]);
    __syncthreads();
  }
  if (j == 0) atomicMax(scalebits, __float_as_uint(red[0]));
}

// z0b = bf16(a2^T / scale)
__global__ __launch_bounds__(256) void transpose_scale(const float* __restrict__ a2,
                                                       short* __restrict__ z0b,
                                                       const unsigned int* __restrict__ scalebits) {
  const float inv = 1.0f / __uint_as_float(*scalebits);
  const int idx = blockIdx.x * 256 + threadIdx.x;
  const int j = idx & (M_ - 1), i = (idx >> 8) & (M_ - 1), bh = idx >> 16;
  z0b[idx] = f2bf(a2[((size_t)bh * M_ + j) * M_ + i] * inv);
}

// ============ Newton-Schulz bf16 MFMA machinery (64x64 tiles of 256^2, K=256) ============
// As staged via global_load_lds; Bs transposed, stride 44 (write banks spread, 2-way free)
__device__ __forceinline__ void ns_core(const short* __restrict__ A, const short* __restrict__ B,
                                        int m0, int n0, short* As, short* Bs, f32x4 acc[4]) {
  const int tid = threadIdx.x, wave = tid >> 6, lane = tid & 63;
  const int mi = lane & 15, quad = lane >> 4;
  const int arow = tid >> 2, acol = (tid & 3) * 8;
  const int bkk = tid & 31, g = tid >> 5;
  for (int k0 = 0; k0 < M_; k0 += 32) {
    __builtin_amdgcn_global_load_lds(
        (const __attribute__((address_space(1))) void*)(A + (size_t)(m0 + arow) * M_ + k0 + acol),
        (__attribute__((address_space(3))) void*)(As + (size_t)wave * 512), 16, 0, 0);
    const bf16x8 bv = *(const bf16x8*)(B + (size_t)(k0 + bkk) * M_ + n0 + g * 8);
#pragma unroll
    for (int e = 0; e < 8; ++e) Bs[(g * 8 + e) * 44 + bkk] = bv[e];
    __syncthreads();
    const bf16x8 af = *(const bf16x8*)&As[(wave * 16 + mi) * 32 + quad * 8];
#pragma unroll
    for (int j = 0; j < 4; ++j) {
      union { bf16x8 v; s16x4 h[2]; } bfr;
      const short* bp = &Bs[(j * 16 + mi) * 44 + quad * 8];
      bfr.h[0] = *(const s16x4*)bp;       // 8B-aligned (44*2=88 B rows)
      bfr.h[1] = *(const s16x4*)(bp + 4);
      acc[j] = __builtin_amdgcn_mfma_f32_16x16x32_bf16(af, bfr.v, acc[j], 0, 0, 0);
    }
    __syncthreads();
  }
}

// y0 = A@B
__global__ __launch_bounds__(256) void ns_gemm0(const short* __restrict__ A,
                                                const short* __restrict__ B,
                                                short* __restrict__ C) {
  __shared__ short As[64 * 32], Bs[64 * 44];
  const int m0 = (blockIdx.x >> 2) * 64, n0 = (blockIdx.x & 3) * 64;
  const size_t mo = (size_t)blockIdx.y * (M_ * M_);
  f32x4 acc[4] = {};
  ns_core(A + mo, B + mo, m0, n0, As, Bs, acc);
  const int wave = threadIdx.x >> 6, lane = threadIdx.x & 63;
  const int mi = lane & 15, quad = lane >> 4;
#pragma unroll
  for (int j = 0; j < 4; ++j)
#pragma unroll
    for (int r = 0; r < 4; ++r) {
      const int row = m0 + wave * 16 + quad * 4 + r, col = n0 + j * 16 + mi;
      C[mo + (size_t)row * M_ + col] = f2bf(acc[j][r]);
    }
}

// stage A: sel0: p1 = z@y ; sel1: y2 = y@y, w = 1.75y - 0.25*y2
__global__ __launch_bounds__(256) void ns_stageA(const short* __restrict__ z,
                                                 const short* __restrict__ y,
                                                 short* __restrict__ p1,
                                                 short* __restrict__ y2,
                                                 short* __restrict__ w) {
  __shared__ short As[64 * 32], Bs[64 * 44];
  const int m0 = (blockIdx.x >> 2) * 64, n0 = (blockIdx.x & 3) * 64;
  const int sel = blockIdx.y & 1;
  const size_t mo = (size_t)(blockIdx.y >> 1) * (M_ * M_);
  f32x4 acc[4] = {};
  ns_core((sel ? y : z) + mo, y + mo, m0, n0, As, Bs, acc);
  const int wave = threadIdx.x >> 6, lane = threadIdx.x & 63;
  const int mi = lane & 15, quad = lane >> 4;
#pragma unroll
  for (int j = 0; j < 4; ++j)
#pragma unroll
    for (int r = 0; r < 4; ++r) {
      const int row = m0 + wave * 16 + quad * 4 + r, col = n0 + j * 16 + mi;
      const size_t idx = mo + (size_t)row * M_ + col;
      if (sel) {
        y2[idx] = f2bf(acc[j][r]);
        w[idx] = f2bf(1.75f * bf2f(y[idx]) - 0.25f * acc[j][r]);
      } else {
        p1[idx] = f2bf(acc[j][r]);
      }
    }
}

// stage B: sel0: zo = 3.25z - 3.75p1 + p1@w (opt fp32 out) ; sel1: yo = 3.25y - 3.75y2 + y2@w
__global__ __launch_bounds__(256) void ns_stageB(const short* __restrict__ p1,
                                                 const short* __restrict__ y2,
                                                 const short* __restrict__ w,
                                                 const short* __restrict__ z,
                                                 const short* __restrict__ y,
                                                 short* __restrict__ zo,
                                                 short* __restrict__ yo,
                                                 float* __restrict__ zf, int zonly) {
  __shared__ short As[64 * 32], Bs[64 * 44];
  const int m0 = (blockIdx.x >> 2) * 64, n0 = (blockIdx.x & 3) * 64;
  const int sel = zonly ? 0 : (blockIdx.y & 1);
  const size_t mo = (size_t)(zonly ? blockIdx.y : (blockIdx.y >> 1)) * (M_ * M_);
  f32x4 acc[4] = {};
  ns_core((sel ? y2 : p1) + mo, w + mo, m0, n0, As, Bs, acc);
  const int wave = threadIdx.x >> 6, lane = threadIdx.x & 63;
  const int mi = lane & 15, quad = lane >> 4;
#pragma unroll
  for (int j = 0; j < 4; ++j)
#pragma unroll
    for (int r = 0; r < 4; ++r) {
      const int row = m0 + wave * 16 + quad * 4 + r, col = n0 + j * 16 + mi;
      const size_t idx = mo + (size_t)row * M_ + col;
      if (sel) {
        yo[idx] = f2bf(3.25f * bf2f(y[idx]) - 3.75f * bf2f(y2[idx]) + acc[j][r]);
      } else {
        const float v = 3.25f * bf2f(z[idx]) - 3.75f * bf2f(p1[idx]) + acc[j][r];
        zo[idx] = f2bf(v);
        if (zf) zf[idx] = v;
      }
    }
}

// ---------------- fp32 64x64 core (w2 = z @ a3v only) ----------------
__device__ __forceinline__ void mm_step(float (*As)[68], float (*Bs)[68],
                                        int tr, int tc, float acc[4][4]) {
#pragma unroll
  for (int kk = 0; kk < 16; ++kk) {
    const float4 a4 = *(const float4*)&As[kk][tr * 4];
    const float4 b4 = *(const float4*)&Bs[kk][tc * 4];
    const float a[4] = {a4.x, a4.y, a4.z, a4.w};
    const float b[4] = {b4.x, b4.y, b4.z, b4.w};
#pragma unroll
    for (int i = 0; i < 4; ++i)
#pragma unroll
      for (int j = 0; j < 4; ++j) acc[i][j] = fmaf(a[i], b[j], acc[i][j]);
  }
}

__device__ __forceinline__ void load_a_tile(const float* A, int lda, int m0, int k0,
                                            int tid, float (*As)[68]) {
  const int r = tid >> 2, kq = tid & 3;
  const float4 a4 = *(const float4*)(A + (size_t)(m0 + r) * lda + k0 + kq * 4);
  As[kq * 4 + 0][r] = a4.x;
  As[kq * 4 + 1][r] = a4.y;
  As[kq * 4 + 2][r] = a4.z;
  As[kq * 4 + 3][r] = a4.w;
}

__device__ __forceinline__ void load_b_nn(const float* B, int ldb, int k0, int n0,
                                          int tid, float (*Bs)[68]) {
  const int kr = tid >> 4, c4 = tid & 15;
  const float4 b4 = *(const float4*)(B + (size_t)(k0 + kr) * ldb + n0 + c4 * 4);
  *(float4*)&Bs[kr][c4 * 4] = b4;
}

__global__ __launch_bounds__(256) void gemm_nn64(const float* __restrict__ A, int lda,
                                                 long long strideA,
                                                 const float* __restrict__ B, long long strideB,
                                                 float* __restrict__ C, long long strideC,
                                                 int kchunk) {
  const int bz = blockIdx.z;
  A += (size_t)bz * strideA;
  B += (size_t)bz * strideB;
  C += (size_t)bz * strideC;
  const int m0 = blockIdx.x * 64;
  const int tid = threadIdx.x, tr = tid >> 4, tc = tid & 15;
  __shared__ float As[16][68], Bs[16][68];
  float acc[4][4] = {};
  for (int k0 = 0; k0 < kchunk; k0 += 16) {
    load_a_tile(A, lda, m0, k0, tid, As);
    load_b_nn(B, DH_, k0, 0, tid, Bs);
    __syncthreads();
    mm_step(As, Bs, tr, tc, acc);
    __syncthreads();
  }
#pragma unroll
  for (int i = 0; i < 4; ++i) {
    const int row = m0 + tr * 4 + i;
    *(float4*)(C + (size_t)row * DH_ + tc * 4) =
        make_float4(acc[i][0], acc[i][1], acc[i][2], acc[i][3]);
  }
}

// ---------------- a3 flash: PV B-frags from global vtb ----------------
__global__ __launch_bounds__(256) void a3_flash(const short* __restrict__ qlb,
                                                const short* __restrict__ kb,
                                                const short* __restrict__ vtb,
                                                float* __restrict__ Opart,
                                                float* __restrict__ mpart,
                                                float* __restrict__ lpart) {
  const int chunk = blockIdx.x, rt = blockIdx.y, bh = blockIdx.z;
  __shared__ short qs[64 * 80], ks[64 * 80], ps[64 * 80];
  const int tid = threadIdx.x, wave = tid >> 6, lane = tid & 63;
  const int mi = lane & 15, quad = lane >> 4;
#pragma unroll
  for (int i = 0; i < 2; ++i) {
    const int c = tid * 2 + i, row = c >> 3, col = (c & 7) * 8;
    *(bf16x8*)&qs[row * 80 + col] =
        *(const bf16x8*)(qlb + ((size_t)bh * M_ + rt * 64 + row) * DH_ + col);
  }
  __syncthreads();
  const bf16x8 aq0 = *(const bf16x8*)&qs[(wave * 16 + mi) * 80 + quad * 8];
  const bf16x8 aq1 = *(const bf16x8*)&qs[(wave * 16 + mi) * 80 + 32 + quad * 8];
  float m[4] = {-INFINITY, -INFINITY, -INFINITY, -INFINITY};
  float l[4] = {0.f, 0.f, 0.f, 0.f};
  f32x4 o[4] = {};
  for (int t = 0; t < 16; ++t) {
    const int n0 = chunk * 1024 + t * 64;
#pragma unroll
    for (int i = 0; i < 2; ++i) {
      const int c = tid * 2 + i, row = c >> 3, col = (c & 7) * 8;
      *(bf16x8*)&ks[row * 80 + col] =
          *(const bf16x8*)(kb + ((size_t)bh * N_ + n0 + row) * DH_ + col);
    }
    __syncthreads();
    f32x4 s[4];
#pragma unroll
    for (int j = 0; j < 4; ++j) {
      const bf16x8 b0 = *(const bf16x8*)&ks[(j * 16 + mi) * 80 + quad * 8];
      const bf16x8 b1 = *(const bf16x8*)&ks[(j * 16 + mi) * 80 + 32 + quad * 8];
      f32x4 z = {0.f, 0.f, 0.f, 0.f};
      z = __builtin_amdgcn_mfma_f32_16x16x32_bf16(aq0, b0, z, 0, 0, 0);
      s[j] = __builtin_amdgcn_mfma_f32_16x16x32_bf16(aq1, b1, z, 0, 0, 0);
    }
    float alpha[4];
#pragma unroll
    for (int r = 0; r < 4; ++r) {
      float v = fmaxf(fmaxf(s[0][r], s[1][r]), fmaxf(s[2][r], s[3][r]));
      v = fmaxf(v, __shfl_xor(v, 1, 64));
      v = fmaxf(v, __shfl_xor(v, 2, 64));
      v = fmaxf(v, __shfl_xor(v, 4, 64));
      v = fmaxf(v, __shfl_xor(v, 8, 64));
      const float mnew = fmaxf(m[r], v);
      alpha[r] = __expf(m[r] - mnew);
      m[r] = mnew;
    }
    float rs[4] = {0.f, 0.f, 0.f, 0.f};
#pragma unroll
    for (int j = 0; j < 4; ++j)
#pragma unroll
      for (int r = 0; r < 4; ++r) {
        const float p = __expf(s[j][r] - m[r]);
        rs[r] += p;
        ps[(wave * 16 + quad * 4 + r) * 80 + j * 16 + mi] = f2bf(p);
      }
#pragma unroll
    for (int r = 0; r < 4; ++r) {
      float v = rs[r];
      v += __shfl_xor(v, 1, 64);
      v += __shfl_xor(v, 2, 64);
      v += __shfl_xor(v, 4, 64);
      v += __shfl_xor(v, 8, 64);
      l[r] = l[r] * alpha[r] + v;
#pragma unroll
      for (int j = 0; j < 4; ++j) o[j][r] *= alpha[r];
    }
    __syncthreads();
    const bf16x8 ap0 = *(const bf16x8*)&ps[(wave * 16 + mi) * 80 + quad * 8];
    const bf16x8 ap1 = *(const bf16x8*)&ps[(wave * 16 + mi) * 80 + 32 + quad * 8];
#pragma unroll
    for (int j = 0; j < 4; ++j) {
      const short* vp = vtb + ((size_t)bh * DH_ + j * 16 + mi) * N_ + n0;
      const bf16x8 b0 = *(const bf16x8*)(vp + quad * 8);
      const bf16x8 b1 = *(const bf16x8*)(vp + 32 + quad * 8);
      o[j] = __builtin_amdgcn_mfma_f32_16x16x32_bf16(ap0, b0, o[j], 0, 0, 0);
      o[j] = __builtin_amdgcn_mfma_f32_16x16x32_bf16(ap1, b1, o[j], 0, 0, 0);
    }
    __syncthreads();
  }
  const int p2 = bh * 4 + rt;
  float* Ob = Opart + ((size_t)chunk * 64 + p2) * 4096;
#pragma unroll
  for (int j = 0; j < 4; ++j)
#pragma unroll
    for (int r = 0; r < 4; ++r)
      Ob[(wave * 16 + quad * 4 + r) * 64 + j * 16 + mi] = o[j][r];
  if (mi == 0) {
#pragma unroll
    for (int r = 0; r < 4; ++r) {
      mpart[((size_t)chunk * 64 + p2) * 64 + wave * 16 + quad * 4 + r] = m[r];
      lpart[((size_t)chunk * 64 + p2) * 64 + wave * 16 + quad * 4 + r] = l[r];
    }
  }
}

__global__ __launch_bounds__(256) void a3_combine(const float* __restrict__ Opart,
                                                  const float* __restrict__ mpart,
                                                  const float* __restrict__ lpart,
                                                  float* __restrict__ a3v) {
  const int p2 = blockIdx.x;
  const int bh = p2 >> 2, rt = p2 & 3;
  __shared__ float wgt[8][64];
  const int tid = threadIdx.x;
  if (tid < 64) {
    float mg = -INFINITY;
    for (int c = 0; c < 8; ++c) mg = fmaxf(mg, mpart[((size_t)c * 64 + p2) * 64 + tid]);
    float e[8], lg = 0.f;
    for (int c = 0; c < 8; ++c) {
      e[c] = __expf(mpart[((size_t)c * 64 + p2) * 64 + tid] - mg);
      lg += lpart[((size_t)c * 64 + p2) * 64 + tid] * e[c];
    }
    const float inv = 1.f / lg;
    for (int c = 0; c < 8; ++c) wgt[c][tid] = e[c] * inv;
  }
  __syncthreads();
  for (int i = tid; i < 4096; i += 256) {
    const int row = i >> 6, d = i & 63;
    float s = 0.f;
    for (int c = 0; c < 8; ++c) s += Opart[((size_t)c * 64 + p2) * 4096 + i] * wgt[c][row];
    a3v[((size_t)bh * M_ + rt * 64 + row) * DH_ + d] = s;
  }
}

// ---------------- w2 fp32 -> w2t bf16 ----------------
__global__ __launch_bounds__(256) void w2t_kernel(const float* __restrict__ w2,
                                                  short* __restrict__ w2tb) {
  const int bh = blockIdx.x, tid = threadIdx.x;
  for (int i = tid; i < M_ * DH_; i += 256) {
    const int r = i >> 6, d = i & 63;
    w2tb[((size_t)bh * DH_ + d) * M_ + r] = f2bf(w2[(size_t)bh * M_ * DH_ + i]);
  }
}

// ---------------- a1 fused: omb = softmax(q @ kl^T) @ w2 + Band@Vc (conv) ----------------
// LDS: ps[64][264] + band[64][104]; q/kl/w2t/vT fragments straight from global (L1/L2)
__global__ __launch_bounds__(256) void a1_conv(const short* __restrict__ qb,
                                               const short* __restrict__ klb,
                                               const short* __restrict__ w2tb,
                                               const short* __restrict__ vtb,
                                               const float* __restrict__ rk,
                                               short* __restrict__ omb) {
  __shared__ short ps[64 * 264];
  __shared__ short band[64 * 104];
  const int bh = blockIdx.y, t0 = blockIdx.x * 64;
  const int b = bh >> 3, h = bh & 7;
  const int tid = threadIdx.x, wave = tid >> 6, lane = tid & 63;
  const int mi = lane & 15, quad = lane >> 4;
  // band[r][c] = rk[c-r] where valid AND source token in range (edge zeroing)
  {
    const int r = tid >> 2, cb = (tid & 3) * 24;
#pragma unroll
    for (int e = 0; e < 24; ++e) {
      const int c = cb + e, u = c - r, tg = t0 - 16 + c;
      band[r * 104 + c] =
          (u >= 0 && u < KC_ && tg >= 0 && tg < N_) ? f2bf(rk[h * KC_ + u]) : (short)0;
    }
  }
  // q A-frags direct from global
  const short* qrow = qb + ((size_t)bh * N_ + t0 + wave * 16 + mi) * DH_;
  const bf16x8 aq0 = *(const bf16x8*)(qrow + quad * 8);
  const bf16x8 aq1 = *(const bf16x8*)(qrow + 32 + quad * 8);
  // S = q @ kl^T
  f32x4 s[16];
#pragma unroll
  for (int f = 0; f < 16; ++f) {
    const short* kp = klb + ((size_t)bh * M_ + f * 16 + mi) * DH_;
    const bf16x8 b0 = *(const bf16x8*)(kp + quad * 8);
    const bf16x8 b1 = *(const bf16x8*)(kp + 32 + quad * 8);
    f32x4 z = {0.f, 0.f, 0.f, 0.f};
    z = __builtin_amdgcn_mfma_f32_16x16x32_bf16(aq0, b0, z, 0, 0, 0);
    s[f] = __builtin_amdgcn_mfma_f32_16x16x32_bf16(aq1, b1, z, 0, 0, 0);
  }
  // exact softmax over 256 cols
  float inv[4];
#pragma unroll
  for (int r = 0; r < 4; ++r) {
    float v = s[0][r];
#pragma unroll
    for (int f = 1; f < 16; ++f) v = fmaxf(v, s[f][r]);
    v = fmaxf(v, __shfl_xor(v, 1, 64));
    v = fmaxf(v, __shfl_xor(v, 2, 64));
    v = fmaxf(v, __shfl_xor(v, 4, 64));
    v = fmaxf(v, __shfl_xor(v, 8, 64));
    float sum = 0.f;
#pragma unroll
    for (int f = 0; f < 16; ++f) {
      const float p = __expf(s[f][r] - v);
      s[f][r] = p;
      sum += p;
    }
    sum += __shfl_xor(sum, 1, 64);
    sum += __shfl_xor(sum, 2, 64);
    sum += __shfl_xor(sum, 4, 64);
    sum += __shfl_xor(sum, 8, 64);
    inv[r] = 1.f / sum;
  }
#pragma unroll
  for (int f = 0; f < 16; ++f)
#pragma unroll
    for (int r = 0; r < 4; ++r)
      ps[(wave * 16 + quad * 4 + r) * 264 + f * 16 + mi] = f2bf(s[f][r] * inv[r]);
  __syncthreads();
  // O = P @ w2 + Band @ Vc
  f32x4 o[4] = {};
#pragma unroll
  for (int k0 = 0; k0 < 8; ++k0) {
    const bf16x8 ap = *(const bf16x8*)&ps[(wave * 16 + mi) * 264 + k0 * 32 + quad * 8];
#pragma unroll
    for (int j = 0; j < 4; ++j) {
      const bf16x8 bw =
          *(const bf16x8*)(w2tb + ((size_t)bh * DH_ + j * 16 + mi) * M_ + k0 * 32 + quad * 8);
      o[j] = __builtin_amdgcn_mfma_f32_16x16x32_bf16(ap, bw, o[j], 0, 0, 0);
    }
  }
#pragma unroll
  for (int ks = 0; ks < 3; ++ks) {
    const bf16x8 ab = *(const bf16x8*)&band[(wave * 16 + mi) * 104 + ks * 32 + quad * 8];
    int tcol = t0 - 16 + ks * 32 + quad * 8;
    tcol = tcol < 0 ? 0 : (tcol > N_ - 8 ? N_ - 8 : tcol);  // OOB columns have zero band coeff
#pragma unroll
    for (int j = 0; j < 4; ++j) {
      const bf16x8 bv = *(const bf16x8*)(vtb + ((size_t)bh * DH_ + j * 16 + mi) * N_ + tcol);
      o[j] = __builtin_amdgcn_mfma_f32_16x16x32_bf16(ab, bv, o[j], 0, 0, 0);
    }
  }
#pragma unroll
  for (int j = 0; j < 4; ++j) {
    const int d = j * 16 + mi;
#pragma unroll
    for (int r = 0; r < 4; ++r) {
      const int t = t0 + wave * 16 + quad * 4 + r;
      omb[((size_t)(b * N_ + t)) * DIM_ + h * DH_ + d] = f2bf(o[j][r]);
    }
  }
}

extern "C" void kernel_launch(void* const* d_in, const int* in_sizes, int n_in,
                              void* d_out, int out_size, void* d_ws, size_t ws_size,
                              hipStream_t stream) {
  (void)in_sizes; (void)n_in; (void)out_size;
  const float* x = (const float*)d_in[0];
  const float* gamma = (const float*)d_in[1];
  const float* beta = (const float*)d_in[2];
  const float* wqkv = (const float*)d_in[3];
  const float* wout = (const float*)d_in[4];
  const float* bout = (const float*)d_in[5];
  const float* rk = (const float*)d_in[6];
  float* y = (float*)d_out;
  float* ws = (float*)d_ws;

  size_t o = 0;
  short* xnb = (short*)(ws + o);   o += (size_t)2 * N_ * DIM_ / 2;
  short* wqkvt = (short*)(ws + o); o += (size_t)3 * DIM_ * DIM_ / 2;
  short* woutt = (short*)(ws + o); o += (size_t)DIM_ * DIM_ / 2;
  short* qb = (short*)(ws + o);    o += (size_t)BH_ * N_ * DH_ / 2;
  short* kb = (short*)(ws + o);    o += (size_t)BH_ * N_ * DH_ / 2;
  short* vb = (short*)(ws + o);    o += (size_t)BH_ * N_ * DH_ / 2;
  short* vtb = (short*)(ws + o);   o += (size_t)BH_ * N_ * DH_ / 2;
  float* ql = ws + o;  o += (size_t)BH_ * M_ * DH_;
  float* kl = ws + o;  o += (size_t)BH_ * M_ * DH_;
  short* qlb = (short*)(ws + o); o += (size_t)BH_ * M_ * DH_ / 2;
  short* klb = (short*)(ws + o); o += (size_t)BH_ * M_ * DH_ / 2;
  float* a2 = ws + o;  o += (size_t)BH_ * M_ * M_;
  float* z0f = ws + o; o += (size_t)BH_ * M_ * M_;
  short* a2b = (short*)(ws + o); o += (size_t)BH_ * M_ * M_ / 2;
  short* zb0 = (short*)(ws + o); o += (size_t)BH_ * M_ * M_ / 2;
  short* zb1 = (short*)(ws + o); o += (size_t)BH_ * M_ * M_ / 2;
  short* yb0 = (short*)(ws + o); o += (size_t)BH_ * M_ * M_ / 2;
  short* yb1 = (short*)(ws + o); o += (size_t)BH_ * M_ * M_ / 2;
  short* p1b = (short*)(ws + o); o += (size_t)BH_ * M_ * M_ / 2;
  short* y2b = (short*)(ws + o); o += (size_t)BH_ * M_ * M_ / 2;
  short* wb  = (short*)(ws + o); o += (size_t)BH_ * M_ * M_ / 2;
  float* Opart = ws + o; o += (size_t)8 * 64 * 4096;
  float* mpart = ws + o; o += (size_t)8 * 64 * 64;
  float* lpart = ws + o; o += (size_t)8 * 64 * 64;
  float* a3v = ws + o; o += (size_t)BH_ * M_ * DH_;
  float* w2 = ws + o;  o += (size_t)BH_ * M_ * DH_;
  short* w2tb = (short*)(ws + o); o += (size_t)BH_ * M_ * DH_ / 2;
  short* omb = (short*)(ws + o);  o += (size_t)2 * N_ * DIM_ / 2;
  unsigned int* scalebits = (unsigned int*)(ws + o); o += 16;
  if (ws_size < o * sizeof(float)) return;

  (void)hipMemsetAsync(scalebits, 0, 64, stream);
  ln_kernel<<<2 * N_, 128, 0, stream>>>(x, gamma, beta, xnb);
  convt_kernel<<<dim3(3 * DIM_ / 32, DIM_ / 32), 256, 0, stream>>>(wqkv, wqkvt, DIM_, 3 * DIM_);
  convt_kernel<<<dim3(DIM_ / 32, DIM_ / 32), 256, 0, stream>>>(wout, woutt, DIM_, DIM_);
  qkv_mfma<<<dim3(2 * N_ / 128, 3 * DIM_ / 128), 256, 0, stream>>>(xnb, wqkvt, qb, kb, vb);
  vt_kernel<<<dim3(N_ / 32, 2, BH_), 256, 0, stream>>>(vb, vtb);

  landmark_kernel<<<BH_ * M_ * DH_ / 256, 256, 0, stream>>>(qb, kb, ql, kl, qlb, klb);
  sim2_softmax<<<dim3(M_, BH_), 256, 0, stream>>>(ql, kl, a2, a2b);
  colmax_kernel<<<BH_, 256, 0, stream>>>(a2, scalebits);
  transpose_scale<<<BH_ * M_ * M_ / 256, 256, 0, stream>>>(a2, zb0, scalebits);

  // a3 flash (independent of pinv)
  a3_flash<<<dim3(8, 4, BH_), 256, 0, stream>>>(qlb, kb, vtb, Opart, mpart, lpart);
  a3_combine<<<64, 256, 0, stream>>>(Opart, mpart, lpart, a3v);

  // Newton-Schulz, 2 dependent launches/iter:
  //   stageA: p1 = z@y ; y2 = y@y, w = 1.75y - 0.25y2
  //   stageB: z' = 3.25z - 3.75p1 + p1@w ; y' = 3.25y - 3.75y2 + y2@w
  ns_gemm0<<<dim3(16, BH_), 256, 0, stream>>>(a2b, zb0, yb0);
  short* zc = zb0; short* zn = zb1; short* yc = yb0; short* yn = yb1;
  for (int it = 0; it < 6; ++it) {
    const int last = (it == 5);
    ns_stageA<<<dim3(16, 2 * BH_), 256, 0, stream>>>(zc, yc, p1b, y2b, wb);
    ns_stageB<<<dim3(16, last ? BH_ : 2 * BH_), 256, 0, stream>>>(
        p1b, y2b, wb, zc, yc, zn, yn, last ? z0f : nullptr, last);
    short* t;
    t = zc; zc = zn; zn = t;
    t = yc; yc = yn; yn = t;
  }

  // w2 = z @ a3v (fp32), transpose to bf16
  gemm_nn64<<<dim3(M_ / 64, 1, BH_), 256, 0, stream>>>(
      z0f, M_, (long long)M_ * M_, a3v, (long long)M_ * DH_, w2, (long long)M_ * DH_, M_);
  w2t_kernel<<<BH_, 256, 0, stream>>>(w2, w2tb);

  // fused a1 @ w2 + band-MFMA depthwise conv -> omb bf16
  a1_conv<<<dim3(N_ / 64, BH_), 256, 0, stream>>>(qb, klb, w2tb, vtb, rk, omb);

  final_mfma<<<dim3(2 * N_ / 128, DIM_ / 128), 256, 0, stream>>>(omb, woutt, x, bout, y);
}

// Round 7
// 507.378 us; speedup vs baseline: 3.5899x; 1.0542x over previous
//
#include <hip/hip_runtime.h>
#include <math.h>

#define H_ 8
#define DH_ 64
#define DIM_ 512
#define M_ 256
#define N_ 8192
#define BH_ 16
#define LG_ 32
#define KC_ 33
#define PADC_ 16

typedef __attribute__((ext_vector_type(8))) short bf16x8;
typedef __attribute__((ext_vector_type(4))) short s16x4;
typedef __attribute__((ext_vector_type(4))) float f32x4;

__device__ __forceinline__ short f2bf(float f) {
  unsigned u = __float_as_uint(f);
  unsigned r = (u + 0x7FFF + ((u >> 16) & 1)) >> 16;  // RNE
  return (short)r;
}
__device__ __forceinline__ float bf2f(short s) {
  return __uint_as_float(((unsigned)(unsigned short)s) << 16);
}

// =================== bf16 MFMA NT core (128x128 tile) ===================
__device__ __forceinline__ void mfma_nt_core(const short* __restrict__ A,
                                             const short* __restrict__ Bt, int K,
                                             int m0, int n0, size_t lda, size_t ldb,
                                             f32x4 acc[4][4], short* As, short* Bs) {
  const int tid = threadIdx.x;
  const int wave = tid >> 6, lane = tid & 63;
  const int wr = (wave >> 1) * 64, wc = (wave & 1) * 64;
  const int mi = lane & 15, quad = lane >> 4;
  for (int k0 = 0; k0 < K; k0 += 32) {
#pragma unroll
    for (int t = 0; t < 2; ++t) {
      const int cbase = (t * 4 + wave) * 64;
      const int chunk = cbase + lane;
      const int row = chunk >> 2, cc = (chunk & 3) * 8;
      __builtin_amdgcn_global_load_lds(
          (const __attribute__((address_space(1))) void*)(A + (size_t)(m0 + row) * lda + k0 + cc),
          (__attribute__((address_space(3))) void*)(As + (size_t)cbase * 8), 16, 0, 0);
      __builtin_amdgcn_global_load_lds(
          (const __attribute__((address_space(1))) void*)(Bt + (size_t)(n0 + row) * ldb + k0 + cc),
          (__attribute__((address_space(3))) void*)(Bs + (size_t)cbase * 8), 16, 0, 0);
    }
    __syncthreads();
    bf16x8 af[4], bf[4];
#pragma unroll
    for (int i = 0; i < 4; ++i)
      af[i] = *(const bf16x8*)&As[(wr + i * 16 + mi) * 32 + quad * 8];
#pragma unroll
    for (int j = 0; j < 4; ++j)
      bf[j] = *(const bf16x8*)&Bs[(wc + j * 16 + mi) * 32 + quad * 8];
#pragma unroll
    for (int i = 0; i < 4; ++i)
#pragma unroll
      for (int j = 0; j < 4; ++j)
        acc[i][j] = __builtin_amdgcn_mfma_f32_16x16x32_bf16(af[i], bf[j], acc[i][j], 0, 0, 0);
    __syncthreads();
  }
}

// QKV GEMM -> bf16 q/k/v (bh,n,d), q scaled
__global__ __launch_bounds__(256) void qkv_mfma(const short* __restrict__ xnb,
                                                const short* __restrict__ wt,
                                                short* __restrict__ qb, short* __restrict__ kb,
                                                short* __restrict__ vb) {
  __shared__ short As[128 * 32], Bs[128 * 32];
  f32x4 acc[4][4] = {};
  const int m0 = blockIdx.x * 128, n0 = blockIdx.y * 128;
  mfma_nt_core(xnb, wt, DIM_, m0, n0, DIM_, DIM_, acc, As, Bs);
  const int wave = threadIdx.x >> 6, lane = threadIdx.x & 63;
  const int wr = (wave >> 1) * 64, wc = (wave & 1) * 64;
  const int mi = lane & 15, quad = lane >> 4;
  const int which = n0 >> 9;
  short* dst = which == 0 ? qb : which == 1 ? kb : vb;
  const float sc = which == 0 ? 0.125f : 1.0f;
#pragma unroll
  for (int j = 0; j < 4; ++j) {
    const int col = n0 + wc + j * 16 + mi;
    const int h = (col >> 6) & 7, d = col & 63;
#pragma unroll
    for (int i = 0; i < 4; ++i) {
#pragma unroll
      for (int r = 0; r < 4; ++r) {
        const int row = m0 + wr + i * 16 + quad * 4 + r;
        const int b = row >> 13, t = row & (N_ - 1);
        dst[((size_t)(b * H_ + h) * N_ + t) * DH_ + d] = f2bf(acc[i][j][r] * sc);
      }
    }
  }
}

// final: y = x + omb @ woutt^T + b_out
__global__ __launch_bounds__(256) void final_mfma(const short* __restrict__ omb,
                                                  const short* __restrict__ wt,
                                                  const float* __restrict__ x,
                                                  const float* __restrict__ bout,
                                                  float* __restrict__ y) {
  __shared__ short As[128 * 32], Bs[128 * 32];
  f32x4 acc[4][4] = {};
  const int m0 = blockIdx.x * 128, n0 = blockIdx.y * 128;
  mfma_nt_core(omb, wt, DIM_, m0, n0, DIM_, DIM_, acc, As, Bs);
  const int wave = threadIdx.x >> 6, lane = threadIdx.x & 63;
  const int wr = (wave >> 1) * 64, wc = (wave & 1) * 64;
  const int mi = lane & 15, quad = lane >> 4;
#pragma unroll
  for (int j = 0; j < 4; ++j) {
    const int col = n0 + wc + j * 16 + mi;
    const float bo = bout[col];
#pragma unroll
    for (int i = 0; i < 4; ++i) {
#pragma unroll
      for (int r = 0; r < 4; ++r) {
        const int row = m0 + wr + i * 16 + quad * 4 + r;
        y[(size_t)row * DIM_ + col] = acc[i][j][r] + x[(size_t)row * DIM_ + col] + bo;
      }
    }
  }
}

// fp32 (K x N) -> bf16 transposed (N x K)
__global__ __launch_bounds__(256) void convt_kernel(const float* __restrict__ in,
                                                    short* __restrict__ out, int K, int N) {
  __shared__ float tile[32][33];
  const int n0 = blockIdx.x * 32, k0 = blockIdx.y * 32;
  const int tx = threadIdx.x & 31, ty = threadIdx.x >> 5;
  for (int r = ty; r < 32; r += 8) tile[r][tx] = in[(size_t)(k0 + r) * N + n0 + tx];
  __syncthreads();
  for (int r = ty; r < 32; r += 8) out[(size_t)(n0 + r) * K + k0 + tx] = f2bf(tile[tx][r]);
}

// bf16 v (bh,t,d) -> vtb (bh,d,t): 32x32 LDS tiles, conflict-free (+1 pad)
__global__ __launch_bounds__(256) void vt_kernel(const short* __restrict__ vb,
                                                 short* __restrict__ vtb) {
  __shared__ short tile[32][33];
  const int t0 = blockIdx.x * 32, d0 = blockIdx.y * 32, bh = blockIdx.z;
  const int tx = threadIdx.x & 31, ty = threadIdx.x >> 5;
  for (int r = ty; r < 32; r += 8)
    tile[r][tx] = vb[((size_t)bh * N_ + t0 + r) * DH_ + d0 + tx];
  __syncthreads();
  for (int r = ty; r < 32; r += 8)
    vtb[((size_t)bh * DH_ + d0 + r) * N_ + t0 + tx] = tile[tx][r];
}

// ---------------- LayerNorm -> bf16 ----------------
__global__ __launch_bounds__(128) void ln_kernel(const float* __restrict__ x,
                                                 const float* __restrict__ gamma,
                                                 const float* __restrict__ beta,
                                                 short* __restrict__ xnb) {
  const int row = blockIdx.x, tid = threadIdx.x;
  const float4 v = ((const float4*)(x + (size_t)row * DIM_))[tid];
  float s = v.x + v.y + v.z + v.w;
  float ss = v.x * v.x + v.y * v.y + v.z * v.z + v.w * v.w;
  __shared__ float r1[128], r2[128];
  r1[tid] = s;
  r2[tid] = ss;
  __syncthreads();
  for (int off = 64; off > 0; off >>= 1) {
    if (tid < off) {
      r1[tid] += r1[tid + off];
      r2[tid] += r2[tid + off];
    }
    __syncthreads();
  }
  const float mu = r1[0] * (1.0f / DIM_);
  const float var = r2[0] * (1.0f / DIM_) - mu * mu;
  const float rs = rsqrtf(var + 1e-5f);
  const float4 g = ((const float4*)gamma)[tid];
  const float4 bb = ((const float4*)beta)[tid];
  s16x4 o = {f2bf((v.x - mu) * rs * g.x + bb.x), f2bf((v.y - mu) * rs * g.y + bb.y),
             f2bf((v.z - mu) * rs * g.z + bb.z), f2bf((v.w - mu) * rs * g.w + bb.w)};
  ((s16x4*)(xnb + (size_t)row * DIM_))[tid] = o;
}

// ---------------- landmarks ----------------
__global__ __launch_bounds__(256) void landmark_kernel(const short* __restrict__ qb,
                                                       const short* __restrict__ kb,
                                                       float* __restrict__ ql,
                                                       float* __restrict__ kl,
                                                       short* __restrict__ qlb,
                                                       short* __restrict__ klb) {
  const int idx = blockIdx.x * 256 + threadIdx.x;
  const int d = idx & (DH_ - 1);
  const int m = (idx >> 6) & (M_ - 1);
  const int bh = idx >> 14;
  const size_t base = ((size_t)bh * N_ + m * LG_) * DH_ + d;
  float sq = 0.f, sk = 0.f;
#pragma unroll 8
  for (int t = 0; t < LG_; ++t) {
    sq += bf2f(qb[base + (size_t)t * DH_]);
    sk += bf2f(kb[base + (size_t)t * DH_]);
  }
  sq *= (1.0f / LG_);
  sk *= (1.0f / LG_);
  ql[idx] = sq;
  kl[idx] = sk;
  qlb[idx] = f2bf(sq);
  klb[idx] = f2bf(sk);
}

// ---------------- sim2 + softmax ----------------
__global__ __launch_bounds__(256) void sim2_softmax(const float* __restrict__ ql,
                                                    const float* __restrict__ kl,
                                                    float* __restrict__ a2,
                                                    short* __restrict__ a2b) {
  const int i = blockIdx.x, bh = blockIdx.y, j = threadIdx.x;
  __shared__ float qrow[DH_];
  if (j < DH_) qrow[j] = ql[((size_t)bh * M_ + i) * DH_ + j];
  __syncthreads();
  const float* kr = kl + ((size_t)bh * M_ + j) * DH_;
  float s = 0.f;
#pragma unroll 16
  for (int d = 0; d < DH_; ++d) s += qrow[d] * kr[d];
  __shared__ float red[256];
  red[j] = s;
  __syncthreads();
  for (int off = 128; off > 0; off >>= 1) {
    if (j < off) red[j] = fmaxf(red[j], red[j + off]);
    __syncthreads();
  }
  const float mx = red[0];
  __syncthreads();
  const float e = expf(s - mx);
  red[j] = e;
  __syncthreads();
  for (int off = 128; off > 0; off >>= 1) {
    if (j < off) red[j] += red[j + off];
    __syncthreads();
  }
  const float out = e / red[0];
  a2[((size_t)bh * M_ + i) * M_ + j] = out;
  a2b[((size_t)bh * M_ + i) * M_ + j] = f2bf(out);
}

__global__ __launch_bounds__(256) void colmax_kernel(const float* __restrict__ a2,
                                                     unsigned int* __restrict__ scalebits) {
  const int bh = blockIdx.x, j = threadIdx.x;
  const float* mat = a2 + (size_t)bh * M_ * M_;
  float s = 0.f;
  for (int i = 0; i < M_; ++i) s += fabsf(mat[i * M_ + j]);
  __shared__ float red[256];
  red[j] = s;
  __syncthreads();
  for (int off = 128; off > 0; off >>= 1) {
    if (j < off) red[j] = fmaxf(red[j], red[j + off]);
    __syncthreads();
  }
  if (j == 0) atomicMax(scalebits, __float_as_uint(red[0]));
}

// z0b = bf16(a2^T / scale)
__global__ __launch_bounds__(256) void transpose_scale(const float* __restrict__ a2,
                                                       short* __restrict__ z0b,
                                                       const unsigned int* __restrict__ scalebits) {
  const float inv = 1.0f / __uint_as_float(*scalebits);
  const int idx = blockIdx.x * 256 + threadIdx.x;
  const int j = idx & (M_ - 1), i = (idx >> 8) & (M_ - 1), bh = idx >> 16;
  z0b[idx] = f2bf(a2[((size_t)bh * M_ + j) * M_ + i] * inv);
}

// ============ Newton-Schulz bf16 MFMA machinery (64x64 tiles of 256^2, K=256) ============
__device__ __forceinline__ void ns_core(const short* __restrict__ A, const short* __restrict__ B,
                                        int m0, int n0, short* As, short* Bs, f32x4 acc[4]) {
  const int tid = threadIdx.x, wave = tid >> 6, lane = tid & 63;
  const int mi = lane & 15, quad = lane >> 4;
  const int arow = tid >> 2, acol = (tid & 3) * 8;
  const int bkk = tid & 31, g = tid >> 5;
  for (int k0 = 0; k0 < M_; k0 += 32) {
    __builtin_amdgcn_global_load_lds(
        (const __attribute__((address_space(1))) void*)(A + (size_t)(m0 + arow) * M_ + k0 + acol),
        (__attribute__((address_space(3))) void*)(As + (size_t)wave * 512), 16, 0, 0);
    const bf16x8 bv = *(const bf16x8*)(B + (size_t)(k0 + bkk) * M_ + n0 + g * 8);
#pragma unroll
    for (int e = 0; e < 8; ++e) Bs[(g * 8 + e) * 44 + bkk] = bv[e];
    __syncthreads();
    const bf16x8 af = *(const bf16x8*)&As[(wave * 16 + mi) * 32 + quad * 8];
#pragma unroll
    for (int j = 0; j < 4; ++j) {
      union { bf16x8 v; s16x4 h[2]; } bfr;
      const short* bp = &Bs[(j * 16 + mi) * 44 + quad * 8];
      bfr.h[0] = *(const s16x4*)bp;
      bfr.h[1] = *(const s16x4*)(bp + 4);
      acc[j] = __builtin_amdgcn_mfma_f32_16x16x32_bf16(af, bfr.v, acc[j], 0, 0, 0);
    }
    __syncthreads();
  }
}

// y0 = A@B
__global__ __launch_bounds__(256) void ns_gemm0(const short* __restrict__ A,
                                                const short* __restrict__ B,
                                                short* __restrict__ C) {
  __shared__ short As[64 * 32], Bs[64 * 44];
  const int m0 = (blockIdx.x >> 2) * 64, n0 = (blockIdx.x & 3) * 64;
  const size_t mo = (size_t)blockIdx.y * (M_ * M_);
  f32x4 acc[4] = {};
  ns_core(A + mo, B + mo, m0, n0, As, Bs, acc);
  const int wave = threadIdx.x >> 6, lane = threadIdx.x & 63;
  const int mi = lane & 15, quad = lane >> 4;
#pragma unroll
  for (int j = 0; j < 4; ++j)
#pragma unroll
    for (int r = 0; r < 4; ++r) {
      const int row = m0 + wave * 16 + quad * 4 + r, col = n0 + j * 16 + mi;
      C[mo + (size_t)row * M_ + col] = f2bf(acc[j][r]);
    }
}

// stage A: sel0: p1 = z@y ; sel1: y2 = y@y, w = 1.75y - 0.25*y2
__global__ __launch_bounds__(256) void ns_stageA(const short* __restrict__ z,
                                                 const short* __restrict__ y,
                                                 short* __restrict__ p1,
                                                 short* __restrict__ y2,
                                                 short* __restrict__ w) {
  __shared__ short As[64 * 32], Bs[64 * 44];
  const int m0 = (blockIdx.x >> 2) * 64, n0 = (blockIdx.x & 3) * 64;
  const int sel = blockIdx.y & 1;
  const size_t mo = (size_t)(blockIdx.y >> 1) * (M_ * M_);
  f32x4 acc[4] = {};
  ns_core((sel ? y : z) + mo, y + mo, m0, n0, As, Bs, acc);
  const int wave = threadIdx.x >> 6, lane = threadIdx.x & 63;
  const int mi = lane & 15, quad = lane >> 4;
#pragma unroll
  for (int j = 0; j < 4; ++j)
#pragma unroll
    for (int r = 0; r < 4; ++r) {
      const int row = m0 + wave * 16 + quad * 4 + r, col = n0 + j * 16 + mi;
      const size_t idx = mo + (size_t)row * M_ + col;
      if (sel) {
        y2[idx] = f2bf(acc[j][r]);
        w[idx] = f2bf(1.75f * bf2f(y[idx]) - 0.25f * acc[j][r]);
      } else {
        p1[idx] = f2bf(acc[j][r]);
      }
    }
}

// stage B: sel0: zo = 3.25z - 3.75p1 + p1@w (opt fp32 out) ; sel1: yo = 3.25y - 3.75y2 + y2@w
__global__ __launch_bounds__(256) void ns_stageB(const short* __restrict__ p1,
                                                 const short* __restrict__ y2,
                                                 const short* __restrict__ w,
                                                 const short* __restrict__ z,
                                                 const short* __restrict__ y,
                                                 short* __restrict__ zo,
                                                 short* __restrict__ yo,
                                                 float* __restrict__ zf, int zonly) {
  __shared__ short As[64 * 32], Bs[64 * 44];
  const int m0 = (blockIdx.x >> 2) * 64, n0 = (blockIdx.x & 3) * 64;
  const int sel = zonly ? 0 : (blockIdx.y & 1);
  const size_t mo = (size_t)(zonly ? blockIdx.y : (blockIdx.y >> 1)) * (M_ * M_);
  f32x4 acc[4] = {};
  ns_core((sel ? y2 : p1) + mo, w + mo, m0, n0, As, Bs, acc);
  const int wave = threadIdx.x >> 6, lane = threadIdx.x & 63;
  const int mi = lane & 15, quad = lane >> 4;
#pragma unroll
  for (int j = 0; j < 4; ++j)
#pragma unroll
    for (int r = 0; r < 4; ++r) {
      const int row = m0 + wave * 16 + quad * 4 + r, col = n0 + j * 16 + mi;
      const size_t idx = mo + (size_t)row * M_ + col;
      if (sel) {
        yo[idx] = f2bf(3.25f * bf2f(y[idx]) - 3.75f * bf2f(y2[idx]) + acc[j][r]);
      } else {
        const float v = 3.25f * bf2f(z[idx]) - 3.75f * bf2f(p1[idx]) + acc[j][r];
        zo[idx] = f2bf(v);
        if (zf) zf[idx] = v;
      }
    }
}

// ---------------- fp32 64x64 core (w2 = z @ a3v only) ----------------
__device__ __forceinline__ void mm_step(float (*As)[68], float (*Bs)[68],
                                        int tr, int tc, float acc[4][4]) {
#pragma unroll
  for (int kk = 0; kk < 16; ++kk) {
    const float4 a4 = *(const float4*)&As[kk][tr * 4];
    const float4 b4 = *(const float4*)&Bs[kk][tc * 4];
    const float a[4] = {a4.x, a4.y, a4.z, a4.w};
    const float b[4] = {b4.x, b4.y, b4.z, b4.w};
#pragma unroll
    for (int i = 0; i < 4; ++i)
#pragma unroll
      for (int j = 0; j < 4; ++j) acc[i][j] = fmaf(a[i], b[j], acc[i][j]);
  }
}

__device__ __forceinline__ void load_a_tile(const float* A, int lda, int m0, int k0,
                                            int tid, float (*As)[68]) {
  const int r = tid >> 2, kq = tid & 3;
  const float4 a4 = *(const float4*)(A + (size_t)(m0 + r) * lda + k0 + kq * 4);
  As[kq * 4 + 0][r] = a4.x;
  As[kq * 4 + 1][r] = a4.y;
  As[kq * 4 + 2][r] = a4.z;
  As[kq * 4 + 3][r] = a4.w;
}

__device__ __forceinline__ void load_b_nn(const float* B, int ldb, int k0, int n0,
                                          int tid, float (*Bs)[68]) {
  const int kr = tid >> 4, c4 = tid & 15;
  const float4 b4 = *(const float4*)(B + (size_t)(k0 + kr) * ldb + n0 + c4 * 4);
  *(float4*)&Bs[kr][c4 * 4] = b4;
}

__global__ __launch_bounds__(256) void gemm_nn64(const float* __restrict__ A, int lda,
                                                 long long strideA,
                                                 const float* __restrict__ B, long long strideB,
                                                 float* __restrict__ C, long long strideC,
                                                 int kchunk) {
  const int bz = blockIdx.z;
  A += (size_t)bz * strideA;
  B += (size_t)bz * strideB;
  C += (size_t)bz * strideC;
  const int m0 = blockIdx.x * 64;
  const int tid = threadIdx.x, tr = tid >> 4, tc = tid & 15;
  __shared__ float As[16][68], Bs[16][68];
  float acc[4][4] = {};
  for (int k0 = 0; k0 < kchunk; k0 += 16) {
    load_a_tile(A, lda, m0, k0, tid, As);
    load_b_nn(B, DH_, k0, 0, tid, Bs);
    __syncthreads();
    mm_step(As, Bs, tr, tc, acc);
    __syncthreads();
  }
#pragma unroll
  for (int i = 0; i < 4; ++i) {
    const int row = m0 + tr * 4 + i;
    *(float4*)(C + (size_t)row * DH_ + tc * 4) =
        make_float4(acc[i][0], acc[i][1], acc[i][2], acc[i][3]);
  }
}

// ---------------- a3 flash: PV B-frags from global vtb ----------------
__global__ __launch_bounds__(256) void a3_flash(const short* __restrict__ qlb,
                                                const short* __restrict__ kb,
                                                const short* __restrict__ vtb,
                                                float* __restrict__ Opart,
                                                float* __restrict__ mpart,
                                                float* __restrict__ lpart) {
  const int chunk = blockIdx.x, rt = blockIdx.y, bh = blockIdx.z;
  __shared__ short qs[64 * 80], ks[64 * 80], ps[64 * 80];
  const int tid = threadIdx.x, wave = tid >> 6, lane = tid & 63;
  const int mi = lane & 15, quad = lane >> 4;
#pragma unroll
  for (int i = 0; i < 2; ++i) {
    const int c = tid * 2 + i, row = c >> 3, col = (c & 7) * 8;
    *(bf16x8*)&qs[row * 80 + col] =
        *(const bf16x8*)(qlb + ((size_t)bh * M_ + rt * 64 + row) * DH_ + col);
  }
  __syncthreads();
  const bf16x8 aq0 = *(const bf16x8*)&qs[(wave * 16 + mi) * 80 + quad * 8];
  const bf16x8 aq1 = *(const bf16x8*)&qs[(wave * 16 + mi) * 80 + 32 + quad * 8];
  float m[4] = {-INFINITY, -INFINITY, -INFINITY, -INFINITY};
  float l[4] = {0.f, 0.f, 0.f, 0.f};
  f32x4 o[4] = {};
  for (int t = 0; t < 16; ++t) {
    const int n0 = chunk * 1024 + t * 64;
#pragma unroll
    for (int i = 0; i < 2; ++i) {
      const int c = tid * 2 + i, row = c >> 3, col = (c & 7) * 8;
      *(bf16x8*)&ks[row * 80 + col] =
          *(const bf16x8*)(kb + ((size_t)bh * N_ + n0 + row) * DH_ + col);
    }
    __syncthreads();
    f32x4 s[4];
#pragma unroll
    for (int j = 0; j < 4; ++j) {
      const bf16x8 b0 = *(const bf16x8*)&ks[(j * 16 + mi) * 80 + quad * 8];
      const bf16x8 b1 = *(const bf16x8*)&ks[(j * 16 + mi) * 80 + 32 + quad * 8];
      f32x4 z = {0.f, 0.f, 0.f, 0.f};
      z = __builtin_amdgcn_mfma_f32_16x16x32_bf16(aq0, b0, z, 0, 0, 0);
      s[j] = __builtin_amdgcn_mfma_f32_16x16x32_bf16(aq1, b1, z, 0, 0, 0);
    }
    float alpha[4];
#pragma unroll
    for (int r = 0; r < 4; ++r) {
      float v = fmaxf(fmaxf(s[0][r], s[1][r]), fmaxf(s[2][r], s[3][r]));
      v = fmaxf(v, __shfl_xor(v, 1, 64));
      v = fmaxf(v, __shfl_xor(v, 2, 64));
      v = fmaxf(v, __shfl_xor(v, 4, 64));
      v = fmaxf(v, __shfl_xor(v, 8, 64));
      const float mnew = fmaxf(m[r], v);
      alpha[r] = __expf(m[r] - mnew);
      m[r] = mnew;
    }
    float rs[4] = {0.f, 0.f, 0.f, 0.f};
#pragma unroll
    for (int j = 0; j < 4; ++j)
#pragma unroll
      for (int r = 0; r < 4; ++r) {
        const float p = __expf(s[j][r] - m[r]);
        rs[r] += p;
        ps[(wave * 16 + quad * 4 + r) * 80 + j * 16 + mi] = f2bf(p);
      }
#pragma unroll
    for (int r = 0; r < 4; ++r) {
      float v = rs[r];
      v += __shfl_xor(v, 1, 64);
      v += __shfl_xor(v, 2, 64);
      v += __shfl_xor(v, 4, 64);
      v += __shfl_xor(v, 8, 64);
      l[r] = l[r] * alpha[r] + v;
#pragma unroll
      for (int j = 0; j < 4; ++j) o[j][r] *= alpha[r];
    }
    __syncthreads();
    const bf16x8 ap0 = *(const bf16x8*)&ps[(wave * 16 + mi) * 80 + quad * 8];
    const bf16x8 ap1 = *(const bf16x8*)&ps[(wave * 16 + mi) * 80 + 32 + quad * 8];
#pragma unroll
    for (int j = 0; j < 4; ++j) {
      const short* vp = vtb + ((size_t)bh * DH_ + j * 16 + mi) * N_ + n0;
      const bf16x8 b0 = *(const bf16x8*)(vp + quad * 8);
      const bf16x8 b1 = *(const bf16x8*)(vp + 32 + quad * 8);
      o[j] = __builtin_amdgcn_mfma_f32_16x16x32_bf16(ap0, b0, o[j], 0, 0, 0);
      o[j] = __builtin_amdgcn_mfma_f32_16x16x32_bf16(ap1, b1, o[j], 0, 0, 0);
    }
    __syncthreads();
  }
  const int p2 = bh * 4 + rt;
  float* Ob = Opart + ((size_t)chunk * 64 + p2) * 4096;
#pragma unroll
  for (int j = 0; j < 4; ++j)
#pragma unroll
    for (int r = 0; r < 4; ++r)
      Ob[(wave * 16 + quad * 4 + r) * 64 + j * 16 + mi] = o[j][r];
  if (mi == 0) {
#pragma unroll
    for (int r = 0; r < 4; ++r) {
      mpart[((size_t)chunk * 64 + p2) * 64 + wave * 16 + quad * 4 + r] = m[r];
      lpart[((size_t)chunk * 64 + p2) * 64 + wave * 16 + quad * 4 + r] = l[r];
    }
  }
}

__global__ __launch_bounds__(256) void a3_combine(const float* __restrict__ Opart,
                                                  const float* __restrict__ mpart,
                                                  const float* __restrict__ lpart,
                                                  float* __restrict__ a3v) {
  const int p2 = blockIdx.x;
  const int bh = p2 >> 2, rt = p2 & 3;
  __shared__ float wgt[8][64];
  const int tid = threadIdx.x;
  if (tid < 64) {
    float mg = -INFINITY;
    for (int c = 0; c < 8; ++c) mg = fmaxf(mg, mpart[((size_t)c * 64 + p2) * 64 + tid]);
    float e[8], lg = 0.f;
    for (int c = 0; c < 8; ++c) {
      e[c] = __expf(mpart[((size_t)c * 64 + p2) * 64 + tid] - mg);
      lg += lpart[((size_t)c * 64 + p2) * 64 + tid] * e[c];
    }
    const float inv = 1.f / lg;
    for (int c = 0; c < 8; ++c) wgt[c][tid] = e[c] * inv;
  }
  __syncthreads();
  for (int i = tid; i < 4096; i += 256) {
    const int row = i >> 6, d = i & 63;
    float s = 0.f;
    for (int c = 0; c < 8; ++c) s += Opart[((size_t)c * 64 + p2) * 4096 + i] * wgt[c][row];
    a3v[((size_t)bh * M_ + rt * 64 + row) * DH_ + d] = s;
  }
}

// ---------------- w2 fp32 -> w2t bf16 ----------------
__global__ __launch_bounds__(256) void w2t_kernel(const float* __restrict__ w2,
                                                  short* __restrict__ w2tb) {
  const int bh = blockIdx.x, tid = threadIdx.x;
  for (int i = tid; i < M_ * DH_; i += 256) {
    const int r = i >> 6, d = i & 63;
    w2tb[((size_t)bh * DH_ + d) * M_ + r] = f2bf(w2[(size_t)bh * M_ * DH_ + i]);
  }
}

// ---------------- a1 fused: omb = softmax(q @ kl^T) @ w2 + Band@Vwin (conv) ----------------
// LDS (34.5 KB -> 4 blocks/CU):
//   [0,16384)      kls[256][32]   (K-chunk staging, glds m97 pattern; dead after S)
//   [0,14848)      vwin[64][116]  (V^T window, zero-padded; built after S)
//   [14848,17024)  band[16][68]   (Toeplitz conv tile, shared by all waves)
//   [17408,35328)  ps[64][140]    (half of P at a time; stride 70 dw -> ~2-way banks)
__global__ __launch_bounds__(256) void a1_conv(const short* __restrict__ qb,
                                               const short* __restrict__ klb,
                                               const short* __restrict__ w2tb,
                                               const short* __restrict__ vtb,
                                               const float* __restrict__ rk,
                                               short* __restrict__ omb) {
  __shared__ __align__(16) char smem[35328];
  short* kls = (short*)smem;
  short* vwin = (short*)smem;
  short* band = (short*)(smem + 14848);
  short* ps = (short*)(smem + 17408);
  const int bh = blockIdx.y, t0 = blockIdx.x * 64;
  const int b = bh >> 3, h = bh & 7;
  const int tid = threadIdx.x, wave = tid >> 6, lane = tid & 63;
  const int mi = lane & 15, quad = lane >> 4;

  // q A-frags direct from global (wave-private rows, no reuse)
  const short* qrow = qb + ((size_t)bh * N_ + t0 + wave * 16 + mi) * DH_;
  const bf16x8 aq0 = *(const bf16x8*)(qrow + quad * 8);
  const bf16x8 aq1 = *(const bf16x8*)(qrow + 32 + quad * 8);

  // S = q @ kl^T over two 32-wide K chunks, klb staged via global_load_lds
  f32x4 s[16] = {};
#pragma unroll
  for (int kc = 0; kc < 2; ++kc) {
    if (kc) __syncthreads();  // all reads of chunk0 done
#pragma unroll
    for (int i = 0; i < 4; ++i) {
      const int cb = i * 256 + wave * 64;  // wave-uniform base chunk
      const int c = cb + lane;
      const int row = c >> 2, cc = (c & 3) * 8;
      __builtin_amdgcn_global_load_lds(
          (const __attribute__((address_space(1))) void*)(klb + ((size_t)bh * M_ + row) * DH_ +
                                                          kc * 32 + cc),
          (__attribute__((address_space(3))) void*)(kls + (size_t)cb * 8), 16, 0, 0);
    }
    __syncthreads();
    const bf16x8 aq = kc ? aq1 : aq0;
#pragma unroll
    for (int f = 0; f < 16; ++f) {
      const bf16x8 bf = *(const bf16x8*)&kls[(f * 16 + mi) * 32 + quad * 8];
      s[f] = __builtin_amdgcn_mfma_f32_16x16x32_bf16(aq, bf, s[f], 0, 0, 0);
    }
  }
  // exact softmax over 256 cols
  float inv[4];
#pragma unroll
  for (int r = 0; r < 4; ++r) {
    float v = s[0][r];
#pragma unroll
    for (int f = 1; f < 16; ++f) v = fmaxf(v, s[f][r]);
    v = fmaxf(v, __shfl_xor(v, 1, 64));
    v = fmaxf(v, __shfl_xor(v, 2, 64));
    v = fmaxf(v, __shfl_xor(v, 4, 64));
    v = fmaxf(v, __shfl_xor(v, 8, 64));
    float sum = 0.f;
#pragma unroll
    for (int f = 0; f < 16; ++f) {
      const float p = __expf(s[f][r] - v);
      s[f][r] = p;
      sum += p;
    }
    sum += __shfl_xor(sum, 1, 64);
    sum += __shfl_xor(sum, 2, 64);
    sum += __shfl_xor(sum, 4, 64);
    sum += __shfl_xor(sum, 8, 64);
    inv[r] = 1.f / sum;
  }
  __syncthreads();  // kls dead everywhere before vwin overwrite

  // write psA (cols 0..127); build vwin (64 x 112, zero-padded) + band (16 x 64)
#pragma unroll
  for (int f = 0; f < 8; ++f)
#pragma unroll
    for (int r = 0; r < 4; ++r)
      ps[(wave * 16 + quad * 4 + r) * 140 + f * 16 + mi] = f2bf(s[f][r] * inv[r]);
  {
    const int d = tid & 63, cg0 = tid >> 6;
    const short* vrow = vtb + ((size_t)bh * DH_ + d) * N_;
    for (int ch = cg0; ch < 14; ch += 4) {
      const int tbase = t0 - 16 + ch * 8;
      bf16x8 vv;
      if (tbase >= 0 && tbase + 8 <= N_) {
        vv = *(const bf16x8*)(vrow + tbase);
      } else {
#pragma unroll
        for (int e = 0; e < 8; ++e) {
          const int tt = tbase + e;
          vv[e] = (tt >= 0 && tt < N_) ? vrow[tt] : (short)0;
        }
      }
      *(bf16x8*)&vwin[d * 116 + ch * 8] = vv;
    }
  }
#pragma unroll
  for (int i = 0; i < 4; ++i) {
    const int idx = tid + i * 256;  // < 1024
    const int r = idx >> 6, c = idx & 63, u = c - r;
    band[r * 68 + c] = (u >= 0 && u < KC_) ? f2bf(rk[h * KC_ + u]) : (short)0;
  }
  __syncthreads();

  f32x4 o[4] = {};
  // PV pass A: landmarks 0..127
#pragma unroll
  for (int k0 = 0; k0 < 4; ++k0) {
    union { bf16x8 v; s16x4 hh[2]; } ap;
    const short* pp = &ps[(wave * 16 + mi) * 140 + k0 * 32 + quad * 8];
    ap.hh[0] = *(const s16x4*)pp;
    ap.hh[1] = *(const s16x4*)(pp + 4);
#pragma unroll
    for (int j = 0; j < 4; ++j) {
      const bf16x8 bw =
          *(const bf16x8*)(w2tb + ((size_t)bh * DH_ + j * 16 + mi) * M_ + k0 * 32 + quad * 8);
      o[j] = __builtin_amdgcn_mfma_f32_16x16x32_bf16(ap.v, bw, o[j], 0, 0, 0);
    }
  }
  __syncthreads();  // psA reads done
#pragma unroll
  for (int f = 8; f < 16; ++f)
#pragma unroll
    for (int r = 0; r < 4; ++r)
      ps[(wave * 16 + quad * 4 + r) * 140 + (f - 8) * 16 + mi] = f2bf(s[f][r] * inv[r]);
  __syncthreads();
  // PV pass B: landmarks 128..255
#pragma unroll
  for (int k0 = 0; k0 < 4; ++k0) {
    union { bf16x8 v; s16x4 hh[2]; } ap;
    const short* pp = &ps[(wave * 16 + mi) * 140 + k0 * 32 + quad * 8];
    ap.hh[0] = *(const s16x4*)pp;
    ap.hh[1] = *(const s16x4*)(pp + 4);
#pragma unroll
    for (int j = 0; j < 4; ++j) {
      const bf16x8 bw = *(const bf16x8*)(w2tb + ((size_t)bh * DH_ + j * 16 + mi) * M_ +
                                         (k0 + 4) * 32 + quad * 8);
      o[j] = __builtin_amdgcn_mfma_f32_16x16x32_bf16(ap.v, bw, o[j], 0, 0, 0);
    }
  }
  // conv: o += Band(16x64) @ Vwin-slice (wave-offset window)
#pragma unroll
  for (int ks = 0; ks < 2; ++ks) {
    union { bf16x8 v; s16x4 hh[2]; } ab;
    const short* bp = &band[mi * 68 + ks * 32 + quad * 8];
    ab.hh[0] = *(const s16x4*)bp;
    ab.hh[1] = *(const s16x4*)(bp + 4);
#pragma unroll
    for (int j = 0; j < 4; ++j) {
      union { bf16x8 v; s16x4 hh[2]; } bv;
      const short* vp = &vwin[(j * 16 + mi) * 116 + wave * 16 + ks * 32 + quad * 8];
      bv.hh[0] = *(const s16x4*)vp;
      bv.hh[1] = *(const s16x4*)(vp + 4);
      o[j] = __builtin_amdgcn_mfma_f32_16x16x32_bf16(ab.v, bv.v, o[j], 0, 0, 0);
    }
  }
  // epilogue
#pragma unroll
  for (int j = 0; j < 4; ++j) {
    const int d = j * 16 + mi;
#pragma unroll
    for (int r = 0; r < 4; ++r) {
      const int t = t0 + wave * 16 + quad * 4 + r;
      omb[((size_t)(b * N_ + t)) * DIM_ + h * DH_ + d] = f2bf(o[j][r]);
    }
  }
}

extern "C" void kernel_launch(void* const* d_in, const int* in_sizes, int n_in,
                              void* d_out, int out_size, void* d_ws, size_t ws_size,
                              hipStream_t stream) {
  (void)in_sizes; (void)n_in; (void)out_size;
  const float* x = (const float*)d_in[0];
  const float* gamma = (const float*)d_in[1];
  const float* beta = (const float*)d_in[2];
  const float* wqkv = (const float*)d_in[3];
  const float* wout = (const float*)d_in[4];
  const float* bout = (const float*)d_in[5];
  const float* rk = (const float*)d_in[6];
  float* y = (float*)d_out;
  float* ws = (float*)d_ws;

  size_t o = 0;
  short* xnb = (short*)(ws + o);   o += (size_t)2 * N_ * DIM_ / 2;
  short* wqkvt = (short*)(ws + o); o += (size_t)3 * DIM_ * DIM_ / 2;
  short* woutt = (short*)(ws + o); o += (size_t)DIM_ * DIM_ / 2;
  short* qb = (short*)(ws + o);    o += (size_t)BH_ * N_ * DH_ / 2;
  short* kb = (short*)(ws + o);    o += (size_t)BH_ * N_ * DH_ / 2;
  short* vb = (short*)(ws + o);    o += (size_t)BH_ * N_ * DH_ / 2;
  short* vtb = (short*)(ws + o);   o += (size_t)BH_ * N_ * DH_ / 2;
  float* ql = ws + o;  o += (size_t)BH_ * M_ * DH_;
  float* kl = ws + o;  o += (size_t)BH_ * M_ * DH_;
  short* qlb = (short*)(ws + o); o += (size_t)BH_ * M_ * DH_ / 2;
  short* klb = (short*)(ws + o); o += (size_t)BH_ * M_ * DH_ / 2;
  float* a2 = ws + o;  o += (size_t)BH_ * M_ * M_;
  float* z0f = ws + o; o += (size_t)BH_ * M_ * M_;
  short* a2b = (short*)(ws + o); o += (size_t)BH_ * M_ * M_ / 2;
  short* zb0 = (short*)(ws + o); o += (size_t)BH_ * M_ * M_ / 2;
  short* zb1 = (short*)(ws + o); o += (size_t)BH_ * M_ * M_ / 2;
  short* yb0 = (short*)(ws + o); o += (size_t)BH_ * M_ * M_ / 2;
  short* yb1 = (short*)(ws + o); o += (size_t)BH_ * M_ * M_ / 2;
  short* p1b = (short*)(ws + o); o += (size_t)BH_ * M_ * M_ / 2;
  short* y2b = (short*)(ws + o); o += (size_t)BH_ * M_ * M_ / 2;
  short* wb  = (short*)(ws + o); o += (size_t)BH_ * M_ * M_ / 2;
  float* Opart = ws + o; o += (size_t)8 * 64 * 4096;
  float* mpart = ws + o; o += (size_t)8 * 64 * 64;
  float* lpart = ws + o; o += (size_t)8 * 64 * 64;
  float* a3v = ws + o; o += (size_t)BH_ * M_ * DH_;
  float* w2 = ws + o;  o += (size_t)BH_ * M_ * DH_;
  short* w2tb = (short*)(ws + o); o += (size_t)BH_ * M_ * DH_ / 2;
  short* omb = (short*)(ws + o);  o += (size_t)2 * N_ * DIM_ / 2;
  unsigned int* scalebits = (unsigned int*)(ws + o); o += 16;
  if (ws_size < o * sizeof(float)) return;

  (void)hipMemsetAsync(scalebits, 0, 64, stream);
  ln_kernel<<<2 * N_, 128, 0, stream>>>(x, gamma, beta, xnb);
  convt_kernel<<<dim3(3 * DIM_ / 32, DIM_ / 32), 256, 0, stream>>>(wqkv, wqkvt, DIM_, 3 * DIM_);
  convt_kernel<<<dim3(DIM_ / 32, DIM_ / 32), 256, 0, stream>>>(wout, woutt, DIM_, DIM_);
  qkv_mfma<<<dim3(2 * N_ / 128, 3 * DIM_ / 128), 256, 0, stream>>>(xnb, wqkvt, qb, kb, vb);
  vt_kernel<<<dim3(N_ / 32, 2, BH_), 256, 0, stream>>>(vb, vtb);

  landmark_kernel<<<BH_ * M_ * DH_ / 256, 256, 0, stream>>>(qb, kb, ql, kl, qlb, klb);
  sim2_softmax<<<dim3(M_, BH_), 256, 0, stream>>>(ql, kl, a2, a2b);
  colmax_kernel<<<BH_, 256, 0, stream>>>(a2, scalebits);
  transpose_scale<<<BH_ * M_ * M_ / 256, 256, 0, stream>>>(a2, zb0, scalebits);

  // a3 flash (independent of pinv)
  a3_flash<<<dim3(8, 4, BH_), 256, 0, stream>>>(qlb, kb, vtb, Opart, mpart, lpart);
  a3_combine<<<64, 256, 0, stream>>>(Opart, mpart, lpart, a3v);

  // Newton-Schulz, 2 dependent launches/iter
  ns_gemm0<<<dim3(16, BH_), 256, 0, stream>>>(a2b, zb0, yb0);
  short* zc = zb0; short* zn = zb1; short* yc = yb0; short* yn = yb1;
  for (int it = 0; it < 6; ++it) {
    const int last = (it == 5);
    ns_stageA<<<dim3(16, 2 * BH_), 256, 0, stream>>>(zc, yc, p1b, y2b, wb);
    ns_stageB<<<dim3(16, last ? BH_ : 2 * BH_), 256, 0, stream>>>(
        p1b, y2b, wb, zc, yc, zn, yn, last ? z0f : nullptr, last);
    short* t;
    t = zc; zc = zn; zn = t;
    t = yc; yc = yn; yn = t;
  }

  // w2 = z @ a3v (fp32), transpose to bf16
  gemm_nn64<<<dim3(M_ / 64, 1, BH_), 256, 0, stream>>>(
      z0f, M_, (long long)M_ * M_, a3v, (long long)M_ * DH_, w2, (long long)M_ * DH_, M_);
  w2t_kernel<<<BH_, 256, 0, stream>>>(w2, w2tb);

  // fused a1 @ w2 + band-MFMA depthwise conv -> omb bf16
  a1_conv<<<dim3(N_ / 64, BH_), 256, 0, stream>>>(qb, klb, w2tb, vtb, rk, omb);

  final_mfma<<<dim3(2 * N_ / 128, DIM_ / 128), 256, 0, stream>>>(omb, woutt, x, bout, y);
}